// Round 6
// baseline (6979.477 us; speedup 1.0000x reference)
//
#include <hip/hip_runtime.h>
#include <hip/hip_bf16.h>
#include <math.h>

#define T_   4
#define B_   32
#define C_   384
#define N_   196
#define HID_ 1536
#define NH_  12
#define DH_  32
#define NCOL (B_*N_)            // 6272 columns (b,n)
#define XBLK 25                 // ceil(6272/256)
#define KCH  384                // K chunk (= c_in for all but fc2)

typedef unsigned char u8;

// ---------------------------------------------------------------------------
// Fused 1x1-conv + BN + LIF scan. f32 tensors in, all pre-threshold math in
// f64 so spike decisions match the f64 numpy reference (order noise ~1e-14
// vs ~1e-7 min threshold gaps; r5 absmax=0.0 proves order-independence).
// IN_MODE: 0 = f32 X; 1 = u8 X (spikes); 2 = f32 X + u8 Sadd (x + proj spikes)
// OM:      0 = write u8 spikes; 1 = write f32 (xres + sres + spike)  [final]
// NZ:      3 = fused q/k/v (z selects branch), else 1.
// OT:      output channels per thread (16 dense heavies, 8 small-grid convs)
// Each thread owns one column (b,n), OT output channels, all 4 timesteps.
// W tile (OT x 384 f64, <=48KB LDS) staged once per K-chunk; broadcast
// double4 reads are bank-conflict-free.
// ---------------------------------------------------------------------------
template<int IN_MODE, int OM, int NZ, int OT>
__global__ __launch_bounds__(256, (OT == 16 ? 2 : 3)) void conv_lif_kernel(
    const void* __restrict__ Xv, const u8* __restrict__ Sadd,
    const float* __restrict__ W0, const float* __restrict__ W1, const float* __restrict__ W2,
    const float* __restrict__ cb0, const float* __restrict__ cb1, const float* __restrict__ cb2,
    const float* __restrict__ bn0, const float* __restrict__ bn1, const float* __restrict__ bn2,
    const float* __restrict__ lw0, const float* __restrict__ lw1, const float* __restrict__ lw2,
    u8* S0, u8* S1, u8* S2,
    const float* __restrict__ xres, const u8* __restrict__ sres,
    float* out,
    int c_out, int c_in, int ny)
{
    __shared__ double w_lds[OT][KCH];     // OT=16: 48 KB, OT=8: 24 KB
    const int tid = threadIdx.x;
    const int id  = blockIdx.x;
    const int xblk = id / (ny * NZ);
    const int rem  = id % (ny * NZ);
    const int z = (NZ == 1) ? 0 : (rem % NZ);
    const int y = (NZ == 1) ? rem : (rem / NZ);

    const float* W   = (z == 0) ? W0  : ((z == 1) ? W1  : W2);
    const float* cb  = (z == 0) ? cb0 : ((z == 1) ? cb1 : cb2);
    const float* bnp = (z == 0) ? bn0 : ((z == 1) ? bn1 : bn2);
    const float* lw  = (z == 0) ? lw0 : ((z == 1) ? lw1 : lw2);
    u8* SOUT         = (z == 0) ? S0  : ((z == 1) ? S1  : S2);

    const float* Xf = (const float*)Xv;
    const u8*    Xb = (const u8*)Xv;

    int col = xblk * 256 + tid;
    const bool valid = (col < NCOL);
    if (!valid) col = 0;
    const int b = col / N_, n = col % N_;
    const int o_base = y * OT;

    size_t xbase[4];
#pragma unroll
    for (int t = 0; t < 4; ++t)
        xbase[t] = ((size_t)(t * B_ + b) * c_in) * N_ + n;

    double acc[4][OT];
#pragma unroll
    for (int t = 0; t < 4; ++t)
#pragma unroll
        for (int o = 0; o < OT; ++o) acc[t][o] = 0.0;

    for (int kc = 0; kc < c_in; kc += KCH) {
        __syncthreads();
        // stage OT x 384 W tile as f64: (OT*384/4) float4 loads over 256 thr
#pragma unroll
        for (int j = 0; j < OT * KCH / 1024; ++j) {
            int idx4 = tid + 256 * j;
            int o = idx4 / (KCH / 4);
            int k = (idx4 % (KCH / 4)) * 4;
            float4 w = *(const float4*)&W[(size_t)(o_base + o) * c_in + kc + k];
            *(double2*)&w_lds[o][k]     = make_double2((double)w.x, (double)w.y);
            *(double2*)&w_lds[o][k + 2] = make_double2((double)w.z, (double)w.w);
        }
        __syncthreads();

        for (int k = 0; k < KCH; k += 4) {
            double xv[4][4];
#pragma unroll
            for (int t = 0; t < 4; ++t)
#pragma unroll
                for (int kk = 0; kk < 4; ++kk) {
                    const size_t i = xbase[t] + (size_t)(kc + k + kk) * N_;
                    if (IN_MODE == 0)      xv[t][kk] = (double)Xf[i];
                    else if (IN_MODE == 1) xv[t][kk] = (double)Xb[i];
                    else                   xv[t][kk] = (double)Xf[i] + (double)Sadd[i];
                }
#pragma unroll
            for (int o = 0; o < OT; ++o) {
                const double4 wv = *(const double4*)&w_lds[o][k];
#pragma unroll
                for (int t = 0; t < 4; ++t) {
                    acc[t][o] = fma(wv.x, xv[t][0], acc[t][o]);
                    acc[t][o] = fma(wv.y, xv[t][1], acc[t][o]);
                    acc[t][o] = fma(wv.z, xv[t][2], acc[t][o]);
                    acc[t][o] = fma(wv.w, xv[t][3], acc[t][o]);
                }
            }
        }
    }

    if (valid) {
        const double tau = 1.0 / (1.0 + exp(-(double)lw[0]));
        const size_t per_t = (size_t)B_ * c_out * N_;
#pragma unroll
        for (int o = 0; o < OT; ++o) {
            const int oo = o_base + o;
            const double g  = (double)bnp[oo];
            const double be = (double)bnp[c_out + oo];
            const double mm = (double)bnp[2 * c_out + oo];
            const double vv = (double)bnp[3 * c_out + oo];
            const double inv   = g / sqrt(vv + 1e-5);
            const double shift = be - mm * inv;
            const double cbv   = cb ? (double)cb[oo] : 0.0;
            const size_t idx0 = ((size_t)b * c_out + oo) * N_ + n;
            double v = 0.0;
#pragma unroll
            for (int t = 0; t < 4; ++t) {
                const double yv = (acc[t][o] + cbv) * inv + shift;
                const double h  = v + (yv - v) * tau;
                const double sp = (h >= 1.0) ? 1.0 : 0.0;
                v = h * (1.0 - sp);
                const size_t idx = (size_t)t * per_t + idx0;
                if (OM == 0) {
                    SOUT[idx] = (u8)sp;
                } else {
                    out[idx] = (float)((double)xres[idx] + (double)sres[idx] + sp);
                }
            }
        }
    }
}

// ---------------------------------------------------------------------------
// Spike attention + fused LIF. One block per (b,h); loops t internally.
// All values are dyadic rationals (ints scaled by 2^-k, k<=7, magnitude<2^13)
// -> exact in f32, bit-identical to any higher-precision reference.
// grid = B*NH = 384, block = 256
// ---------------------------------------------------------------------------
__global__ __launch_bounds__(256) void attn_lif_kernel(
    const u8* __restrict__ SQ, const u8* __restrict__ SK, const u8* __restrict__ SV,
    u8* __restrict__ SATT, const float* __restrict__ lw)
{
    __shared__ u8 q_lds[DH_ * N_];        // 6272 B
    __shared__ u8 k_lds[DH_ * N_];
    __shared__ u8 v_lds[DH_ * N_];
    __shared__ float kv_lds[DH_ * DH_];   // 4 KB
    __shared__ float vstate[DH_ * N_];    // 25 KB
    const int tid = threadIdx.x;
    const int b = blockIdx.x / NH_, h = blockIdx.x % NH_;
    const float tau = 1.0f / (1.0f + expf(-lw[0]));   // lw=0 -> exactly 0.5

    for (int i = tid; i < DH_ * N_; i += 256) vstate[i] = 0.0f;

    for (int t = 0; t < T_; ++t) {
        const size_t base = ((size_t)((t * B_ + b) * C_) + h * DH_) * N_;
        __syncthreads();
        for (int i = tid; i < DH_ * N_ / 4; i += 256) {
            ((unsigned int*)q_lds)[i] = ((const unsigned int*)(SQ + base))[i];
            ((unsigned int*)k_lds)[i] = ((const unsigned int*)(SK + base))[i];
            ((unsigned int*)v_lds)[i] = ((const unsigned int*)(SV + base))[i];
        }
        __syncthreads();

#pragma unroll
        for (int r = 0; r < 4; ++r) {
            const int e = tid + 256 * r;
            const int i = e >> 5, j = e & 31;
            int s = 0;
            for (int nn = 0; nn < N_; nn += 4) {
                uchar4 kk = *(const uchar4*)&k_lds[i * N_ + nn];
                uchar4 uv = *(const uchar4*)&v_lds[j * N_ + nn];
                s += kk.x * uv.x + kk.y * uv.y + kk.z * uv.z + kk.w * uv.w;
            }
            kv_lds[e] = (float)s;
        }
        __syncthreads();

        for (int e = tid; e < DH_ * N_; e += 256) {
            const int j = e / N_, nn = e % N_;
            float s = 0.0f;
#pragma unroll
            for (int i = 0; i < DH_; ++i)
                s += q_lds[i * N_ + nn] ? kv_lds[i * DH_ + j] : 0.0f;
            const float att = 0.125f * s;           // exact dyadic
            const float v = vstate[e];
            const float hh = v + (att - v) * tau;   // exact dyadic
            const float sp = (hh >= 1.0f) ? 1.0f : 0.0f;
            vstate[e] = hh * (1.0f - sp);
            SATT[base + e] = (u8)sp;
        }
    }
}

// ---------------------------------------------------------------------------
extern "C" void kernel_launch(void* const* d_in, const int* in_sizes, int n_in,
                              void* d_out, int out_size, void* d_ws, size_t ws_size,
                              hipStream_t stream)
{
    const float* x       = (const float*)d_in[0];
    const float* q_w     = (const float*)d_in[1];
    const float* q_bn    = (const float*)d_in[2];
    const float* q_lw    = (const float*)d_in[3];
    const float* k_w     = (const float*)d_in[4];
    const float* k_bn    = (const float*)d_in[5];
    const float* k_lw    = (const float*)d_in[6];
    const float* v_w     = (const float*)d_in[7];
    const float* v_bn    = (const float*)d_in[8];
    const float* v_lw    = (const float*)d_in[9];
    const float* attn_lw = (const float*)d_in[10];
    const float* proj_w  = (const float*)d_in[11];
    const float* proj_b  = (const float*)d_in[12];
    const float* proj_bn = (const float*)d_in[13];
    const float* proj_lw = (const float*)d_in[14];
    const float* fc1_w   = (const float*)d_in[15];
    const float* fc1_b   = (const float*)d_in[16];
    const float* fc1_bn  = (const float*)d_in[17];
    const float* fc1_lw  = (const float*)d_in[18];
    const float* fc2_w   = (const float*)d_in[19];
    const float* fc2_b   = (const float*)d_in[20];
    const float* fc2_bn  = (const float*)d_in[21];
    const float* fc2_lw  = (const float*)d_in[22];

    // ---- workspace: u8 spike tensors only (~83 MB, proven safe) ----
    u8* SQ   = (u8*)d_ws;                 // 9,633,792 B each
    u8* SK   = SQ + 9633792;
    u8* SV   = SK + 9633792;
    u8* SATT = SV + 9633792;
    u8* SP   = SATT + 9633792;            // proj spikes
    u8* SZ   = SP + 9633792;              // fc1 spikes, 38,535,168 B
    float* out = (float*)d_out;

    // 1. fused q/k/v conv+BN+LIF -> u8 spikes   (OT=16, ny=24)
    conv_lif_kernel<0, 0, 3, 16><<<XBLK * 24 * 3, 256, 0, stream>>>(
        x, nullptr,
        q_w, k_w, v_w,
        nullptr, nullptr, nullptr,
        q_bn, k_bn, v_bn,
        q_lw, k_lw, v_lw,
        SQ, SK, SV,
        nullptr, nullptr, nullptr,
        C_, C_, 24);

    // 2. attention + LIF -> u8 spikes (exact arithmetic)
    attn_lif_kernel<<<B_ * NH_, 256, 0, stream>>>(SQ, SK, SV, SATT, attn_lw);

    // 3. proj conv + BN + LIF -> u8 spikes  (OT=8, ny=48)
    conv_lif_kernel<1, 0, 1, 8><<<XBLK * 48, 256, 0, stream>>>(
        SATT, nullptr,
        proj_w, proj_w, proj_w,
        proj_b, proj_b, proj_b,
        proj_bn, proj_bn, proj_bn,
        proj_lw, proj_lw, proj_lw,
        SP, SP, SP,
        nullptr, nullptr, nullptr,
        C_, C_, 48);

    // 4. fc1 conv (input = f32 x + u8 SP, exact in f64) + BN + LIF  (OT=16)
    conv_lif_kernel<2, 0, 1, 16><<<XBLK * 96, 256, 0, stream>>>(
        x, SP,
        fc1_w, fc1_w, fc1_w,
        fc1_b, fc1_b, fc1_b,
        fc1_bn, fc1_bn, fc1_bn,
        fc1_lw, fc1_lw, fc1_lw,
        SZ, SZ, SZ,
        nullptr, nullptr, nullptr,
        HID_, C_, 96);

    // 5. fc2 conv + BN + LIF + residual(x + SP) -> final f32 output (OT=8)
    conv_lif_kernel<1, 1, 1, 8><<<XBLK * 48, 256, 0, stream>>>(
        SZ, nullptr,
        fc2_w, fc2_w, fc2_w,
        fc2_b, fc2_b, fc2_b,
        fc2_bn, fc2_bn, fc2_bn,
        fc2_lw, fc2_lw, fc2_lw,
        nullptr, nullptr, nullptr,
        x, SP, out,
        C_, HID_, 48);
}

// Round 7
// 4726.084 us; speedup vs baseline: 1.4768x; 1.4768x over previous
//
#include <hip/hip_runtime.h>
#include <math.h>

#define T_   4
#define B_   32
#define C_   384
#define N_   196
#define HID_ 1536
#define NH_  12
#define DH_  32
#define NCOL (B_*N_)            // 6272 columns (b,n)
#define XBLK 25                 // ceil(6272/256)
#define KCH  128                // K chunk
#define THRESH 2.5e-4f          // f32 certainty margin (Hoeffding ~e^-56)
#define FCAP (1u<<20)           // flag list capacity per layer

typedef unsigned char u8;
typedef unsigned int  u32;

__global__ void zero_counters(u32* cnt) { if (threadIdx.x < 4) cnt[threadIdx.x] = 0; }

// ---------------------------------------------------------------------------
// f32 main pass: fused 1x1-conv + BN + LIF scan, OT=16 outputs/thread.
// Flags any (z,o,col) whose LIF trajectory passes within THRESH of the
// threshold; fixup_kernel recomputes those exactly in f64 (r5-proven math).
// IN_MODE: 0 = f32 X; 1 = u8 X (spikes); 2 = f32 X + u8 Sadd
// OM:      0 = write u8 spikes; 1 = write f32 (xres + sres + spike) [final]
// NZ:      3 = fused q/k/v (z selects branch), else 1.
// ---------------------------------------------------------------------------
template<int IN_MODE, int OM, int NZ>
__global__ __launch_bounds__(256) void conv_lif_f32(
    const void* __restrict__ Xv, const u8* __restrict__ Sadd,
    const float* __restrict__ W0, const float* __restrict__ W1, const float* __restrict__ W2,
    const float* __restrict__ cb0, const float* __restrict__ cb1, const float* __restrict__ cb2,
    const float* __restrict__ bn0, const float* __restrict__ bn1, const float* __restrict__ bn2,
    const float* __restrict__ lw0, const float* __restrict__ lw1, const float* __restrict__ lw2,
    u8* S0, u8* S1, u8* S2,
    const float* __restrict__ xres, const u8* __restrict__ sres, float* out,
    u32* __restrict__ cnt, u32* __restrict__ flags,
    int c_out, int c_in, int ny)
{
    __shared__ float w_lds[16][KCH];      // 8 KB
    const int tid = threadIdx.x;
    const int id  = blockIdx.x;
    const int xblk = id / (ny * NZ);
    const int rem  = id % (ny * NZ);
    const int z = (NZ == 1) ? 0 : (rem % NZ);
    const int y = (NZ == 1) ? rem : (rem / NZ);

    const float* W   = (z == 0) ? W0  : ((z == 1) ? W1  : W2);
    const float* cb  = (z == 0) ? cb0 : ((z == 1) ? cb1 : cb2);
    const float* bnp = (z == 0) ? bn0 : ((z == 1) ? bn1 : bn2);
    const float* lw  = (z == 0) ? lw0 : ((z == 1) ? lw1 : lw2);
    u8* SOUT         = (z == 0) ? S0  : ((z == 1) ? S1  : S2);

    const float* Xf = (const float*)Xv;
    const u8*    Xb = (const u8*)Xv;

    int col = xblk * 256 + tid;
    const bool valid = (col < NCOL);
    if (!valid) col = 0;
    const int b = col / N_, n = col % N_;
    const int o_base = y * 16;

    size_t xbase[4];
#pragma unroll
    for (int t = 0; t < 4; ++t)
        xbase[t] = ((size_t)(t * B_ + b) * c_in) * N_ + n;

    float acc[4][16];
#pragma unroll
    for (int t = 0; t < 4; ++t)
#pragma unroll
        for (int o = 0; o < 16; ++o) acc[t][o] = 0.0f;

    for (int kc = 0; kc < c_in; kc += KCH) {
        __syncthreads();
        // stage 16x128 W tile: 512 float4 over 256 threads
#pragma unroll
        for (int j = 0; j < 2; ++j) {
            int idx4 = tid + 256 * j;          // 0..511
            int o = idx4 >> 5;                 // /32 (KCH/4=32)
            int k = (idx4 & 31) << 2;
            *(float4*)&w_lds[o][k] =
                *(const float4*)&W[(size_t)(o_base + o) * c_in + kc + k];
        }
        __syncthreads();

#pragma unroll 2
        for (int k = 0; k < KCH; k += 4) {
            float xv[4][4];
#pragma unroll
            for (int t = 0; t < 4; ++t)
#pragma unroll
                for (int kk = 0; kk < 4; ++kk) {
                    const size_t i = xbase[t] + (size_t)(kc + k + kk) * N_;
                    if (IN_MODE == 0)      xv[t][kk] = Xf[i];
                    else if (IN_MODE == 1) xv[t][kk] = (float)Xb[i];
                    else                   xv[t][kk] = Xf[i] + (float)Sadd[i];
                }
#pragma unroll
            for (int o = 0; o < 16; ++o) {
                const float4 wv = *(const float4*)&w_lds[o][k];
#pragma unroll
                for (int t = 0; t < 4; ++t) {
                    acc[t][o] = fmaf(wv.x, xv[t][0], acc[t][o]);
                    acc[t][o] = fmaf(wv.y, xv[t][1], acc[t][o]);
                    acc[t][o] = fmaf(wv.z, xv[t][2], acc[t][o]);
                    acc[t][o] = fmaf(wv.w, xv[t][3], acc[t][o]);
                }
            }
        }
    }

    if (valid) {
        const float tau = 1.0f / (1.0f + expf(-lw[0]));
        const size_t per_t = (size_t)B_ * c_out * N_;
#pragma unroll
        for (int o = 0; o < 16; ++o) {
            const int oo = o_base + o;
            const float g  = bnp[oo];
            const float be = bnp[c_out + oo];
            const float mm = bnp[2 * c_out + oo];
            const float vv = bnp[3 * c_out + oo];
            const float inv   = g / sqrtf(vv + 1e-5f);
            const float shift = be - mm * inv;
            const float cbv   = cb ? cb[oo] : 0.0f;
            const size_t idx0 = ((size_t)b * c_out + oo) * N_ + n;
            float v = 0.0f;
            bool flag = false;
#pragma unroll
            for (int t = 0; t < 4; ++t) {
                const float yv = (acc[t][o] + cbv) * inv + shift;
                const float h  = v + (yv - v) * tau;
                const float sp = (h >= 1.0f) ? 1.0f : 0.0f;
                flag = flag || (fabsf(h - 1.0f) < THRESH);
                v = h * (1.0f - sp);
                const size_t idx = (size_t)t * per_t + idx0;
                if (OM == 0) {
                    SOUT[idx] = (u8)sp;
                } else {
                    out[idx] = (float)((double)xres[idx] + (double)sres[idx] + (double)sp);
                }
            }
            if (flag) {
                u32 pos = atomicAdd(cnt, 1u);
                if (pos < FCAP)
                    flags[pos] = ((u32)(z * c_out + oo)) * (u32)NCOL + (u32)col;
            }
        }
    }
}

// ---------------------------------------------------------------------------
// f64 fixup: one wave per flagged record; recomputes the 4-timestep LIF
// sequence exactly as the r5 all-f64 kernel (verified absmax 0.0) and
// rewrites the spikes / final outputs. Grid-strided over records.
// ---------------------------------------------------------------------------
template<int IN_MODE, int OM>
__global__ __launch_bounds__(256) void fixup_kernel(
    const void* __restrict__ Xv, const u8* __restrict__ Sadd,
    const float* __restrict__ W0, const float* __restrict__ W1, const float* __restrict__ W2,
    const float* __restrict__ cb0, const float* __restrict__ cb1, const float* __restrict__ cb2,
    const float* __restrict__ bn0, const float* __restrict__ bn1, const float* __restrict__ bn2,
    const float* __restrict__ lw0, const float* __restrict__ lw1, const float* __restrict__ lw2,
    u8* S0, u8* S1, u8* S2,
    const float* __restrict__ xres, const u8* __restrict__ sres, float* out,
    const u32* __restrict__ cnt, const u32* __restrict__ flags,
    int c_out, int c_in)
{
    const int lane = threadIdx.x & 63;
    const int wid  = (blockIdx.x * 256 + threadIdx.x) >> 6;
    const int nw   = (gridDim.x * 256) >> 6;
    u32 nrec = *cnt;
    if (nrec > FCAP) nrec = FCAP;

    const float* Xf = (const float*)Xv;
    const u8*    Xb = (const u8*)Xv;

    for (u32 r = wid; r < nrec; r += nw) {
        const u32 rec = flags[r];
        const int col = (int)(rec % (u32)NCOL);
        const u32 zo  = rec / (u32)NCOL;
        const int z   = (int)(zo / (u32)c_out);
        const int o   = (int)(zo % (u32)c_out);

        const float* W   = (z == 0) ? W0  : ((z == 1) ? W1  : W2);
        const float* cb  = (z == 0) ? cb0 : ((z == 1) ? cb1 : cb2);
        const float* bnp = (z == 0) ? bn0 : ((z == 1) ? bn1 : bn2);
        const float* lw  = (z == 0) ? lw0 : ((z == 1) ? lw1 : lw2);
        u8* SOUT         = (z == 0) ? S0  : ((z == 1) ? S1  : S2);

        const int b = col / N_, nn = col % N_;
        double acc[4] = {0.0, 0.0, 0.0, 0.0};
        for (int c = lane; c < c_in; c += 64) {
            const double w = (double)W[(size_t)o * c_in + c];
#pragma unroll
            for (int t = 0; t < 4; ++t) {
                const size_t i = ((size_t)(t * B_ + b) * c_in + c) * N_ + nn;
                double xval;
                if (IN_MODE == 0)      xval = (double)Xf[i];
                else if (IN_MODE == 1) xval = (double)Xb[i];
                else                   xval = (double)Xf[i] + (double)Sadd[i];
                acc[t] = fma(w, xval, acc[t]);
            }
        }
#pragma unroll
        for (int m = 32; m; m >>= 1) {
#pragma unroll
            for (int t = 0; t < 4; ++t)
                acc[t] += __shfl_xor(acc[t], m, 64);
        }

        if (lane == 0) {
            const double tau = 1.0 / (1.0 + exp(-(double)lw[0]));
            const double g  = (double)bnp[o];
            const double be = (double)bnp[c_out + o];
            const double mm = (double)bnp[2 * c_out + o];
            const double vv = (double)bnp[3 * c_out + o];
            const double inv   = g / sqrt(vv + 1e-5);
            const double shift = be - mm * inv;
            const double cbv   = cb ? (double)cb[o] : 0.0;
            const size_t per_t = (size_t)B_ * c_out * N_;
            const size_t idx0  = ((size_t)b * c_out + o) * N_ + nn;
            double v = 0.0;
#pragma unroll
            for (int t = 0; t < 4; ++t) {
                const double yv = (acc[t] + cbv) * inv + shift;
                const double h  = v + (yv - v) * tau;
                const double sp = (h >= 1.0) ? 1.0 : 0.0;
                v = h * (1.0 - sp);
                const size_t idx = (size_t)t * per_t + idx0;
                if (OM == 0) {
                    SOUT[idx] = (u8)sp;
                } else {
                    out[idx] = (float)((double)xres[idx] + (double)sres[idx] + sp);
                }
            }
        }
    }
}

// ---------------------------------------------------------------------------
// Spike attention + fused LIF (exact dyadic arithmetic, no flags needed).
// grid = B*NH = 384, block = 256
// ---------------------------------------------------------------------------
__global__ __launch_bounds__(256) void attn_lif_kernel(
    const u8* __restrict__ SQ, const u8* __restrict__ SK, const u8* __restrict__ SV,
    u8* __restrict__ SATT, const float* __restrict__ lw)
{
    __shared__ u8 q_lds[DH_ * N_];
    __shared__ u8 k_lds[DH_ * N_];
    __shared__ u8 v_lds[DH_ * N_];
    __shared__ float kv_lds[DH_ * DH_];
    __shared__ float vstate[DH_ * N_];
    const int tid = threadIdx.x;
    const int b = blockIdx.x / NH_, h = blockIdx.x % NH_;
    const float tau = 1.0f / (1.0f + expf(-lw[0]));

    for (int i = tid; i < DH_ * N_; i += 256) vstate[i] = 0.0f;

    for (int t = 0; t < T_; ++t) {
        const size_t base = ((size_t)((t * B_ + b) * C_) + h * DH_) * N_;
        __syncthreads();
        for (int i = tid; i < DH_ * N_ / 4; i += 256) {
            ((unsigned int*)q_lds)[i] = ((const unsigned int*)(SQ + base))[i];
            ((unsigned int*)k_lds)[i] = ((const unsigned int*)(SK + base))[i];
            ((unsigned int*)v_lds)[i] = ((const unsigned int*)(SV + base))[i];
        }
        __syncthreads();

#pragma unroll
        for (int r = 0; r < 4; ++r) {
            const int e = tid + 256 * r;
            const int i = e >> 5, j = e & 31;
            int s = 0;
            for (int nn = 0; nn < N_; nn += 4) {
                uchar4 kk = *(const uchar4*)&k_lds[i * N_ + nn];
                uchar4 uv = *(const uchar4*)&v_lds[j * N_ + nn];
                s += kk.x * uv.x + kk.y * uv.y + kk.z * uv.z + kk.w * uv.w;
            }
            kv_lds[e] = (float)s;
        }
        __syncthreads();

        for (int e = tid; e < DH_ * N_; e += 256) {
            const int j = e / N_, nn = e % N_;
            float s = 0.0f;
#pragma unroll
            for (int i = 0; i < DH_; ++i)
                s += q_lds[i * N_ + nn] ? kv_lds[i * DH_ + j] : 0.0f;
            const float att = 0.125f * s;
            const float v = vstate[e];
            const float hh = v + (att - v) * tau;
            const float sp = (hh >= 1.0f) ? 1.0f : 0.0f;
            vstate[e] = hh * (1.0f - sp);
            SATT[base + e] = (u8)sp;
        }
    }
}

// ---------------------------------------------------------------------------
extern "C" void kernel_launch(void* const* d_in, const int* in_sizes, int n_in,
                              void* d_out, int out_size, void* d_ws, size_t ws_size,
                              hipStream_t stream)
{
    const float* x       = (const float*)d_in[0];
    const float* q_w     = (const float*)d_in[1];
    const float* q_bn    = (const float*)d_in[2];
    const float* q_lw    = (const float*)d_in[3];
    const float* k_w     = (const float*)d_in[4];
    const float* k_bn    = (const float*)d_in[5];
    const float* k_lw    = (const float*)d_in[6];
    const float* v_w     = (const float*)d_in[7];
    const float* v_bn    = (const float*)d_in[8];
    const float* v_lw    = (const float*)d_in[9];
    const float* attn_lw = (const float*)d_in[10];
    const float* proj_w  = (const float*)d_in[11];
    const float* proj_b  = (const float*)d_in[12];
    const float* proj_bn = (const float*)d_in[13];
    const float* proj_lw = (const float*)d_in[14];
    const float* fc1_w   = (const float*)d_in[15];
    const float* fc1_b   = (const float*)d_in[16];
    const float* fc1_bn  = (const float*)d_in[17];
    const float* fc1_lw  = (const float*)d_in[18];
    const float* fc2_w   = (const float*)d_in[19];
    const float* fc2_b   = (const float*)d_in[20];
    const float* fc2_bn  = (const float*)d_in[21];
    const float* fc2_lw  = (const float*)d_in[22];

    // ---- workspace layout (~104 MB) ----
    u8* SQ   = (u8*)d_ws;                 // 9,633,792 B each
    u8* SK   = SQ + 9633792;
    u8* SV   = SK + 9633792;
    u8* SATT = SV + 9633792;
    u8* SP   = SATT + 9633792;            // proj spikes
    u8* SZ   = SP + 9633792;              // fc1 spikes, 38,535,168 B
    u32* cnt    = (u32*)(SZ + 38535168);  // 4 counters (+pad)
    u32* flagsQ = cnt + 64;
    u32* flagsP = flagsQ + FCAP;
    u32* flags1 = flagsP + FCAP;
    u32* flags2 = flags1 + FCAP;
    float* out = (float*)d_out;

    zero_counters<<<1, 64, 0, stream>>>(cnt);

    // 1. fused q/k/v conv+BN+LIF (f32) -> spikes, flags
    conv_lif_f32<0, 0, 3><<<XBLK * 24 * 3, 256, 0, stream>>>(
        x, nullptr, q_w, k_w, v_w,
        nullptr, nullptr, nullptr, q_bn, k_bn, v_bn, q_lw, k_lw, v_lw,
        SQ, SK, SV, nullptr, nullptr, nullptr,
        cnt + 0, flagsQ, C_, C_, 24);
    fixup_kernel<0, 0><<<512, 256, 0, stream>>>(
        x, nullptr, q_w, k_w, v_w,
        nullptr, nullptr, nullptr, q_bn, k_bn, v_bn, q_lw, k_lw, v_lw,
        SQ, SK, SV, nullptr, nullptr, nullptr,
        cnt + 0, flagsQ, C_, C_);

    // 2. attention + LIF (exact)
    attn_lif_kernel<<<B_ * NH_, 256, 0, stream>>>(SQ, SK, SV, SATT, attn_lw);

    // 3. proj conv + BN + LIF -> SP
    conv_lif_f32<1, 0, 1><<<XBLK * 24, 256, 0, stream>>>(
        SATT, nullptr, proj_w, proj_w, proj_w,
        proj_b, proj_b, proj_b, proj_bn, proj_bn, proj_bn, proj_lw, proj_lw, proj_lw,
        SP, SP, SP, nullptr, nullptr, nullptr,
        cnt + 1, flagsP, C_, C_, 24);
    fixup_kernel<1, 0><<<512, 256, 0, stream>>>(
        SATT, nullptr, proj_w, proj_w, proj_w,
        proj_b, proj_b, proj_b, proj_bn, proj_bn, proj_bn, proj_lw, proj_lw, proj_lw,
        SP, SP, SP, nullptr, nullptr, nullptr,
        cnt + 1, flagsP, C_, C_);

    // 4. fc1 conv (x + SP) + BN + LIF -> SZ
    conv_lif_f32<2, 0, 1><<<XBLK * 96, 256, 0, stream>>>(
        x, SP, fc1_w, fc1_w, fc1_w,
        fc1_b, fc1_b, fc1_b, fc1_bn, fc1_bn, fc1_bn, fc1_lw, fc1_lw, fc1_lw,
        SZ, SZ, SZ, nullptr, nullptr, nullptr,
        cnt + 2, flags1, HID_, C_, 96);
    fixup_kernel<2, 0><<<512, 256, 0, stream>>>(
        x, SP, fc1_w, fc1_w, fc1_w,
        fc1_b, fc1_b, fc1_b, fc1_bn, fc1_bn, fc1_bn, fc1_lw, fc1_lw, fc1_lw,
        SZ, SZ, SZ, nullptr, nullptr, nullptr,
        cnt + 2, flags1, HID_, C_);

    // 5. fc2 conv + BN + LIF + residual(x + SP) -> final f32 output
    conv_lif_f32<1, 1, 1><<<XBLK * 24, 256, 0, stream>>>(
        SZ, nullptr, fc2_w, fc2_w, fc2_w,
        fc2_b, fc2_b, fc2_b, fc2_bn, fc2_bn, fc2_bn, fc2_lw, fc2_lw, fc2_lw,
        nullptr, nullptr, nullptr, x, SP, out,
        cnt + 3, flags2, C_, HID_, 24);
    fixup_kernel<1, 1><<<512, 256, 0, stream>>>(
        SZ, nullptr, fc2_w, fc2_w, fc2_w,
        fc2_b, fc2_b, fc2_b, fc2_bn, fc2_bn, fc2_bn, fc2_lw, fc2_lw, fc2_lw,
        nullptr, nullptr, nullptr, x, SP, out,
        cnt + 3, flags2, C_, HID_);
}

// Round 8
// 3063.987 us; speedup vs baseline: 2.2779x; 1.5425x over previous
//
#include <hip/hip_runtime.h>
#include <math.h>

#define T_   4
#define B_   32
#define C_   384
#define N_   196
#define HID_ 1536
#define NH_  12
#define DH_  32
#define NCOL (B_*N_)            // 6272 columns j=(b,n)
#define THRESH 4e-3f            // f32/MFMA certainty margin (worst-case est ~1e-4)
#define FCAP (1u<<17)

typedef unsigned char u8;
typedef unsigned int  u32;
using bf16x8 = __attribute__((ext_vector_type(8))) short;
using f32x4  = __attribute__((ext_vector_type(4))) float;

__device__ __forceinline__ float bfbits2f(short u) {
    union { u32 i; float f; } c; c.i = ((u32)(unsigned short)u) << 16; return c.f;
}
__device__ __forceinline__ short f2bf(float f) {       // RNE f32 -> bf16 bits
    u32 b = __float_as_uint(f);
    return (short)((b + 0x7FFFu + ((b >> 16) & 1u)) >> 16);
}

__global__ void zero_counters(u32* cnt) { if (threadIdx.x < 4) cnt[threadIdx.x] = 0; }

// ---------------------------------------------------------------------------
// Weight split: W(f32) -> hi,lo bf16 (hi = bf16(w), lo = bf16(w - hi))
// ---------------------------------------------------------------------------
__global__ void wprep(const float* __restrict__ W, short* __restrict__ H,
                      short* __restrict__ L, int n)
{
    int i = blockIdx.x * 256 + threadIdx.x;
    if (i >= n) return;
    float f = W[i];
    short h = f2bf(f);
    H[i] = h;
    L[i] = f2bf(f - bfbits2f(h));
}

// ---------------------------------------------------------------------------
// Transpose [tb][c][n] -> [tb*196+n][c] with bf16 split.
// MODE 0: f32 src (+optional u8 add) -> hi+lo.  MODE 1: u8 spikes -> hi only.
// LDS-tiled: reads and writes both coalesced.
// ---------------------------------------------------------------------------
template<int MODE>
__global__ __launch_bounds__(256) void tpose(
    const void* __restrict__ src, const u8* __restrict__ Sadd,
    short* __restrict__ H, short* __restrict__ L, int c_tot, int nct)
{
    __shared__ float lds[64][197];
    const int tid = threadIdx.x;
    const int tb = blockIdx.x / nct;
    const int ct = blockIdx.x % nct;
    const float* Xf = (const float*)src;
    const u8*    Xb = (const u8*)src;
    for (int i = tid; i < 64 * N_; i += 256) {
        int c = i / N_, n = i % N_;
        size_t g = ((size_t)tb * c_tot + ct * 64 + c) * N_ + n;
        float v;
        if (MODE == 0) { v = Xf[g]; if (Sadd) v += (float)Sadd[g]; }
        else            v = (float)Xb[g];
        lds[c][n] = v;
    }
    __syncthreads();
    for (int i = tid; i < 64 * N_; i += 256) {
        int n = i / 64, c = i % 64;
        float f = lds[c][n];
        short h = f2bf(f);
        size_t o = ((size_t)tb * N_ + n) * c_tot + ct * 64 + c;
        H[o] = h;
        if (MODE == 0) L[o] = f2bf(f - bfbits2f(h));
    }
}

// ---------------------------------------------------------------------------
// MFMA GEMM + BN + LIF + flagging.  C[o,j,t] = sum_c W[o,c] X[t,j,c]
// A = W (hi/lo), B = XT (hi/lo or exact-spike hi).  16x16x32 bf16 MFMA.
// Block: 64o x 64m; 4 waves split m (16 cols each).  SPLITS = B-side splits.
// A-frag: row = lane&15, k = (lane>>4)*8+i ; B-frag: col = lane&15, same k.
// D: col = lane&15, row = (lane>>4)*4 + reg  [m89-verified].
// ---------------------------------------------------------------------------
template<int SPLITS, int OM, int NZ>
__global__ __launch_bounds__(256) void gemm_lif(
    const short* __restrict__ BH, const short* __restrict__ BL,
    const short* __restrict__ WH0, const short* __restrict__ WH1, const short* __restrict__ WH2,
    const short* __restrict__ WL0, const short* __restrict__ WL1, const short* __restrict__ WL2,
    const float* __restrict__ cb0, const float* __restrict__ cb1, const float* __restrict__ cb2,
    const float* __restrict__ bn0, const float* __restrict__ bn1, const float* __restrict__ bn2,
    const float* __restrict__ lw0, const float* __restrict__ lw1, const float* __restrict__ lw2,
    u8* S0, u8* S1, u8* S2,
    const float* __restrict__ xres, const u8* __restrict__ sres, float* __restrict__ out,
    u32* __restrict__ cnt, u32* __restrict__ flags,
    int c_out, int c_in, int nob)
{
    const int tid = threadIdx.x;
    const int w = tid >> 6, l = tid & 63;
    const int id = blockIdx.x;
    const int mt  = id / (nob * NZ);
    const int rem = id % (nob * NZ);
    const int z  = (NZ == 1) ? 0 : (rem % NZ);
    const int ob = (NZ == 1) ? rem : (rem / NZ);

    const short* WH = (z == 0) ? WH0 : ((z == 1) ? WH1 : WH2);
    const short* WL = (z == 0) ? WL0 : ((z == 1) ? WL1 : WL2);
    const float* cb  = (z == 0) ? cb0 : ((z == 1) ? cb1 : cb2);
    const float* bnp = (z == 0) ? bn0 : ((z == 1) ? bn1 : bn2);
    const float* lw  = (z == 0) ? lw0 : ((z == 1) ? lw1 : lw2);
    u8* SOUT         = (z == 0) ? S0  : ((z == 1) ? S1  : S2);

    const int j    = mt * 64 + w * 16 + (l & 15);
    const int kg   = (l >> 4) * 8;
    const int ob64 = ob * 64;
    const size_t tstr = (size_t)NCOL * c_in;

    f32x4 acc[4][4];
#pragma unroll
    for (int t = 0; t < 4; ++t)
#pragma unroll
        for (int os = 0; os < 4; ++os)
            acc[t][os] = (f32x4){0.f, 0.f, 0.f, 0.f};

    const short* bhp = BH + (size_t)j * c_in + kg;
    const short* blp = (SPLITS == 2) ? (BL + (size_t)j * c_in + kg) : nullptr;
    const short* ahp = WH + (size_t)(ob64 + (l & 15)) * c_in + kg;
    const short* alp = WL + (size_t)(ob64 + (l & 15)) * c_in + kg;

    for (int kc = 0; kc < c_in; kc += 32) {
        bf16x8 bh[4], bl[4];
#pragma unroll
        for (int t = 0; t < 4; ++t) {
            bh[t] = *(const bf16x8*)(bhp + (size_t)t * tstr + kc);
            if (SPLITS == 2) bl[t] = *(const bf16x8*)(blp + (size_t)t * tstr + kc);
        }
#pragma unroll
        for (int os = 0; os < 4; ++os) {
            const bf16x8 ah = *(const bf16x8*)(ahp + (size_t)os * 16 * c_in + kc);
            const bf16x8 al = *(const bf16x8*)(alp + (size_t)os * 16 * c_in + kc);
#pragma unroll
            for (int t = 0; t < 4; ++t) {
                acc[t][os] = __builtin_amdgcn_mfma_f32_16x16x32_bf16(ah, bh[t], acc[t][os], 0, 0, 0);
                acc[t][os] = __builtin_amdgcn_mfma_f32_16x16x32_bf16(al, bh[t], acc[t][os], 0, 0, 0);
                if (SPLITS == 2) {
                    acc[t][os] = __builtin_amdgcn_mfma_f32_16x16x32_bf16(ah, bl[t], acc[t][os], 0, 0, 0);
                    acc[t][os] = __builtin_amdgcn_mfma_f32_16x16x32_bf16(al, bl[t], acc[t][os], 0, 0, 0);
                }
            }
        }
    }

    const float tau = 1.0f / (1.0f + expf(-lw[0]));
    const size_t per_t = (size_t)B_ * c_out * N_;
    const int jb = j / N_, jn = j % N_;
#pragma unroll
    for (int os = 0; os < 4; ++os) {
#pragma unroll
        for (int r = 0; r < 4; ++r) {
            const int o = ob64 + os * 16 + (l >> 4) * 4 + r;
            const float g  = bnp[o];
            const float be = bnp[c_out + o];
            const float mm = bnp[2 * c_out + o];
            const float vv = bnp[3 * c_out + o];
            const float inv   = g / sqrtf(vv + 1e-5f);
            const float shift = be - mm * inv;
            const float cbv   = cb ? cb[o] : 0.0f;
            const size_t idx0 = ((size_t)jb * c_out + o) * N_ + jn;
            float v = 0.0f;
            bool flag = false;
#pragma unroll
            for (int t = 0; t < 4; ++t) {
                const float yv = (acc[t][os][r] + cbv) * inv + shift;
                const float h  = v + (yv - v) * tau;
                const float sp = (h >= 1.0f) ? 1.0f : 0.0f;
                flag = flag || (fabsf(h - 1.0f) < THRESH);
                v = h * (1.0f - sp);
                const size_t idx = (size_t)t * per_t + idx0;
                if (OM == 0) SOUT[idx] = (u8)sp;
                else out[idx] = (float)((double)xres[idx] + (double)sres[idx] + (double)sp);
            }
            if (flag) {
                u32 p = atomicAdd(cnt, 1u);
                if (p < FCAP) flags[p] = ((u32)(z * c_out + o)) * (u32)NCOL + (u32)j;
            }
        }
    }
}

// ---------------------------------------------------------------------------
// f64 fixup (r7-proven, verbatim): one wave per flagged (z,o,col) record.
// ---------------------------------------------------------------------------
template<int IN_MODE, int OM>
__global__ __launch_bounds__(256) void fixup_kernel(
    const void* __restrict__ Xv, const u8* __restrict__ Sadd,
    const float* __restrict__ W0, const float* __restrict__ W1, const float* __restrict__ W2,
    const float* __restrict__ cb0, const float* __restrict__ cb1, const float* __restrict__ cb2,
    const float* __restrict__ bn0, const float* __restrict__ bn1, const float* __restrict__ bn2,
    const float* __restrict__ lw0, const float* __restrict__ lw1, const float* __restrict__ lw2,
    u8* S0, u8* S1, u8* S2,
    const float* __restrict__ xres, const u8* __restrict__ sres, float* out,
    const u32* __restrict__ cnt, const u32* __restrict__ flags,
    int c_out, int c_in)
{
    const int lane = threadIdx.x & 63;
    const int wid  = (blockIdx.x * 256 + threadIdx.x) >> 6;
    const int nw   = (gridDim.x * 256) >> 6;
    u32 nrec = *cnt;
    if (nrec > FCAP) nrec = FCAP;

    const float* Xf = (const float*)Xv;
    const u8*    Xb = (const u8*)Xv;

    for (u32 r = wid; r < nrec; r += nw) {
        const u32 rec = flags[r];
        const int col = (int)(rec % (u32)NCOL);
        const u32 zo  = rec / (u32)NCOL;
        const int z   = (int)(zo / (u32)c_out);
        const int o   = (int)(zo % (u32)c_out);

        const float* W   = (z == 0) ? W0  : ((z == 1) ? W1  : W2);
        const float* cb  = (z == 0) ? cb0 : ((z == 1) ? cb1 : cb2);
        const float* bnp = (z == 0) ? bn0 : ((z == 1) ? bn1 : bn2);
        const float* lw  = (z == 0) ? lw0 : ((z == 1) ? lw1 : lw2);
        u8* SOUT         = (z == 0) ? S0  : ((z == 1) ? S1  : S2);

        const int b = col / N_, nn = col % N_;
        double acc[4] = {0.0, 0.0, 0.0, 0.0};
        for (int c = lane; c < c_in; c += 64) {
            const double w = (double)W[(size_t)o * c_in + c];
#pragma unroll
            for (int t = 0; t < 4; ++t) {
                const size_t i = ((size_t)(t * B_ + b) * c_in + c) * N_ + nn;
                double xval;
                if (IN_MODE == 0)      xval = (double)Xf[i];
                else if (IN_MODE == 1) xval = (double)Xb[i];
                else                   xval = (double)Xf[i] + (double)Sadd[i];
                acc[t] = fma(w, xval, acc[t]);
            }
        }
#pragma unroll
        for (int m = 32; m; m >>= 1) {
#pragma unroll
            for (int t = 0; t < 4; ++t)
                acc[t] += __shfl_xor(acc[t], m, 64);
        }

        if (lane == 0) {
            const double tau = 1.0 / (1.0 + exp(-(double)lw[0]));
            const double g  = (double)bnp[o];
            const double be = (double)bnp[c_out + o];
            const double mm = (double)bnp[2 * c_out + o];
            const double vv = (double)bnp[3 * c_out + o];
            const double inv   = g / sqrt(vv + 1e-5);
            const double shift = be - mm * inv;
            const double cbv   = cb ? (double)cb[o] : 0.0;
            const size_t per_t = (size_t)B_ * c_out * N_;
            const size_t idx0  = ((size_t)b * c_out + o) * N_ + nn;
            double v = 0.0;
#pragma unroll
            for (int t = 0; t < 4; ++t) {
                const double yv = (acc[t] + cbv) * inv + shift;
                const double h  = v + (yv - v) * tau;
                const double sp = (h >= 1.0) ? 1.0 : 0.0;
                v = h * (1.0 - sp);
                const size_t idx = (size_t)t * per_t + idx0;
                if (OM == 0) SOUT[idx] = (u8)sp;
                else out[idx] = (float)((double)xres[idx] + (double)sres[idx] + sp);
            }
        }
    }
}

// ---------------------------------------------------------------------------
// Spike attention + fused LIF (exact dyadic arithmetic, r5/r7-proven).
// ---------------------------------------------------------------------------
__global__ __launch_bounds__(256) void attn_lif_kernel(
    const u8* __restrict__ SQ, const u8* __restrict__ SK, const u8* __restrict__ SV,
    u8* __restrict__ SATT, const float* __restrict__ lw)
{
    __shared__ u8 q_lds[DH_ * N_];
    __shared__ u8 k_lds[DH_ * N_];
    __shared__ u8 v_lds[DH_ * N_];
    __shared__ float kv_lds[DH_ * DH_];
    __shared__ float vstate[DH_ * N_];
    const int tid = threadIdx.x;
    const int b = blockIdx.x / NH_, h = blockIdx.x % NH_;
    const float tau = 1.0f / (1.0f + expf(-lw[0]));

    for (int i = tid; i < DH_ * N_; i += 256) vstate[i] = 0.0f;

    for (int t = 0; t < T_; ++t) {
        const size_t base = ((size_t)((t * B_ + b) * C_) + h * DH_) * N_;
        __syncthreads();
        for (int i = tid; i < DH_ * N_ / 4; i += 256) {
            ((unsigned int*)q_lds)[i] = ((const unsigned int*)(SQ + base))[i];
            ((unsigned int*)k_lds)[i] = ((const unsigned int*)(SK + base))[i];
            ((unsigned int*)v_lds)[i] = ((const unsigned int*)(SV + base))[i];
        }
        __syncthreads();

#pragma unroll
        for (int r = 0; r < 4; ++r) {
            const int e = tid + 256 * r;
            const int i = e >> 5, jj = e & 31;
            int s = 0;
            for (int nn = 0; nn < N_; nn += 4) {
                uchar4 kk = *(const uchar4*)&k_lds[i * N_ + nn];
                uchar4 uv = *(const uchar4*)&v_lds[jj * N_ + nn];
                s += kk.x * uv.x + kk.y * uv.y + kk.z * uv.z + kk.w * uv.w;
            }
            kv_lds[e] = (float)s;
        }
        __syncthreads();

        for (int e = tid; e < DH_ * N_; e += 256) {
            const int jj = e / N_, nn = e % N_;
            float s = 0.0f;
#pragma unroll
            for (int i = 0; i < DH_; ++i)
                s += q_lds[i * N_ + nn] ? kv_lds[i * DH_ + jj] : 0.0f;
            const float att = 0.125f * s;
            const float v = vstate[e];
            const float hh = v + (att - v) * tau;
            const float sp = (hh >= 1.0f) ? 1.0f : 0.0f;
            vstate[e] = hh * (1.0f - sp);
            SATT[base + e] = (u8)sp;
        }
    }
}

// ---------------------------------------------------------------------------
extern "C" void kernel_launch(void* const* d_in, const int* in_sizes, int n_in,
                              void* d_out, int out_size, void* d_ws, size_t ws_size,
                              hipStream_t stream)
{
    const float* x       = (const float*)d_in[0];
    const float* q_w     = (const float*)d_in[1];
    const float* q_bn    = (const float*)d_in[2];
    const float* q_lw    = (const float*)d_in[3];
    const float* k_w     = (const float*)d_in[4];
    const float* k_bn    = (const float*)d_in[5];
    const float* k_lw    = (const float*)d_in[6];
    const float* v_w     = (const float*)d_in[7];
    const float* v_bn    = (const float*)d_in[8];
    const float* v_lw    = (const float*)d_in[9];
    const float* attn_lw = (const float*)d_in[10];
    const float* proj_w  = (const float*)d_in[11];
    const float* proj_b  = (const float*)d_in[12];
    const float* proj_bn = (const float*)d_in[13];
    const float* proj_lw = (const float*)d_in[14];
    const float* fc1_w   = (const float*)d_in[15];
    const float* fc1_b   = (const float*)d_in[16];
    const float* fc1_bn  = (const float*)d_in[17];
    const float* fc1_lw  = (const float*)d_in[18];
    const float* fc2_w   = (const float*)d_in[19];
    const float* fc2_b   = (const float*)d_in[20];
    const float* fc2_bn  = (const float*)d_in[21];
    const float* fc2_lw  = (const float*)d_in[22];

    // ---- workspace layout (~134.4 MB), region A phase-aliased ----
    u8* base = (u8*)d_ws;
    short* XT_h   = (short*)(base);                 // phase 1: 19,267,584 B
    short* XT_l   = (short*)(base + 19267584);      // 19,267,584 B
    u8*    SQ     = base + 38535168;                // 9,633,792 each
    u8*    SK     = base + 48168960;
    u8*    SV     = base + 57802752;
    u8*    SATT   = base + 67436544;                // ends 77,070,336
    short* SATT_T = (short*)(base + 38535168);      // phase 1.5 (over SQ..SV)
    short* SZT    = (short*)(base);                 // phase 2: 77,070,336 B
    u8*    SP     = base + 77070336;                // 9,633,792
    u8*    SZ     = base + 86704128;                // 38,535,168
    u32*   cnt    = (u32*)(base + 125239296);       // 256 B
    u32*   flags  = (u32*)(base + 125239552);       // 4 * FCAP * 4 = 2,097,152
    short* WHb    = (short*)(base + 127336704);     // 1,769,472 shorts
    short* WLb    = (short*)(base + 130875648);     // 1,769,472 shorts
    float* out = (float*)d_out;

    short *WHq = WHb,          *WHk = WHb + 147456, *WHv = WHb + 294912,
          *WHp = WHb + 442368, *WH1 = WHb + 589824, *WH2 = WHb + 1179648;
    short *WLq = WLb,          *WLk = WLb + 147456, *WLv = WLb + 294912,
          *WLp = WLb + 442368, *WL1 = WLb + 589824, *WL2 = WLb + 1179648;
    u32 *flQ = flags, *flP = flags + FCAP, *fl1 = flags + 2 * FCAP, *fl2 = flags + 3 * FCAP;

    zero_counters<<<1, 64, 0, stream>>>(cnt);

    // 0. weight splits
    wprep<<<576, 256, 0, stream>>>(q_w,    WHq, WLq, 147456);
    wprep<<<576, 256, 0, stream>>>(k_w,    WHk, WLk, 147456);
    wprep<<<576, 256, 0, stream>>>(v_w,    WHv, WLv, 147456);
    wprep<<<576, 256, 0, stream>>>(proj_w, WHp, WLp, 147456);
    wprep<<<2304, 256, 0, stream>>>(fc1_w, WH1, WL1, 589824);
    wprep<<<2304, 256, 0, stream>>>(fc2_w, WH2, WL2, 589824);

    // 1. x -> XT (hi/lo), then fused q/k/v MFMA GEMM + LIF, then f64 fixup
    tpose<0><<<128 * 6, 256, 0, stream>>>(x, nullptr, XT_h, XT_l, C_, 6);
    gemm_lif<2, 0, 3><<<98 * 6 * 3, 256, 0, stream>>>(
        XT_h, XT_l, WHq, WHk, WHv, WLq, WLk, WLv,
        nullptr, nullptr, nullptr, q_bn, k_bn, v_bn, q_lw, k_lw, v_lw,
        SQ, SK, SV, nullptr, nullptr, nullptr, cnt + 0, flQ, C_, C_, 6);
    fixup_kernel<0, 0><<<512, 256, 0, stream>>>(
        x, nullptr, q_w, k_w, v_w, nullptr, nullptr, nullptr,
        q_bn, k_bn, v_bn, q_lw, k_lw, v_lw,
        SQ, SK, SV, nullptr, nullptr, nullptr, cnt + 0, flQ, C_, C_);

    // 2. attention + LIF (exact)
    attn_lif_kernel<<<B_ * NH_, 256, 0, stream>>>(SQ, SK, SV, SATT, attn_lw);

    // 3. proj: SATT -> SATT_T (exact bf16), GEMM (B exact), fixup
    tpose<1><<<128 * 6, 256, 0, stream>>>(SATT, nullptr, SATT_T, nullptr, C_, 6);
    gemm_lif<1, 0, 1><<<98 * 6, 256, 0, stream>>>(
        SATT_T, nullptr, WHp, WHp, WHp, WLp, WLp, WLp,
        proj_b, proj_b, proj_b, proj_bn, proj_bn, proj_bn, proj_lw, proj_lw, proj_lw,
        SP, SP, SP, nullptr, nullptr, nullptr, cnt + 1, flP, C_, C_, 6);
    fixup_kernel<1, 0><<<512, 256, 0, stream>>>(
        SATT, nullptr, proj_w, proj_w, proj_w, proj_b, proj_b, proj_b,
        proj_bn, proj_bn, proj_bn, proj_lw, proj_lw, proj_lw,
        SP, SP, SP, nullptr, nullptr, nullptr, cnt + 1, flP, C_, C_);

    // 4. fc1: (x + SP) -> XT (hi/lo), GEMM, fixup
    tpose<0><<<128 * 6, 256, 0, stream>>>(x, SP, XT_h, XT_l, C_, 6);
    gemm_lif<2, 0, 1><<<98 * 24, 256, 0, stream>>>(
        XT_h, XT_l, WH1, WH1, WH1, WL1, WL1, WL1,
        fc1_b, fc1_b, fc1_b, fc1_bn, fc1_bn, fc1_bn, fc1_lw, fc1_lw, fc1_lw,
        SZ, SZ, SZ, nullptr, nullptr, nullptr, cnt + 2, fl1, HID_, C_, 24);
    fixup_kernel<2, 0><<<512, 256, 0, stream>>>(
        x, SP, fc1_w, fc1_w, fc1_w, fc1_b, fc1_b, fc1_b,
        fc1_bn, fc1_bn, fc1_bn, fc1_lw, fc1_lw, fc1_lw,
        SZ, SZ, SZ, nullptr, nullptr, nullptr, cnt + 2, fl1, HID_, C_);

    // 5. fc2: SZ -> SZT (exact bf16, over region A), GEMM -> out, fixup
    tpose<1><<<128 * 24, 256, 0, stream>>>(SZ, nullptr, SZT, nullptr, HID_, 24);
    gemm_lif<1, 1, 1><<<98 * 6, 256, 0, stream>>>(
        SZT, nullptr, WH2, WH2, WH2, WL2, WL2, WL2,
        fc2_b, fc2_b, fc2_b, fc2_bn, fc2_bn, fc2_bn, fc2_lw, fc2_lw, fc2_lw,
        nullptr, nullptr, nullptr, x, SP, out, cnt + 3, fl2, C_, HID_, 6);
    fixup_kernel<1, 1><<<512, 256, 0, stream>>>(
        SZ, nullptr, fc2_w, fc2_w, fc2_w, fc2_b, fc2_b, fc2_b,
        fc2_bn, fc2_bn, fc2_bn, fc2_lw, fc2_lw, fc2_lw,
        nullptr, nullptr, nullptr, x, SP, out, cnt + 3, fl2, C_, HID_);
}

// Round 9
// 1448.100 us; speedup vs baseline: 4.8197x; 2.1159x over previous
//
#include <hip/hip_runtime.h>
#include <math.h>

#define T_   4
#define B_   32
#define C_   384
#define N_   196
#define HID_ 1536
#define NH_  12
#define DH_  32
#define NCOL (B_*N_)            // 6272 columns j=(b,n)
#define THRESH 2e-3f            // certainty margin (worst-case MFMA-path err ~2.5e-4)
#define FCAP (1u<<17)

typedef unsigned char u8;
typedef unsigned int  u32;
using bf16x8 = __attribute__((ext_vector_type(8))) short;
using f32x4  = __attribute__((ext_vector_type(4))) float;

__device__ __forceinline__ float bfbits2f(short u) {
    union { u32 i; float f; } c; c.i = ((u32)(unsigned short)u) << 16; return c.f;
}
__device__ __forceinline__ short f2bf(float f) {       // RNE f32 -> bf16 bits
    u32 b = __float_as_uint(f);
    return (short)((b + 0x7FFFu + ((b >> 16) & 1u)) >> 16);
}

__global__ void zero_counters(u32* cnt) { if (threadIdx.x < 4) cnt[threadIdx.x] = 0; }

// ---------------------------------------------------------------------------
// Weight split: W(f32) -> hi,lo bf16 (hi = bf16(w), lo = bf16(w - hi))
// ---------------------------------------------------------------------------
__global__ void wprep(const float* __restrict__ W, short* __restrict__ H,
                      short* __restrict__ L, int n)
{
    int i = blockIdx.x * 256 + threadIdx.x;
    if (i >= n) return;
    float f = W[i];
    short h = f2bf(f);
    H[i] = h;
    L[i] = f2bf(f - bfbits2f(h));
}

// ---------------------------------------------------------------------------
// Transpose [tb][c][n] -> [tb*196+n][c].
// MODE 0: f32 src (+optional u8 Sadd) -> bf16 hi+lo of (x+s); optional exact
//         f32 copy F (of x+s; used with Sadd=null -> exact x) and u8 SPT copy.
// MODE 1: u8 spikes -> bf16 hi only (exact).
// LDS-tiled: global reads and writes both coalesced.
// ---------------------------------------------------------------------------
template<int MODE>
__global__ __launch_bounds__(256) void tpose(
    const void* __restrict__ src, const u8* __restrict__ Sadd,
    short* __restrict__ H, short* __restrict__ L,
    float* __restrict__ F, u8* __restrict__ SPTo,
    int c_tot, int nct)
{
    __shared__ float lds[64][197];
    __shared__ u8 slds[MODE == 0 ? 64 : 1][MODE == 0 ? 197 : 1];
    const int tid = threadIdx.x;
    const int tb = blockIdx.x / nct;
    const int ct = blockIdx.x % nct;
    const float* Xf = (const float*)src;
    const u8*    Xb = (const u8*)src;
    for (int i = tid; i < 64 * N_; i += 256) {
        int c = i / N_, n = i % N_;
        size_t g = ((size_t)tb * c_tot + ct * 64 + c) * N_ + n;
        if (MODE == 0) {
            float v = Xf[g];
            u8 s = Sadd ? Sadd[g] : (u8)0;
            lds[c][n] = v + (float)s;
            slds[c][n] = s;
        } else {
            lds[c][n] = (float)Xb[g];
        }
    }
    __syncthreads();
    for (int i = tid; i < 64 * N_; i += 256) {
        int n = i / 64, c = i % 64;
        float f = lds[c][n];
        short h = f2bf(f);
        size_t o = ((size_t)tb * N_ + n) * c_tot + ct * 64 + c;
        H[o] = h;
        if (MODE == 0) {
            L[o] = f2bf(f - bfbits2f(h));
            if (F)    F[o] = f;              // exact f32 (x, when Sadd null)
            if (SPTo) SPTo[o] = slds[c][n];  // exact spike
        }
    }
}

// ---------------------------------------------------------------------------
// MFMA GEMM + BN + LIF + flagging (r8-proven).  C[o,j,t] = sum_c W[o,c] X[t,j,c]
// Block: 64o x 64m; 4 waves split m.  SPLITS = B-side splits.
// D: col = lane&15, row = (lane>>4)*4 + reg  [m89-verified].
// ---------------------------------------------------------------------------
template<int SPLITS, int OM, int NZ>
__global__ __launch_bounds__(256) void gemm_lif(
    const short* __restrict__ BH, const short* __restrict__ BL,
    const short* __restrict__ WH0, const short* __restrict__ WH1, const short* __restrict__ WH2,
    const short* __restrict__ WL0, const short* __restrict__ WL1, const short* __restrict__ WL2,
    const float* __restrict__ cb0, const float* __restrict__ cb1, const float* __restrict__ cb2,
    const float* __restrict__ bn0, const float* __restrict__ bn1, const float* __restrict__ bn2,
    const float* __restrict__ lw0, const float* __restrict__ lw1, const float* __restrict__ lw2,
    u8* S0, u8* S1, u8* S2,
    const float* __restrict__ xres, const u8* __restrict__ sres, float* __restrict__ out,
    u32* __restrict__ cnt, u32* __restrict__ flags,
    int c_out, int c_in, int nob)
{
    const int tid = threadIdx.x;
    const int w = tid >> 6, l = tid & 63;
    const int id = blockIdx.x;
    const int mt  = id / (nob * NZ);
    const int rem = id % (nob * NZ);
    const int z  = (NZ == 1) ? 0 : (rem % NZ);
    const int ob = (NZ == 1) ? rem : (rem / NZ);

    const short* WH = (z == 0) ? WH0 : ((z == 1) ? WH1 : WH2);
    const short* WL = (z == 0) ? WL0 : ((z == 1) ? WL1 : WL2);
    const float* cb  = (z == 0) ? cb0 : ((z == 1) ? cb1 : cb2);
    const float* bnp = (z == 0) ? bn0 : ((z == 1) ? bn1 : bn2);
    const float* lw  = (z == 0) ? lw0 : ((z == 1) ? lw1 : lw2);
    u8* SOUT         = (z == 0) ? S0  : ((z == 1) ? S1  : S2);

    const int j    = mt * 64 + w * 16 + (l & 15);
    const int kg   = (l >> 4) * 8;
    const int ob64 = ob * 64;
    const size_t tstr = (size_t)NCOL * c_in;

    f32x4 acc[4][4];
#pragma unroll
    for (int t = 0; t < 4; ++t)
#pragma unroll
        for (int os = 0; os < 4; ++os)
            acc[t][os] = (f32x4){0.f, 0.f, 0.f, 0.f};

    const short* bhp = BH + (size_t)j * c_in + kg;
    const short* blp = (SPLITS == 2) ? (BL + (size_t)j * c_in + kg) : nullptr;
    const short* ahp = WH + (size_t)(ob64 + (l & 15)) * c_in + kg;
    const short* alp = WL + (size_t)(ob64 + (l & 15)) * c_in + kg;

    for (int kc = 0; kc < c_in; kc += 32) {
        bf16x8 bh[4], bl[4];
#pragma unroll
        for (int t = 0; t < 4; ++t) {
            bh[t] = *(const bf16x8*)(bhp + (size_t)t * tstr + kc);
            if (SPLITS == 2) bl[t] = *(const bf16x8*)(blp + (size_t)t * tstr + kc);
        }
#pragma unroll
        for (int os = 0; os < 4; ++os) {
            const bf16x8 ah = *(const bf16x8*)(ahp + (size_t)os * 16 * c_in + kc);
            const bf16x8 al = *(const bf16x8*)(alp + (size_t)os * 16 * c_in + kc);
#pragma unroll
            for (int t = 0; t < 4; ++t) {
                acc[t][os] = __builtin_amdgcn_mfma_f32_16x16x32_bf16(ah, bh[t], acc[t][os], 0, 0, 0);
                acc[t][os] = __builtin_amdgcn_mfma_f32_16x16x32_bf16(al, bh[t], acc[t][os], 0, 0, 0);
                if (SPLITS == 2) {
                    acc[t][os] = __builtin_amdgcn_mfma_f32_16x16x32_bf16(ah, bl[t], acc[t][os], 0, 0, 0);
                    acc[t][os] = __builtin_amdgcn_mfma_f32_16x16x32_bf16(al, bl[t], acc[t][os], 0, 0, 0);
                }
            }
        }
    }

    const float tau = 1.0f / (1.0f + expf(-lw[0]));
    const size_t per_t = (size_t)B_ * c_out * N_;
    const int jb = j / N_, jn = j % N_;
#pragma unroll
    for (int os = 0; os < 4; ++os) {
#pragma unroll
        for (int r = 0; r < 4; ++r) {
            const int o = ob64 + os * 16 + (l >> 4) * 4 + r;
            const float g  = bnp[o];
            const float be = bnp[c_out + o];
            const float mm = bnp[2 * c_out + o];
            const float vv = bnp[3 * c_out + o];
            const float inv   = g / sqrtf(vv + 1e-5f);
            const float shift = be - mm * inv;
            const float cbv   = cb ? cb[o] : 0.0f;
            const size_t idx0 = ((size_t)jb * c_out + o) * N_ + jn;
            float v = 0.0f;
            bool flag = false;
#pragma unroll
            for (int t = 0; t < 4; ++t) {
                const float yv = (acc[t][os][r] + cbv) * inv + shift;
                const float h  = v + (yv - v) * tau;
                const float sp = (h >= 1.0f) ? 1.0f : 0.0f;
                flag = flag || (fabsf(h - 1.0f) < THRESH);
                v = h * (1.0f - sp);
                const size_t idx = (size_t)t * per_t + idx0;
                if (OM == 0) SOUT[idx] = (u8)sp;
                else out[idx] = (float)((double)xres[idx] + (double)sres[idx] + (double)sp);
            }
            if (flag) {
                u32 p = atomicAdd(cnt, 1u);
                if (p < FCAP) flags[p] = ((u32)(z * c_out + o)) * (u32)NCOL + (u32)j;
            }
        }
    }
}

// ---------------------------------------------------------------------------
// f64 fixup on TRANSPOSED exact inputs (coalesced lane-over-c reads).
// IN_MODE: 0 = f32 XT [t*NCOL+j][c]; 1 = bf16 spike XT (exact);
//          2 = f32 XT + u8 SPT (x and spikes summed in f64 -> exact).
// Decision math identical to the r5/r7-proven all-f64 path.
// ---------------------------------------------------------------------------
template<int IN_MODE, int OM>
__global__ __launch_bounds__(256) void fixup_t(
    const void* __restrict__ XT, const u8* __restrict__ SPT,
    const float* __restrict__ W0, const float* __restrict__ W1, const float* __restrict__ W2,
    const float* __restrict__ cb0, const float* __restrict__ cb1, const float* __restrict__ cb2,
    const float* __restrict__ bn0, const float* __restrict__ bn1, const float* __restrict__ bn2,
    const float* __restrict__ lw0, const float* __restrict__ lw1, const float* __restrict__ lw2,
    u8* S0, u8* S1, u8* S2,
    const float* __restrict__ xres, const u8* __restrict__ sres, float* out,
    const u32* __restrict__ cnt, const u32* __restrict__ flags,
    int c_out, int c_in)
{
    const int lane = threadIdx.x & 63;
    const int wid  = (blockIdx.x * 256 + threadIdx.x) >> 6;
    const int nw   = (gridDim.x * 256) >> 6;
    u32 nrec = *cnt;
    if (nrec > FCAP) nrec = FCAP;

    const float* XTf = (const float*)XT;
    const short* XTs = (const short*)XT;

    for (u32 r = wid; r < nrec; r += nw) {
        const u32 rec = flags[r];
        const int j  = (int)(rec % (u32)NCOL);
        const u32 zo = rec / (u32)NCOL;
        const int z  = (int)(zo / (u32)c_out);
        const int o  = (int)(zo % (u32)c_out);

        const float* W   = (z == 0) ? W0  : ((z == 1) ? W1  : W2);
        const float* cb  = (z == 0) ? cb0 : ((z == 1) ? cb1 : cb2);
        const float* bnp = (z == 0) ? bn0 : ((z == 1) ? bn1 : bn2);
        const float* lw  = (z == 0) ? lw0 : ((z == 1) ? lw1 : lw2);
        u8* SOUT         = (z == 0) ? S0  : ((z == 1) ? S1  : S2);

        double acc[4] = {0.0, 0.0, 0.0, 0.0};
        for (int c = lane; c < c_in; c += 64) {
            const double w = (double)W[(size_t)o * c_in + c];
#pragma unroll
            for (int t = 0; t < 4; ++t) {
                const size_t i = ((size_t)(t * NCOL + j)) * c_in + c;
                double xval;
                if (IN_MODE == 0)      xval = (double)XTf[i];
                else if (IN_MODE == 1) xval = (double)bfbits2f(XTs[i]);
                else                   xval = (double)XTf[i] + (double)SPT[i];
                acc[t] = fma(w, xval, acc[t]);
            }
        }
#pragma unroll
        for (int m = 32; m; m >>= 1) {
#pragma unroll
            for (int t = 0; t < 4; ++t)
                acc[t] += __shfl_xor(acc[t], m, 64);
        }

        if (lane == 0) {
            const double tau = 1.0 / (1.0 + exp(-(double)lw[0]));
            const double g  = (double)bnp[o];
            const double be = (double)bnp[c_out + o];
            const double mm = (double)bnp[2 * c_out + o];
            const double vv = (double)bnp[3 * c_out + o];
            const double inv   = g / sqrt(vv + 1e-5);
            const double shift = be - mm * inv;
            const double cbv   = cb ? (double)cb[o] : 0.0;
            const size_t per_t = (size_t)B_ * c_out * N_;
            const int jb = j / N_, jn = j % N_;
            const size_t idx0  = ((size_t)jb * c_out + o) * N_ + jn;
            double v = 0.0;
#pragma unroll
            for (int t = 0; t < 4; ++t) {
                const double yv = (acc[t] + cbv) * inv + shift;
                const double h  = v + (yv - v) * tau;
                const double sp = (h >= 1.0) ? 1.0 : 0.0;
                v = h * (1.0 - sp);
                const size_t idx = (size_t)t * per_t + idx0;
                if (OM == 0) SOUT[idx] = (u8)sp;
                else out[idx] = (float)((double)xres[idx] + (double)sres[idx] + sp);
            }
        }
    }
}

// ---------------------------------------------------------------------------
// Spike attention + fused LIF (exact dyadic arithmetic, r5-r8 proven).
// ---------------------------------------------------------------------------
__global__ __launch_bounds__(256) void attn_lif_kernel(
    const u8* __restrict__ SQ, const u8* __restrict__ SK, const u8* __restrict__ SV,
    u8* __restrict__ SATT, const float* __restrict__ lw)
{
    __shared__ u8 q_lds[DH_ * N_];
    __shared__ u8 k_lds[DH_ * N_];
    __shared__ u8 v_lds[DH_ * N_];
    __shared__ float kv_lds[DH_ * DH_];
    __shared__ float vstate[DH_ * N_];
    const int tid = threadIdx.x;
    const int b = blockIdx.x / NH_, h = blockIdx.x % NH_;
    const float tau = 1.0f / (1.0f + expf(-lw[0]));

    for (int i = tid; i < DH_ * N_; i += 256) vstate[i] = 0.0f;

    for (int t = 0; t < T_; ++t) {
        const size_t base = ((size_t)((t * B_ + b) * C_) + h * DH_) * N_;
        __syncthreads();
        for (int i = tid; i < DH_ * N_ / 4; i += 256) {
            ((unsigned int*)q_lds)[i] = ((const unsigned int*)(SQ + base))[i];
            ((unsigned int*)k_lds)[i] = ((const unsigned int*)(SK + base))[i];
            ((unsigned int*)v_lds)[i] = ((const unsigned int*)(SV + base))[i];
        }
        __syncthreads();

#pragma unroll
        for (int r = 0; r < 4; ++r) {
            const int e = tid + 256 * r;
            const int i = e >> 5, jj = e & 31;
            int s = 0;
            for (int nn = 0; nn < N_; nn += 4) {
                uchar4 kk = *(const uchar4*)&k_lds[i * N_ + nn];
                uchar4 uv = *(const uchar4*)&v_lds[jj * N_ + nn];
                s += kk.x * uv.x + kk.y * uv.y + kk.z * uv.z + kk.w * uv.w;
            }
            kv_lds[e] = (float)s;
        }
        __syncthreads();

        for (int e = tid; e < DH_ * N_; e += 256) {
            const int jj = e / N_, nn = e % N_;
            float s = 0.0f;
#pragma unroll
            for (int i = 0; i < DH_; ++i)
                s += q_lds[i * N_ + nn] ? kv_lds[i * DH_ + jj] : 0.0f;
            const float att = 0.125f * s;
            const float v = vstate[e];
            const float hh = v + (att - v) * tau;
            const float sp = (hh >= 1.0f) ? 1.0f : 0.0f;
            vstate[e] = hh * (1.0f - sp);
            SATT[base + e] = (u8)sp;
        }
    }
}

// ---------------------------------------------------------------------------
extern "C" void kernel_launch(void* const* d_in, const int* in_sizes, int n_in,
                              void* d_out, int out_size, void* d_ws, size_t ws_size,
                              hipStream_t stream)
{
    const float* x       = (const float*)d_in[0];
    const float* q_w     = (const float*)d_in[1];
    const float* q_bn    = (const float*)d_in[2];
    const float* q_lw    = (const float*)d_in[3];
    const float* k_w     = (const float*)d_in[4];
    const float* k_bn    = (const float*)d_in[5];
    const float* k_lw    = (const float*)d_in[6];
    const float* v_w     = (const float*)d_in[7];
    const float* v_bn    = (const float*)d_in[8];
    const float* v_lw    = (const float*)d_in[9];
    const float* attn_lw = (const float*)d_in[10];
    const float* proj_w  = (const float*)d_in[11];
    const float* proj_b  = (const float*)d_in[12];
    const float* proj_bn = (const float*)d_in[13];
    const float* proj_lw = (const float*)d_in[14];
    const float* fc1_w   = (const float*)d_in[15];
    const float* fc1_b   = (const float*)d_in[16];
    const float* fc1_bn  = (const float*)d_in[17];
    const float* fc1_lw  = (const float*)d_in[18];
    const float* fc2_w   = (const float*)d_in[19];
    const float* fc2_b   = (const float*)d_in[20];
    const float* fc2_bn  = (const float*)d_in[21];
    const float* fc2_lw  = (const float*)d_in[22];

    // ---- workspace layout (~154 MB), phase-aliased ----
    u8* base = (u8*)d_ws;
    float* XTf32  = (float*)(base);                 // [0, 38.5M)   ph1-4
    short* XT_h   = (short*)(base + 38535168);      // [38.5, 57.8) ph1&4
    short* XT_l   = (short*)(base + 57802752);      // [57.8, 77.1) ph1&4
    short* SZT    = (short*)(base);                 // [0, 77.1)    ph5 (overlay)
    u8*    SQ     = base + 77070336;                // 9,633,792 each, ph1-2
    u8*    SK     = base + 86704128;
    u8*    SV     = base + 96337920;
    u8*    SATT   = base + 105971712;               // ph2-3, ends 115.6M
    u8*    SZ     = base + 77070336;                // ph4-5 (overlays SQ..SATT)
    short* SATT_T = (short*)(base + 115605504);     // 19.3M, ph3
    u8*    SPT    = base + 115605504;               // 9.6M,  ph4 (overlay)
    u8*    SP     = base + 134873088;               // 9.6M,  ph3-5
    u32*   cnt    = (u32*)(base + 144506880);       // 256 B
    u32*   flags  = (u32*)(base + 144507136);       // 4*FCAP*4 = 2.1M
    short* WHb    = (short*)(base + 146604288);     // 3.54M
    short* WLb    = (short*)(base + 150143232);     // 3.54M -> ends ~153.7M
    float* out = (float*)d_out;

    short *WHq = WHb,          *WHk = WHb + 147456, *WHv = WHb + 294912,
          *WHp = WHb + 442368, *WH1 = WHb + 589824, *WH2 = WHb + 1179648;
    short *WLq = WLb,          *WLk = WLb + 147456, *WLv = WLb + 294912,
          *WLp = WLb + 442368, *WL1 = WLb + 589824, *WL2 = WLb + 1179648;
    u32 *flQ = flags, *flP = flags + FCAP, *fl1 = flags + 2 * FCAP, *fl2 = flags + 3 * FCAP;

    zero_counters<<<1, 64, 0, stream>>>(cnt);

    // 0. weight splits
    wprep<<<576, 256, 0, stream>>>(q_w,    WHq, WLq, 147456);
    wprep<<<576, 256, 0, stream>>>(k_w,    WHk, WLk, 147456);
    wprep<<<576, 256, 0, stream>>>(v_w,    WHv, WLv, 147456);
    wprep<<<576, 256, 0, stream>>>(proj_w, WHp, WLp, 147456);
    wprep<<<2304, 256, 0, stream>>>(fc1_w, WH1, WL1, 589824);
    wprep<<<2304, 256, 0, stream>>>(fc2_w, WH2, WL2, 589824);

    // 1. x -> XT hi/lo + exact XTf32; fused q/k/v GEMM+LIF; coalesced f64 fixup
    tpose<0><<<128 * 6, 256, 0, stream>>>(x, nullptr, XT_h, XT_l, XTf32, nullptr, C_, 6);
    gemm_lif<2, 0, 3><<<98 * 6 * 3, 256, 0, stream>>>(
        XT_h, XT_l, WHq, WHk, WHv, WLq, WLk, WLv,
        nullptr, nullptr, nullptr, q_bn, k_bn, v_bn, q_lw, k_lw, v_lw,
        SQ, SK, SV, nullptr, nullptr, nullptr, cnt + 0, flQ, C_, C_, 6);
    fixup_t<0, 0><<<512, 256, 0, stream>>>(
        XTf32, nullptr, q_w, k_w, v_w, nullptr, nullptr, nullptr,
        q_bn, k_bn, v_bn, q_lw, k_lw, v_lw,
        SQ, SK, SV, nullptr, nullptr, nullptr, cnt + 0, flQ, C_, C_);

    // 2. attention + LIF (exact)
    attn_lif_kernel<<<B_ * NH_, 256, 0, stream>>>(SQ, SK, SV, SATT, attn_lw);

    // 3. proj: SATT -> SATT_T (exact bf16); GEMM; fixup reads SATT_T
    tpose<1><<<128 * 6, 256, 0, stream>>>(SATT, nullptr, SATT_T, nullptr, nullptr, nullptr, C_, 6);
    gemm_lif<1, 0, 1><<<98 * 6, 256, 0, stream>>>(
        SATT_T, nullptr, WHp, WHp, WHp, WLp, WLp, WLp,
        proj_b, proj_b, proj_b, proj_bn, proj_bn, proj_bn, proj_lw, proj_lw, proj_lw,
        SP, SP, SP, nullptr, nullptr, nullptr, cnt + 1, flP, C_, C_, 6);
    fixup_t<1, 0><<<512, 256, 0, stream>>>(
        SATT_T, nullptr, proj_w, proj_w, proj_w, proj_b, proj_b, proj_b,
        proj_bn, proj_bn, proj_bn, proj_lw, proj_lw, proj_lw,
        SP, SP, SP, nullptr, nullptr, nullptr, cnt + 1, flP, C_, C_);

    // 4. fc1: (x+SP) -> XT hi/lo + SPT; GEMM; fixup reads XTf32 + SPT
    tpose<0><<<128 * 6, 256, 0, stream>>>(x, SP, XT_h, XT_l, nullptr, SPT, C_, 6);
    gemm_lif<2, 0, 1><<<98 * 24, 256, 0, stream>>>(
        XT_h, XT_l, WH1, WH1, WH1, WL1, WL1, WL1,
        fc1_b, fc1_b, fc1_b, fc1_bn, fc1_bn, fc1_bn, fc1_lw, fc1_lw, fc1_lw,
        SZ, SZ, SZ, nullptr, nullptr, nullptr, cnt + 2, fl1, HID_, C_, 24);
    fixup_t<2, 0><<<512, 256, 0, stream>>>(
        XTf32, SPT, fc1_w, fc1_w, fc1_w, fc1_b, fc1_b, fc1_b,
        fc1_bn, fc1_bn, fc1_bn, fc1_lw, fc1_lw, fc1_lw,
        SZ, SZ, SZ, nullptr, nullptr, nullptr, cnt + 2, fl1, HID_, C_);

    // 5. fc2: SZ -> SZT (exact bf16, overlays region A); GEMM -> out; fixup
    tpose<1><<<128 * 24, 256, 0, stream>>>(SZ, nullptr, SZT, nullptr, nullptr, nullptr, HID_, 24);
    gemm_lif<1, 1, 1><<<98 * 6, 256, 0, stream>>>(
        SZT, nullptr, WH2, WH2, WH2, WL2, WL2, WL2,
        fc2_b, fc2_b, fc2_b, fc2_bn, fc2_bn, fc2_bn, fc2_lw, fc2_lw, fc2_lw,
        nullptr, nullptr, nullptr, x, SP, out, cnt + 3, fl2, C_, HID_, 6);
    fixup_t<1, 1><<<512, 256, 0, stream>>>(
        SZT, nullptr, fc2_w, fc2_w, fc2_w, fc2_b, fc2_b, fc2_b,
        fc2_bn, fc2_bn, fc2_bn, fc2_lw, fc2_lw, fc2_lw,
        nullptr, nullptr, nullptr, x, SP, out, cnt + 3, fl2, C_, HID_);
}

// Round 10
// 1420.492 us; speedup vs baseline: 4.9134x; 1.0194x over previous
//
#include <hip/hip_runtime.h>
#include <math.h>

#define T_   4
#define B_   32
#define C_   384
#define N_   196
#define HID_ 1536
#define NH_  12
#define DH_  32
#define NCOL (B_*N_)            // 6272 columns j=(b,n)
#define THRESH 2e-3f            // certainty margin (worst-case MFMA-path err ~2.5e-4)
#define FCAP (1u<<17)

typedef unsigned char u8;
typedef unsigned int  u32;
using bf16x8 = __attribute__((ext_vector_type(8))) short;
using f32x4  = __attribute__((ext_vector_type(4))) float;

__device__ __forceinline__ float bfbits2f(short u) {
    union { u32 i; float f; } c; c.i = ((u32)(unsigned short)u) << 16; return c.f;
}
__device__ __forceinline__ short f2bf(float f) {       // RNE f32 -> bf16 bits
    u32 b = __float_as_uint(f);
    return (short)((b + 0x7FFFu + ((b >> 16) & 1u)) >> 16);
}

__global__ void zero_counters(u32* cnt) { if (threadIdx.x < 4) cnt[threadIdx.x] = 0; }

// ---------------------------------------------------------------------------
// Weight split: W(f32) -> hi,lo bf16 (hi = bf16(w), lo = bf16(w - hi))
// ---------------------------------------------------------------------------
__global__ void wprep(const float* __restrict__ W, short* __restrict__ H,
                      short* __restrict__ L, int n)
{
    int i = blockIdx.x * 256 + threadIdx.x;
    if (i >= n) return;
    float f = W[i];
    short h = f2bf(f);
    H[i] = h;
    L[i] = f2bf(f - bfbits2f(h));
}

// ---------------------------------------------------------------------------
// Transpose [tb][c][n] -> [tb*196+n][c].
// MODE 0: f32 src (+optional u8 Sadd) -> bf16 hi+lo of (x+s); optional exact
//         f32 copy F and u8 SPT copy.  MODE 1: u8 spikes -> bf16 hi (exact).
// ---------------------------------------------------------------------------
template<int MODE>
__global__ __launch_bounds__(256) void tpose(
    const void* __restrict__ src, const u8* __restrict__ Sadd,
    short* __restrict__ H, short* __restrict__ L,
    float* __restrict__ F, u8* __restrict__ SPTo,
    int c_tot, int nct)
{
    __shared__ float lds[64][197];
    __shared__ u8 slds[MODE == 0 ? 64 : 1][MODE == 0 ? 197 : 1];
    const int tid = threadIdx.x;
    const int tb = blockIdx.x / nct;
    const int ct = blockIdx.x % nct;
    const float* Xf = (const float*)src;
    const u8*    Xb = (const u8*)src;
    for (int i = tid; i < 64 * N_; i += 256) {
        int c = i / N_, n = i % N_;
        size_t g = ((size_t)tb * c_tot + ct * 64 + c) * N_ + n;
        if (MODE == 0) {
            float v = Xf[g];
            u8 s = Sadd ? Sadd[g] : (u8)0;
            lds[c][n] = v + (float)s;
            slds[c][n] = s;
        } else {
            lds[c][n] = (float)Xb[g];
        }
    }
    __syncthreads();
    for (int i = tid; i < 64 * N_; i += 256) {
        int n = i / 64, c = i % 64;
        float f = lds[c][n];
        short h = f2bf(f);
        size_t o = ((size_t)tb * N_ + n) * c_tot + ct * 64 + c;
        H[o] = h;
        if (MODE == 0) {
            L[o] = f2bf(f - bfbits2f(h));
            if (F)    F[o] = f;
            if (SPTo) SPTo[o] = slds[c][n];
        }
    }
}

// ---------------------------------------------------------------------------
// MFMA GEMM + BN + LIF + flagging (r8/r9-proven math).
// C[o,j,t] = sum_c W[o,c] X[t,j,c].  Block: 64o x 64m; 4 waves split m.
// NEW (r10): bijective XCD swizzle (m204) so the nob*NZ blocks sharing one
// mt B-panel run on ONE XCD -> panel L2-hot, ~8x less HBM re-fetch.
// D: col = lane&15, row = (lane>>4)*4 + reg  [m89-verified].
// ---------------------------------------------------------------------------
template<int SPLITS, int OM, int NZ>
__global__ __launch_bounds__(256) void gemm_lif(
    const short* __restrict__ BH, const short* __restrict__ BL,
    const short* __restrict__ WH0, const short* __restrict__ WH1, const short* __restrict__ WH2,
    const short* __restrict__ WL0, const short* __restrict__ WL1, const short* __restrict__ WL2,
    const float* __restrict__ cb0, const float* __restrict__ cb1, const float* __restrict__ cb2,
    const float* __restrict__ bn0, const float* __restrict__ bn1, const float* __restrict__ bn2,
    const float* __restrict__ lw0, const float* __restrict__ lw1, const float* __restrict__ lw2,
    u8* S0, u8* S1, u8* S2,
    const float* __restrict__ xres, const u8* __restrict__ sres, float* __restrict__ out,
    u32* __restrict__ cnt, u32* __restrict__ flags,
    int c_out, int c_in, int nob)
{
    const int tid = threadIdx.x;
    const int w = tid >> 6, l = tid & 63;

    // ---- bijective XCD-contiguity swizzle (8 XCDs, m204 formula) ----
    const u32 nwg = gridDim.x;
    const u32 q = nwg >> 3, r = nwg & 7;
    const u32 xcd = blockIdx.x & 7, off = blockIdx.x >> 3;
    const u32 id = (xcd < r ? xcd * (q + 1) : r * (q + 1) + (xcd - r) * q) + off;

    const int mt  = (int)(id / (u32)(nob * NZ));
    const int rem = (int)(id % (u32)(nob * NZ));
    const int z  = (NZ == 1) ? 0 : (rem % NZ);
    const int ob = (NZ == 1) ? rem : (rem / NZ);

    const short* WH = (z == 0) ? WH0 : ((z == 1) ? WH1 : WH2);
    const short* WL = (z == 0) ? WL0 : ((z == 1) ? WL1 : WL2);
    const float* cb  = (z == 0) ? cb0 : ((z == 1) ? cb1 : cb2);
    const float* bnp = (z == 0) ? bn0 : ((z == 1) ? bn1 : bn2);
    const float* lw  = (z == 0) ? lw0 : ((z == 1) ? lw1 : lw2);
    u8* SOUT         = (z == 0) ? S0  : ((z == 1) ? S1  : S2);

    const int j    = mt * 64 + w * 16 + (l & 15);
    const int kg   = (l >> 4) * 8;
    const int ob64 = ob * 64;
    const size_t tstr = (size_t)NCOL * c_in;

    f32x4 acc[4][4];
#pragma unroll
    for (int t = 0; t < 4; ++t)
#pragma unroll
        for (int os = 0; os < 4; ++os)
            acc[t][os] = (f32x4){0.f, 0.f, 0.f, 0.f};

    const short* bhp = BH + (size_t)j * c_in + kg;
    const short* blp = (SPLITS == 2) ? (BL + (size_t)j * c_in + kg) : nullptr;
    const short* ahp = WH + (size_t)(ob64 + (l & 15)) * c_in + kg;
    const short* alp = WL + (size_t)(ob64 + (l & 15)) * c_in + kg;

    for (int kc = 0; kc < c_in; kc += 32) {
        bf16x8 bh[4], bl[4];
#pragma unroll
        for (int t = 0; t < 4; ++t) {
            bh[t] = *(const bf16x8*)(bhp + (size_t)t * tstr + kc);
            if (SPLITS == 2) bl[t] = *(const bf16x8*)(blp + (size_t)t * tstr + kc);
        }
#pragma unroll
        for (int os = 0; os < 4; ++os) {
            const bf16x8 ah = *(const bf16x8*)(ahp + (size_t)os * 16 * c_in + kc);
            const bf16x8 al = *(const bf16x8*)(alp + (size_t)os * 16 * c_in + kc);
#pragma unroll
            for (int t = 0; t < 4; ++t) {
                acc[t][os] = __builtin_amdgcn_mfma_f32_16x16x32_bf16(ah, bh[t], acc[t][os], 0, 0, 0);
                acc[t][os] = __builtin_amdgcn_mfma_f32_16x16x32_bf16(al, bh[t], acc[t][os], 0, 0, 0);
                if (SPLITS == 2) {
                    acc[t][os] = __builtin_amdgcn_mfma_f32_16x16x32_bf16(ah, bl[t], acc[t][os], 0, 0, 0);
                    acc[t][os] = __builtin_amdgcn_mfma_f32_16x16x32_bf16(al, bl[t], acc[t][os], 0, 0, 0);
                }
            }
        }
    }

    const float tau = 1.0f / (1.0f + expf(-lw[0]));
    const size_t per_t = (size_t)B_ * c_out * N_;
    const int jb = j / N_, jn = j % N_;
#pragma unroll
    for (int os = 0; os < 4; ++os) {
#pragma unroll
        for (int r2 = 0; r2 < 4; ++r2) {
            const int o = ob64 + os * 16 + (l >> 4) * 4 + r2;
            const float g  = bnp[o];
            const float be = bnp[c_out + o];
            const float mm = bnp[2 * c_out + o];
            const float vv = bnp[3 * c_out + o];
            const float inv   = g / sqrtf(vv + 1e-5f);
            const float shift = be - mm * inv;
            const float cbv   = cb ? cb[o] : 0.0f;
            const size_t idx0 = ((size_t)jb * c_out + o) * N_ + jn;
            float v = 0.0f;
            bool flag = false;
#pragma unroll
            for (int t = 0; t < 4; ++t) {
                const float yv = (acc[t][os][r2] + cbv) * inv + shift;
                const float h  = v + (yv - v) * tau;
                const float sp = (h >= 1.0f) ? 1.0f : 0.0f;
                flag = flag || (fabsf(h - 1.0f) < THRESH);
                v = h * (1.0f - sp);
                const size_t idx = (size_t)t * per_t + idx0;
                if (OM == 0) SOUT[idx] = (u8)sp;
                else out[idx] = (float)((double)xres[idx] + (double)sres[idx] + (double)sp);
            }
            if (flag) {
                u32 p = atomicAdd(cnt, 1u);
                if (p < FCAP) flags[p] = ((u32)(z * c_out + o)) * (u32)NCOL + (u32)j;
            }
        }
    }
}

// ---------------------------------------------------------------------------
// f64 fixup on TRANSPOSED exact inputs (coalesced lane-over-c reads).
// IN_MODE: 0 = f32 XT; 1 = bf16 spike XT (exact); 2 = f32 XT + u8 SPT.
// Decision math identical to the r5/r7-proven all-f64 path.
// ---------------------------------------------------------------------------
template<int IN_MODE, int OM>
__global__ __launch_bounds__(256) void fixup_t(
    const void* __restrict__ XT, const u8* __restrict__ SPT,
    const float* __restrict__ W0, const float* __restrict__ W1, const float* __restrict__ W2,
    const float* __restrict__ cb0, const float* __restrict__ cb1, const float* __restrict__ cb2,
    const float* __restrict__ bn0, const float* __restrict__ bn1, const float* __restrict__ bn2,
    const float* __restrict__ lw0, const float* __restrict__ lw1, const float* __restrict__ lw2,
    u8* S0, u8* S1, u8* S2,
    const float* __restrict__ xres, const u8* __restrict__ sres, float* out,
    const u32* __restrict__ cnt, const u32* __restrict__ flags,
    int c_out, int c_in)
{
    const int lane = threadIdx.x & 63;
    const int wid  = (blockIdx.x * 256 + threadIdx.x) >> 6;
    const int nw   = (gridDim.x * 256) >> 6;
    u32 nrec = *cnt;
    if (nrec > FCAP) nrec = FCAP;

    const float* XTf = (const float*)XT;
    const short* XTs = (const short*)XT;

    for (u32 r = wid; r < nrec; r += nw) {
        const u32 rec = flags[r];
        const int j  = (int)(rec % (u32)NCOL);
        const u32 zo = rec / (u32)NCOL;
        const int z  = (int)(zo / (u32)c_out);
        const int o  = (int)(zo % (u32)c_out);

        const float* W   = (z == 0) ? W0  : ((z == 1) ? W1  : W2);
        const float* cb  = (z == 0) ? cb0 : ((z == 1) ? cb1 : cb2);
        const float* bnp = (z == 0) ? bn0 : ((z == 1) ? bn1 : bn2);
        const float* lw  = (z == 0) ? lw0 : ((z == 1) ? lw1 : lw2);
        u8* SOUT         = (z == 0) ? S0  : ((z == 1) ? S1  : S2);

        double acc[4] = {0.0, 0.0, 0.0, 0.0};
        for (int c = lane; c < c_in; c += 64) {
            const double w = (double)W[(size_t)o * c_in + c];
#pragma unroll
            for (int t = 0; t < 4; ++t) {
                const size_t i = ((size_t)(t * NCOL + j)) * c_in + c;
                double xval;
                if (IN_MODE == 0)      xval = (double)XTf[i];
                else if (IN_MODE == 1) xval = (double)bfbits2f(XTs[i]);
                else                   xval = (double)XTf[i] + (double)SPT[i];
                acc[t] = fma(w, xval, acc[t]);
            }
        }
#pragma unroll
        for (int m = 32; m; m >>= 1) {
#pragma unroll
            for (int t = 0; t < 4; ++t)
                acc[t] += __shfl_xor(acc[t], m, 64);
        }

        if (lane == 0) {
            const double tau = 1.0 / (1.0 + exp(-(double)lw[0]));
            const double g  = (double)bnp[o];
            const double be = (double)bnp[c_out + o];
            const double mm = (double)bnp[2 * c_out + o];
            const double vv = (double)bnp[3 * c_out + o];
            const double inv   = g / sqrt(vv + 1e-5);
            const double shift = be - mm * inv;
            const double cbv   = cb ? (double)cb[o] : 0.0;
            const size_t per_t = (size_t)B_ * c_out * N_;
            const int jb = j / N_, jn = j % N_;
            const size_t idx0  = ((size_t)jb * c_out + o) * N_ + jn;
            double v = 0.0;
#pragma unroll
            for (int t = 0; t < 4; ++t) {
                const double yv = (acc[t] + cbv) * inv + shift;
                const double h  = v + (yv - v) * tau;
                const double sp = (h >= 1.0) ? 1.0 : 0.0;
                v = h * (1.0 - sp);
                const size_t idx = (size_t)t * per_t + idx0;
                if (OM == 0) SOUT[idx] = (u8)sp;
                else out[idx] = (float)((double)xres[idx] + (double)sres[idx] + sp);
            }
        }
    }
}

// ---------------------------------------------------------------------------
// Spike attention + fused LIF (exact dyadic arithmetic, r5-r9 proven).
// ---------------------------------------------------------------------------
__global__ __launch_bounds__(256) void attn_lif_kernel(
    const u8* __restrict__ SQ, const u8* __restrict__ SK, const u8* __restrict__ SV,
    u8* __restrict__ SATT, const float* __restrict__ lw)
{
    __shared__ u8 q_lds[DH_ * N_];
    __shared__ u8 k_lds[DH_ * N_];
    __shared__ u8 v_lds[DH_ * N_];
    __shared__ float kv_lds[DH_ * DH_];
    __shared__ float vstate[DH_ * N_];
    const int tid = threadIdx.x;
    const int b = blockIdx.x / NH_, h = blockIdx.x % NH_;
    const float tau = 1.0f / (1.0f + expf(-lw[0]));

    for (int i = tid; i < DH_ * N_; i += 256) vstate[i] = 0.0f;

    for (int t = 0; t < T_; ++t) {
        const size_t base = ((size_t)((t * B_ + b) * C_) + h * DH_) * N_;
        __syncthreads();
        for (int i = tid; i < DH_ * N_ / 4; i += 256) {
            ((unsigned int*)q_lds)[i] = ((const unsigned int*)(SQ + base))[i];
            ((unsigned int*)k_lds)[i] = ((const unsigned int*)(SK + base))[i];
            ((unsigned int*)v_lds)[i] = ((const unsigned int*)(SV + base))[i];
        }
        __syncthreads();

#pragma unroll
        for (int r = 0; r < 4; ++r) {
            const int e = tid + 256 * r;
            const int i = e >> 5, jj = e & 31;
            int s = 0;
            for (int nn = 0; nn < N_; nn += 4) {
                uchar4 kk = *(const uchar4*)&k_lds[i * N_ + nn];
                uchar4 uv = *(const uchar4*)&v_lds[jj * N_ + nn];
                s += kk.x * uv.x + kk.y * uv.y + kk.z * uv.z + kk.w * uv.w;
            }
            kv_lds[e] = (float)s;
        }
        __syncthreads();

        for (int e = tid; e < DH_ * N_; e += 256) {
            const int jj = e / N_, nn = e % N_;
            float s = 0.0f;
#pragma unroll
            for (int i = 0; i < DH_; ++i)
                s += q_lds[i * N_ + nn] ? kv_lds[i * DH_ + jj] : 0.0f;
            const float att = 0.125f * s;
            const float v = vstate[e];
            const float hh = v + (att - v) * tau;
            const float sp = (hh >= 1.0f) ? 1.0f : 0.0f;
            vstate[e] = hh * (1.0f - sp);
            SATT[base + e] = (u8)sp;
        }
    }
}

// ---------------------------------------------------------------------------
extern "C" void kernel_launch(void* const* d_in, const int* in_sizes, int n_in,
                              void* d_out, int out_size, void* d_ws, size_t ws_size,
                              hipStream_t stream)
{
    const float* x       = (const float*)d_in[0];
    const float* q_w     = (const float*)d_in[1];
    const float* q_bn    = (const float*)d_in[2];
    const float* q_lw    = (const float*)d_in[3];
    const float* k_w     = (const float*)d_in[4];
    const float* k_bn    = (const float*)d_in[5];
    const float* k_lw    = (const float*)d_in[6];
    const float* v_w     = (const float*)d_in[7];
    const float* v_bn    = (const float*)d_in[8];
    const float* v_lw    = (const float*)d_in[9];
    const float* attn_lw = (const float*)d_in[10];
    const float* proj_w  = (const float*)d_in[11];
    const float* proj_b  = (const float*)d_in[12];
    const float* proj_bn = (const float*)d_in[13];
    const float* proj_lw = (const float*)d_in[14];
    const float* fc1_w   = (const float*)d_in[15];
    const float* fc1_b   = (const float*)d_in[16];
    const float* fc1_bn  = (const float*)d_in[17];
    const float* fc1_lw  = (const float*)d_in[18];
    const float* fc2_w   = (const float*)d_in[19];
    const float* fc2_b   = (const float*)d_in[20];
    const float* fc2_bn  = (const float*)d_in[21];
    const float* fc2_lw  = (const float*)d_in[22];

    // ---- workspace layout (~154 MB), phase-aliased (r9-proven) ----
    u8* base = (u8*)d_ws;
    float* XTf32  = (float*)(base);                 // [0, 38.5M)   ph1-4
    short* XT_h   = (short*)(base + 38535168);      // [38.5, 57.8) ph1&4
    short* XT_l   = (short*)(base + 57802752);      // [57.8, 77.1) ph1&4
    short* SZT    = (short*)(base);                 // [0, 77.1)    ph5 (overlay)
    u8*    SQ     = base + 77070336;                // 9,633,792 each, ph1-2
    u8*    SK     = base + 86704128;
    u8*    SV     = base + 96337920;
    u8*    SATT   = base + 105971712;               // ph2-3, ends 115.6M
    u8*    SZ     = base + 77070336;                // ph4-5 (overlays SQ..SATT)
    short* SATT_T = (short*)(base + 115605504);     // 19.3M, ph3
    u8*    SPT    = base + 115605504;               // 9.6M,  ph4 (overlay)
    u8*    SP     = base + 134873088;               // 9.6M,  ph3-5
    u32*   cnt    = (u32*)(base + 144506880);       // 256 B
    u32*   flags  = (u32*)(base + 144507136);       // 4*FCAP*4 = 2.1M
    short* WHb    = (short*)(base + 146604288);     // 3.54M
    short* WLb    = (short*)(base + 150143232);     // 3.54M -> ends ~153.7M
    float* out = (float*)d_out;

    short *WHq = WHb,          *WHk = WHb + 147456, *WHv = WHb + 294912,
          *WHp = WHb + 442368, *WH1 = WHb + 589824, *WH2 = WHb + 1179648;
    short *WLq = WLb,          *WLk = WLb + 147456, *WLv = WLb + 294912,
          *WLp = WLb + 442368, *WL1 = WLb + 589824, *WL2 = WLb + 1179648;
    u32 *flQ = flags, *flP = flags + FCAP, *fl1 = flags + 2 * FCAP, *fl2 = flags + 3 * FCAP;

    zero_counters<<<1, 64, 0, stream>>>(cnt);

    // 0. weight splits
    wprep<<<576, 256, 0, stream>>>(q_w,    WHq, WLq, 147456);
    wprep<<<576, 256, 0, stream>>>(k_w,    WHk, WLk, 147456);
    wprep<<<576, 256, 0, stream>>>(v_w,    WHv, WLv, 147456);
    wprep<<<576, 256, 0, stream>>>(proj_w, WHp, WLp, 147456);
    wprep<<<2304, 256, 0, stream>>>(fc1_w, WH1, WL1, 589824);
    wprep<<<2304, 256, 0, stream>>>(fc2_w, WH2, WL2, 589824);

    // 1. x -> XT hi/lo + exact XTf32; fused q/k/v GEMM+LIF; coalesced f64 fixup
    tpose<0><<<128 * 6, 256, 0, stream>>>(x, nullptr, XT_h, XT_l, XTf32, nullptr, C_, 6);
    gemm_lif<2, 0, 3><<<98 * 6 * 3, 256, 0, stream>>>(
        XT_h, XT_l, WHq, WHk, WHv, WLq, WLk, WLv,
        nullptr, nullptr, nullptr, q_bn, k_bn, v_bn, q_lw, k_lw, v_lw,
        SQ, SK, SV, nullptr, nullptr, nullptr, cnt + 0, flQ, C_, C_, 6);
    fixup_t<0, 0><<<512, 256, 0, stream>>>(
        XTf32, nullptr, q_w, k_w, v_w, nullptr, nullptr, nullptr,
        q_bn, k_bn, v_bn, q_lw, k_lw, v_lw,
        SQ, SK, SV, nullptr, nullptr, nullptr, cnt + 0, flQ, C_, C_);

    // 2. attention + LIF (exact)
    attn_lif_kernel<<<B_ * NH_, 256, 0, stream>>>(SQ, SK, SV, SATT, attn_lw);

    // 3. proj: SATT -> SATT_T (exact bf16); GEMM; fixup reads SATT_T
    tpose<1><<<128 * 6, 256, 0, stream>>>(SATT, nullptr, SATT_T, nullptr, nullptr, nullptr, C_, 6);
    gemm_lif<1, 0, 1><<<98 * 6, 256, 0, stream>>>(
        SATT_T, nullptr, WHp, WHp, WHp, WLp, WLp, WLp,
        proj_b, proj_b, proj_b, proj_bn, proj_bn, proj_bn, proj_lw, proj_lw, proj_lw,
        SP, SP, SP, nullptr, nullptr, nullptr, cnt + 1, flP, C_, C_, 6);
    fixup_t<1, 0><<<512, 256, 0, stream>>>(
        SATT_T, nullptr, proj_w, proj_w, proj_w, proj_b, proj_b, proj_b,
        proj_bn, proj_bn, proj_bn, proj_lw, proj_lw, proj_lw,
        SP, SP, SP, nullptr, nullptr, nullptr, cnt + 1, flP, C_, C_);

    // 4. fc1: (x+SP) -> XT hi/lo + SPT; GEMM; fixup reads XTf32 + SPT
    tpose<0><<<128 * 6, 256, 0, stream>>>(x, SP, XT_h, XT_l, nullptr, SPT, C_, 6);
    gemm_lif<2, 0, 1><<<98 * 24, 256, 0, stream>>>(
        XT_h, XT_l, WH1, WH1, WH1, WL1, WL1, WL1,
        fc1_b, fc1_b, fc1_b, fc1_bn, fc1_bn, fc1_bn, fc1_lw, fc1_lw, fc1_lw,
        SZ, SZ, SZ, nullptr, nullptr, nullptr, cnt + 2, fl1, HID_, C_, 24);
    fixup_t<2, 0><<<512, 256, 0, stream>>>(
        XTf32, SPT, fc1_w, fc1_w, fc1_w, fc1_b, fc1_b, fc1_b,
        fc1_bn, fc1_bn, fc1_bn, fc1_lw, fc1_lw, fc1_lw,
        SZ, SZ, SZ, nullptr, nullptr, nullptr, cnt + 2, fl1, HID_, C_);

    // 5. fc2: SZ -> SZT (exact bf16, overlays region A); GEMM -> out; fixup
    tpose<1><<<128 * 24, 256, 0, stream>>>(SZ, nullptr, SZT, nullptr, nullptr, nullptr, HID_, 24);
    gemm_lif<1, 1, 1><<<98 * 6, 256, 0, stream>>>(
        SZT, nullptr, WH2, WH2, WH2, WL2, WL2, WL2,
        fc2_b, fc2_b, fc2_b, fc2_bn, fc2_bn, fc2_bn, fc2_lw, fc2_lw, fc2_lw,
        nullptr, nullptr, nullptr, x, SP, out, cnt + 3, fl2, C_, HID_, 6);
    fixup_t<1, 1><<<512, 256, 0, stream>>>(
        SZT, nullptr, fc2_w, fc2_w, fc2_w, fc2_b, fc2_b, fc2_b,
        fc2_bn, fc2_bn, fc2_bn, fc2_lw, fc2_lw, fc2_lw,
        nullptr, nullptr, nullptr, x, SP, out, cnt + 3, fl2, C_, HID_);
}

// Round 11
// 1413.602 us; speedup vs baseline: 4.9374x; 1.0049x over previous
//
#include <hip/hip_runtime.h>
#include <math.h>

#define T_   4
#define B_   32
#define C_   384
#define N_   196
#define HID_ 1536
#define NH_  12
#define DH_  32
#define NCOL (B_*N_)            // 6272 columns j=(b,n)
#define THRESH 2e-3f            // certainty margin (worst-case MFMA-path err ~3e-4)
#define FCAP (1u<<17)

typedef unsigned char u8;
typedef unsigned int  u32;
using bf16x8 = __attribute__((ext_vector_type(8))) short;
using f32x4  = __attribute__((ext_vector_type(4))) float;

__device__ __forceinline__ float bfbits2f(short u) {
    union { u32 i; float f; } c; c.i = ((u32)(unsigned short)u) << 16; return c.f;
}
__device__ __forceinline__ short f2bf(float f) {       // RNE f32 -> bf16 bits
    u32 b = __float_as_uint(f);
    return (short)((b + 0x7FFFu + ((b >> 16) & 1u)) >> 16);
}

__global__ void zero_counters(u32* cnt) { if (threadIdx.x < 4) cnt[threadIdx.x] = 0; }

// ---------------------------------------------------------------------------
// Weight split: W(f32) -> hi,lo bf16 (hi = bf16(w), lo = bf16(w - hi))
// ---------------------------------------------------------------------------
__global__ void wprep(const float* __restrict__ W, short* __restrict__ H,
                      short* __restrict__ L, int n)
{
    int i = blockIdx.x * 256 + threadIdx.x;
    if (i >= n) return;
    float f = W[i];
    short h = f2bf(f);
    H[i] = h;
    L[i] = f2bf(f - bfbits2f(h));
}

// ---------------------------------------------------------------------------
// Transpose [tb][c][n] -> [tb*196+n][c].
// MODE 0: f32 src (+optional u8 Sadd) -> bf16 hi+lo of (x+s); optional exact
//         f32 copy F and u8 SPT copy.  MODE 1: u8 spikes -> bf16 hi (exact).
// ---------------------------------------------------------------------------
template<int MODE>
__global__ __launch_bounds__(256) void tpose(
    const void* __restrict__ src, const u8* __restrict__ Sadd,
    short* __restrict__ H, short* __restrict__ L,
    float* __restrict__ F, u8* __restrict__ SPTo,
    int c_tot, int nct)
{
    __shared__ float lds[64][197];
    __shared__ u8 slds[MODE == 0 ? 64 : 1][MODE == 0 ? 197 : 1];
    const int tid = threadIdx.x;
    const int tb = blockIdx.x / nct;
    const int ct = blockIdx.x % nct;
    const float* Xf = (const float*)src;
    const u8*    Xb = (const u8*)src;
    for (int i = tid; i < 64 * N_; i += 256) {
        int c = i / N_, n = i % N_;
        size_t g = ((size_t)tb * c_tot + ct * 64 + c) * N_ + n;
        if (MODE == 0) {
            float v = Xf[g];
            u8 s = Sadd ? Sadd[g] : (u8)0;
            lds[c][n] = v + (float)s;
            slds[c][n] = s;
        } else {
            lds[c][n] = (float)Xb[g];
        }
    }
    __syncthreads();
    for (int i = tid; i < 64 * N_; i += 256) {
        int n = i / 64, c = i % 64;
        float f = lds[c][n];
        short h = f2bf(f);
        size_t o = ((size_t)tb * N_ + n) * c_tot + ct * 64 + c;
        H[o] = h;
        if (MODE == 0) {
            L[o] = f2bf(f - bfbits2f(h));
            if (F)    F[o] = f;
            if (SPTo) SPTo[o] = slds[c][n];
        }
    }
}

// ---------------------------------------------------------------------------
// MFMA GEMM + BN + LIF + flagging.  C[o,j,t] = sum_c W[o,c] X[t,j,c].
// Block: 64o x 64m; 4 waves split m.  Bijective XCD swizzle (r10-proven).
// r11: (a) lo x lo MFMA dropped (err <= ~5e-5 << THRESH, fixup net catches
// near-threshold anyway); (b) explicit 2-deep ping/pong pipeline on B
// fragments + hoisted A fragments -> loads overlap MFMA bursts.
// D: col = lane&15, row = (lane>>4)*4 + reg  [m89-verified].
// ---------------------------------------------------------------------------
template<int SPLITS, int OM, int NZ>
__global__ __launch_bounds__(256) void gemm_lif(
    const short* __restrict__ BH, const short* __restrict__ BL,
    const short* __restrict__ WH0, const short* __restrict__ WH1, const short* __restrict__ WH2,
    const short* __restrict__ WL0, const short* __restrict__ WL1, const short* __restrict__ WL2,
    const float* __restrict__ cb0, const float* __restrict__ cb1, const float* __restrict__ cb2,
    const float* __restrict__ bn0, const float* __restrict__ bn1, const float* __restrict__ bn2,
    const float* __restrict__ lw0, const float* __restrict__ lw1, const float* __restrict__ lw2,
    u8* S0, u8* S1, u8* S2,
    const float* __restrict__ xres, const u8* __restrict__ sres, float* __restrict__ out,
    u32* __restrict__ cnt, u32* __restrict__ flags,
    int c_out, int c_in, int nob)
{
    const int tid = threadIdx.x;
    const int w = tid >> 6, l = tid & 63;

    // ---- bijective XCD-contiguity swizzle (8 XCDs, m204 formula) ----
    const u32 nwg = gridDim.x;
    const u32 q = nwg >> 3, r = nwg & 7;
    const u32 xcd = blockIdx.x & 7, off = blockIdx.x >> 3;
    const u32 id = (xcd < r ? xcd * (q + 1) : r * (q + 1) + (xcd - r) * q) + off;

    const int mt  = (int)(id / (u32)(nob * NZ));
    const int rem = (int)(id % (u32)(nob * NZ));
    const int z  = (NZ == 1) ? 0 : (rem % NZ);
    const int ob = (NZ == 1) ? rem : (rem / NZ);

    const short* WH = (z == 0) ? WH0 : ((z == 1) ? WH1 : WH2);
    const short* WL = (z == 0) ? WL0 : ((z == 1) ? WL1 : WL2);
    const float* cb  = (z == 0) ? cb0 : ((z == 1) ? cb1 : cb2);
    const float* bnp = (z == 0) ? bn0 : ((z == 1) ? bn1 : bn2);
    const float* lw  = (z == 0) ? lw0 : ((z == 1) ? lw1 : lw2);
    u8* SOUT         = (z == 0) ? S0  : ((z == 1) ? S1  : S2);

    const int j    = mt * 64 + w * 16 + (l & 15);
    const int kg   = (l >> 4) * 8;
    const int ob64 = ob * 64;
    const size_t tstr = (size_t)NCOL * c_in;

    f32x4 acc[4][4];
#pragma unroll
    for (int t = 0; t < 4; ++t)
#pragma unroll
        for (int os = 0; os < 4; ++os)
            acc[t][os] = (f32x4){0.f, 0.f, 0.f, 0.f};

    const short* bhp = BH + (size_t)j * c_in + kg;
    const short* blp = (SPLITS == 2) ? (BL + (size_t)j * c_in + kg) : nullptr;
    const short* ahp = WH + (size_t)(ob64 + (l & 15)) * c_in + kg;
    const short* alp = WL + (size_t)(ob64 + (l & 15)) * c_in + kg;

    // ping/pong B fragment sets (statically named; no dynamic indexing)
    bf16x8 bhA[4], blA[4], bhB[4], blB[4];

    auto LOADB = [&](int kc, bf16x8* bh, bf16x8* bl) {
#pragma unroll
        for (int t = 0; t < 4; ++t) {
            bh[t] = *(const bf16x8*)(bhp + (size_t)t * tstr + kc);
            if (SPLITS == 2) bl[t] = *(const bf16x8*)(blp + (size_t)t * tstr + kc);
        }
    };
    auto COMPUTE = [&](int kc, const bf16x8* bh, const bf16x8* bl) {
        bf16x8 ah[4], al[4];
#pragma unroll
        for (int os = 0; os < 4; ++os) {
            ah[os] = *(const bf16x8*)(ahp + (size_t)os * 16 * c_in + kc);
            al[os] = *(const bf16x8*)(alp + (size_t)os * 16 * c_in + kc);
        }
#pragma unroll
        for (int os = 0; os < 4; ++os) {
#pragma unroll
            for (int t = 0; t < 4; ++t) {
                acc[t][os] = __builtin_amdgcn_mfma_f32_16x16x32_bf16(ah[os], bh[t], acc[t][os], 0, 0, 0);
                acc[t][os] = __builtin_amdgcn_mfma_f32_16x16x32_bf16(al[os], bh[t], acc[t][os], 0, 0, 0);
                if (SPLITS == 2)   // note: lo x lo term dropped (r11)
                    acc[t][os] = __builtin_amdgcn_mfma_f32_16x16x32_bf16(ah[os], bl[t], acc[t][os], 0, 0, 0);
            }
        }
    };

    LOADB(0, bhA, blA);
    for (int kc = 0; kc < c_in; kc += 64) {
        LOADB(kc + 32, bhB, blB);                       // kc+32 < c_in always (c_in % 64 == 0)
        COMPUTE(kc, bhA, blA);
        if (kc + 64 < c_in) LOADB(kc + 64, bhA, blA);
        COMPUTE(kc + 32, bhB, blB);
    }

    const float tau = 1.0f / (1.0f + expf(-lw[0]));
    const size_t per_t = (size_t)B_ * c_out * N_;
    const int jb = j / N_, jn = j % N_;
#pragma unroll
    for (int os = 0; os < 4; ++os) {
#pragma unroll
        for (int r2 = 0; r2 < 4; ++r2) {
            const int o = ob64 + os * 16 + (l >> 4) * 4 + r2;
            const float g  = bnp[o];
            const float be = bnp[c_out + o];
            const float mm = bnp[2 * c_out + o];
            const float vv = bnp[3 * c_out + o];
            const float inv   = g / sqrtf(vv + 1e-5f);
            const float shift = be - mm * inv;
            const float cbv   = cb ? cb[o] : 0.0f;
            const size_t idx0 = ((size_t)jb * c_out + o) * N_ + jn;
            float v = 0.0f;
            bool flag = false;
#pragma unroll
            for (int t = 0; t < 4; ++t) {
                const float yv = (acc[t][os][r2] + cbv) * inv + shift;
                const float h  = v + (yv - v) * tau;
                const float sp = (h >= 1.0f) ? 1.0f : 0.0f;
                flag = flag || (fabsf(h - 1.0f) < THRESH);
                v = h * (1.0f - sp);
                const size_t idx = (size_t)t * per_t + idx0;
                if (OM == 0) SOUT[idx] = (u8)sp;
                else out[idx] = (float)((double)xres[idx] + (double)sres[idx] + (double)sp);
            }
            if (flag) {
                u32 p = atomicAdd(cnt, 1u);
                if (p < FCAP) flags[p] = ((u32)(z * c_out + o)) * (u32)NCOL + (u32)j;
            }
        }
    }
}

// ---------------------------------------------------------------------------
// f64 fixup on TRANSPOSED exact inputs (coalesced lane-over-c reads).
// IN_MODE: 0 = f32 XT; 1 = bf16 spike XT (exact); 2 = f32 XT + u8 SPT.
// Decision math identical to the r5/r7-proven all-f64 path.
// ---------------------------------------------------------------------------
template<int IN_MODE, int OM>
__global__ __launch_bounds__(256) void fixup_t(
    const void* __restrict__ XT, const u8* __restrict__ SPT,
    const float* __restrict__ W0, const float* __restrict__ W1, const float* __restrict__ W2,
    const float* __restrict__ cb0, const float* __restrict__ cb1, const float* __restrict__ cb2,
    const float* __restrict__ bn0, const float* __restrict__ bn1, const float* __restrict__ bn2,
    const float* __restrict__ lw0, const float* __restrict__ lw1, const float* __restrict__ lw2,
    u8* S0, u8* S1, u8* S2,
    const float* __restrict__ xres, const u8* __restrict__ sres, float* out,
    const u32* __restrict__ cnt, const u32* __restrict__ flags,
    int c_out, int c_in)
{
    const int lane = threadIdx.x & 63;
    const int wid  = (blockIdx.x * 256 + threadIdx.x) >> 6;
    const int nw   = (gridDim.x * 256) >> 6;
    u32 nrec = *cnt;
    if (nrec > FCAP) nrec = FCAP;

    const float* XTf = (const float*)XT;
    const short* XTs = (const short*)XT;

    for (u32 r = wid; r < nrec; r += nw) {
        const u32 rec = flags[r];
        const int j  = (int)(rec % (u32)NCOL);
        const u32 zo = rec / (u32)NCOL;
        const int z  = (int)(zo / (u32)c_out);
        const int o  = (int)(zo % (u32)c_out);

        const float* W   = (z == 0) ? W0  : ((z == 1) ? W1  : W2);
        const float* cb  = (z == 0) ? cb0 : ((z == 1) ? cb1 : cb2);
        const float* bnp = (z == 0) ? bn0 : ((z == 1) ? bn1 : bn2);
        const float* lw  = (z == 0) ? lw0 : ((z == 1) ? lw1 : lw2);
        u8* SOUT         = (z == 0) ? S0  : ((z == 1) ? S1  : S2);

        double acc[4] = {0.0, 0.0, 0.0, 0.0};
        for (int c = lane; c < c_in; c += 64) {
            const double w = (double)W[(size_t)o * c_in + c];
#pragma unroll
            for (int t = 0; t < 4; ++t) {
                const size_t i = ((size_t)(t * NCOL + j)) * c_in + c;
                double xval;
                if (IN_MODE == 0)      xval = (double)XTf[i];
                else if (IN_MODE == 1) xval = (double)bfbits2f(XTs[i]);
                else                   xval = (double)XTf[i] + (double)SPT[i];
                acc[t] = fma(w, xval, acc[t]);
            }
        }
#pragma unroll
        for (int m = 32; m; m >>= 1) {
#pragma unroll
            for (int t = 0; t < 4; ++t)
                acc[t] += __shfl_xor(acc[t], m, 64);
        }

        if (lane == 0) {
            const double tau = 1.0 / (1.0 + exp(-(double)lw[0]));
            const double g  = (double)bnp[o];
            const double be = (double)bnp[c_out + o];
            const double mm = (double)bnp[2 * c_out + o];
            const double vv = (double)bnp[3 * c_out + o];
            const double inv   = g / sqrt(vv + 1e-5);
            const double shift = be - mm * inv;
            const double cbv   = cb ? (double)cb[o] : 0.0;
            const size_t per_t = (size_t)B_ * c_out * N_;
            const int jb = j / N_, jn = j % N_;
            const size_t idx0  = ((size_t)jb * c_out + o) * N_ + jn;
            double v = 0.0;
#pragma unroll
            for (int t = 0; t < 4; ++t) {
                const double yv = (acc[t] + cbv) * inv + shift;
                const double h  = v + (yv - v) * tau;
                const double sp = (h >= 1.0) ? 1.0 : 0.0;
                v = h * (1.0 - sp);
                const size_t idx = (size_t)t * per_t + idx0;
                if (OM == 0) SOUT[idx] = (u8)sp;
                else out[idx] = (float)((double)xres[idx] + (double)sres[idx] + sp);
            }
        }
    }
}

// ---------------------------------------------------------------------------
// Spike attention + fused LIF (exact dyadic arithmetic, r5-r10 proven).
// ---------------------------------------------------------------------------
__global__ __launch_bounds__(256) void attn_lif_kernel(
    const u8* __restrict__ SQ, const u8* __restrict__ SK, const u8* __restrict__ SV,
    u8* __restrict__ SATT, const float* __restrict__ lw)
{
    __shared__ u8 q_lds[DH_ * N_];
    __shared__ u8 k_lds[DH_ * N_];
    __shared__ u8 v_lds[DH_ * N_];
    __shared__ float kv_lds[DH_ * DH_];
    __shared__ float vstate[DH_ * N_];
    const int tid = threadIdx.x;
    const int b = blockIdx.x / NH_, h = blockIdx.x % NH_;
    const float tau = 1.0f / (1.0f + expf(-lw[0]));

    for (int i = tid; i < DH_ * N_; i += 256) vstate[i] = 0.0f;

    for (int t = 0; t < T_; ++t) {
        const size_t base = ((size_t)((t * B_ + b) * C_) + h * DH_) * N_;
        __syncthreads();
        for (int i = tid; i < DH_ * N_ / 4; i += 256) {
            ((unsigned int*)q_lds)[i] = ((const unsigned int*)(SQ + base))[i];
            ((unsigned int*)k_lds)[i] = ((const unsigned int*)(SK + base))[i];
            ((unsigned int*)v_lds)[i] = ((const unsigned int*)(SV + base))[i];
        }
        __syncthreads();

#pragma unroll
        for (int r = 0; r < 4; ++r) {
            const int e = tid + 256 * r;
            const int i = e >> 5, jj = e & 31;
            int s = 0;
            for (int nn = 0; nn < N_; nn += 4) {
                uchar4 kk = *(const uchar4*)&k_lds[i * N_ + nn];
                uchar4 uv = *(const uchar4*)&v_lds[jj * N_ + nn];
                s += kk.x * uv.x + kk.y * uv.y + kk.z * uv.z + kk.w * uv.w;
            }
            kv_lds[e] = (float)s;
        }
        __syncthreads();

        for (int e = tid; e < DH_ * N_; e += 256) {
            const int jj = e / N_, nn = e % N_;
            float s = 0.0f;
#pragma unroll
            for (int i = 0; i < DH_; ++i)
                s += q_lds[i * N_ + nn] ? kv_lds[i * DH_ + jj] : 0.0f;
            const float att = 0.125f * s;
            const float v = vstate[e];
            const float hh = v + (att - v) * tau;
            const float sp = (hh >= 1.0f) ? 1.0f : 0.0f;
            vstate[e] = hh * (1.0f - sp);
            SATT[base + e] = (u8)sp;
        }
    }
}

// ---------------------------------------------------------------------------
extern "C" void kernel_launch(void* const* d_in, const int* in_sizes, int n_in,
                              void* d_out, int out_size, void* d_ws, size_t ws_size,
                              hipStream_t stream)
{
    const float* x       = (const float*)d_in[0];
    const float* q_w     = (const float*)d_in[1];
    const float* q_bn    = (const float*)d_in[2];
    const float* q_lw    = (const float*)d_in[3];
    const float* k_w     = (const float*)d_in[4];
    const float* k_bn    = (const float*)d_in[5];
    const float* k_lw    = (const float*)d_in[6];
    const float* v_w     = (const float*)d_in[7];
    const float* v_bn    = (const float*)d_in[8];
    const float* v_lw    = (const float*)d_in[9];
    const float* attn_lw = (const float*)d_in[10];
    const float* proj_w  = (const float*)d_in[11];
    const float* proj_b  = (const float*)d_in[12];
    const float* proj_bn = (const float*)d_in[13];
    const float* proj_lw = (const float*)d_in[14];
    const float* fc1_w   = (const float*)d_in[15];
    const float* fc1_b   = (const float*)d_in[16];
    const float* fc1_bn  = (const float*)d_in[17];
    const float* fc1_lw  = (const float*)d_in[18];
    const float* fc2_w   = (const float*)d_in[19];
    const float* fc2_b   = (const float*)d_in[20];
    const float* fc2_bn  = (const float*)d_in[21];
    const float* fc2_lw  = (const float*)d_in[22];

    // ---- workspace layout (~154 MB), phase-aliased (r9/r10-proven) ----
    u8* base = (u8*)d_ws;
    float* XTf32  = (float*)(base);                 // [0, 38.5M)   ph1-4
    short* XT_h   = (short*)(base + 38535168);      // [38.5, 57.8) ph1&4
    short* XT_l   = (short*)(base + 57802752);      // [57.8, 77.1) ph1&4
    short* SZT    = (short*)(base);                 // [0, 77.1)    ph5 (overlay)
    u8*    SQ     = base + 77070336;                // 9,633,792 each, ph1-2
    u8*    SK     = base + 86704128;
    u8*    SV     = base + 96337920;
    u8*    SATT   = base + 105971712;               // ph2-3, ends 115.6M
    u8*    SZ     = base + 77070336;                // ph4-5 (overlays SQ..SATT)
    short* SATT_T = (short*)(base + 115605504);     // 19.3M, ph3
    u8*    SPT    = base + 115605504;               // 9.6M,  ph4 (overlay)
    u8*    SP     = base + 134873088;               // 9.6M,  ph3-5
    u32*   cnt    = (u32*)(base + 144506880);       // 256 B
    u32*   flags  = (u32*)(base + 144507136);       // 4*FCAP*4 = 2.1M
    short* WHb    = (short*)(base + 146604288);     // 3.54M
    short* WLb    = (short*)(base + 150143232);     // 3.54M -> ends ~153.7M
    float* out = (float*)d_out;

    short *WHq = WHb,          *WHk = WHb + 147456, *WHv = WHb + 294912,
          *WHp = WHb + 442368, *WH1 = WHb + 589824, *WH2 = WHb + 1179648;
    short *WLq = WLb,          *WLk = WLb + 147456, *WLv = WLb + 294912,
          *WLp = WLb + 442368, *WL1 = WLb + 589824, *WL2 = WLb + 1179648;
    u32 *flQ = flags, *flP = flags + FCAP, *fl1 = flags + 2 * FCAP, *fl2 = flags + 3 * FCAP;

    zero_counters<<<1, 64, 0, stream>>>(cnt);

    // 0. weight splits
    wprep<<<576, 256, 0, stream>>>(q_w,    WHq, WLq, 147456);
    wprep<<<576, 256, 0, stream>>>(k_w,    WHk, WLk, 147456);
    wprep<<<576, 256, 0, stream>>>(v_w,    WHv, WLv, 147456);
    wprep<<<576, 256, 0, stream>>>(proj_w, WHp, WLp, 147456);
    wprep<<<2304, 256, 0, stream>>>(fc1_w, WH1, WL1, 589824);
    wprep<<<2304, 256, 0, stream>>>(fc2_w, WH2, WL2, 589824);

    // 1. x -> XT hi/lo + exact XTf32; fused q/k/v GEMM+LIF; coalesced f64 fixup
    tpose<0><<<128 * 6, 256, 0, stream>>>(x, nullptr, XT_h, XT_l, XTf32, nullptr, C_, 6);
    gemm_lif<2, 0, 3><<<98 * 6 * 3, 256, 0, stream>>>(
        XT_h, XT_l, WHq, WHk, WHv, WLq, WLk, WLv,
        nullptr, nullptr, nullptr, q_bn, k_bn, v_bn, q_lw, k_lw, v_lw,
        SQ, SK, SV, nullptr, nullptr, nullptr, cnt + 0, flQ, C_, C_, 6);
    fixup_t<0, 0><<<512, 256, 0, stream>>>(
        XTf32, nullptr, q_w, k_w, v_w, nullptr, nullptr, nullptr,
        q_bn, k_bn, v_bn, q_lw, k_lw, v_lw,
        SQ, SK, SV, nullptr, nullptr, nullptr, cnt + 0, flQ, C_, C_);

    // 2. attention + LIF (exact)
    attn_lif_kernel<<<B_ * NH_, 256, 0, stream>>>(SQ, SK, SV, SATT, attn_lw);

    // 3. proj: SATT -> SATT_T (exact bf16); GEMM; fixup reads SATT_T
    tpose<1><<<128 * 6, 256, 0, stream>>>(SATT, nullptr, SATT_T, nullptr, nullptr, nullptr, C_, 6);
    gemm_lif<1, 0, 1><<<98 * 6, 256, 0, stream>>>(
        SATT_T, nullptr, WHp, WHp, WHp, WLp, WLp, WLp,
        proj_b, proj_b, proj_b, proj_bn, proj_bn, proj_bn, proj_lw, proj_lw, proj_lw,
        SP, SP, SP, nullptr, nullptr, nullptr, cnt + 1, flP, C_, C_, 6);
    fixup_t<1, 0><<<512, 256, 0, stream>>>(
        SATT_T, nullptr, proj_w, proj_w, proj_w, proj_b, proj_b, proj_b,
        proj_bn, proj_bn, proj_bn, proj_lw, proj_lw, proj_lw,
        SP, SP, SP, nullptr, nullptr, nullptr, cnt + 1, flP, C_, C_);

    // 4. fc1: (x+SP) -> XT hi/lo + SPT; GEMM; fixup reads XTf32 + SPT
    tpose<0><<<128 * 6, 256, 0, stream>>>(x, SP, XT_h, XT_l, nullptr, SPT, C_, 6);
    gemm_lif<2, 0, 1><<<98 * 24, 256, 0, stream>>>(
        XT_h, XT_l, WH1, WH1, WH1, WL1, WL1, WL1,
        fc1_b, fc1_b, fc1_b, fc1_bn, fc1_bn, fc1_bn, fc1_lw, fc1_lw, fc1_lw,
        SZ, SZ, SZ, nullptr, nullptr, nullptr, cnt + 2, fl1, HID_, C_, 24);
    fixup_t<2, 0><<<512, 256, 0, stream>>>(
        XTf32, SPT, fc1_w, fc1_w, fc1_w, fc1_b, fc1_b, fc1_b,
        fc1_bn, fc1_bn, fc1_bn, fc1_lw, fc1_lw, fc1_lw,
        SZ, SZ, SZ, nullptr, nullptr, nullptr, cnt + 2, fl1, HID_, C_);

    // 5. fc2: SZ -> SZT (exact bf16, overlays region A); GEMM -> out; fixup
    tpose<1><<<128 * 24, 256, 0, stream>>>(SZ, nullptr, SZT, nullptr, nullptr, nullptr, HID_, 24);
    gemm_lif<1, 1, 1><<<98 * 6, 256, 0, stream>>>(
        SZT, nullptr, WH2, WH2, WH2, WL2, WL2, WL2,
        fc2_b, fc2_b, fc2_b, fc2_bn, fc2_bn, fc2_bn, fc2_lw, fc2_lw, fc2_lw,
        nullptr, nullptr, nullptr, x, SP, out, cnt + 3, fl2, C_, HID_, 6);
    fixup_t<1, 1><<<512, 256, 0, stream>>>(
        SZT, nullptr, fc2_w, fc2_w, fc2_w, fc2_b, fc2_b, fc2_b,
        fc2_bn, fc2_bn, fc2_bn, fc2_lw, fc2_lw, fc2_lw,
        nullptr, nullptr, nullptr, x, SP, out, cnt + 3, fl2, C_, HID_);
}

// Round 12
// 1139.394 us; speedup vs baseline: 6.1256x; 1.2407x over previous
//
#include <hip/hip_runtime.h>
#include <math.h>

#define T_   4
#define B_   32
#define C_   384
#define N_   196
#define HID_ 1536
#define NH_  12
#define DH_  32
#define NCOL (B_*N_)            // 6272 columns j=(b,n)
#define NJT  (NCOL/16)          // 392 j-tiles of 16
#define THRESH 2e-3f            // certainty margin (worst-case MFMA-path err ~3e-4)
#define FCAP (1u<<17)

typedef unsigned char u8;
typedef unsigned int  u32;
using bf16x8 = __attribute__((ext_vector_type(8))) short;
using f32x4  = __attribute__((ext_vector_type(4))) float;

__device__ __forceinline__ float bfbits2f(short u) {
    union { u32 i; float f; } c; c.i = ((u32)(unsigned short)u) << 16; return c.f;
}
__device__ __forceinline__ short f2bf(float f) {       // RNE f32 -> bf16 bits
    u32 b = __float_as_uint(f);
    return (short)((b + 0x7FFFu + ((b >> 16) & 1u)) >> 16);
}

__global__ void zero_counters(u32* cnt) { if (threadIdx.x < 4) cnt[threadIdx.x] = 0; }

// ---------------------------------------------------------------------------
// Weight split -> FRAGMENT-MAJOR layout.
// frag[((ot*nkb + kb)<<9) + lane*8 + i] = W[ot*16 + (lane&15)][kb*32 + (lane>>4)*8 + i]
// Same per-lane data as r8-r11 row-major loads -> MFMA results bit-identical;
// but GEMM wave loads become contiguous 1KB bursts instead of 16-line gathers.
// ---------------------------------------------------------------------------
__global__ void wprep(const float* __restrict__ W, short* __restrict__ H,
                      short* __restrict__ L, int c_out, int c_in)
{
    const int ng = c_out * (c_in >> 3);
    int i = blockIdx.x * 256 + threadIdx.x;
    if (i >= ng) return;
    const int o = i / (c_in >> 3);
    const int c = (i % (c_in >> 3)) << 3;
    const int ot = o >> 4, ol = o & 15;
    const int kb = c >> 5, part = (c & 31) >> 3;
    const int nkb = c_in >> 5;
    const size_t fp = (((size_t)(ot * nkb + kb)) << 9) + (size_t)((ol + (part << 4)) << 3);
    short h8[8], l8[8];
#pragma unroll
    for (int k = 0; k < 8; ++k) {
        float f = W[(size_t)o * c_in + c + k];
        short h = f2bf(f);
        h8[k] = h;
        l8[k] = f2bf(f - bfbits2f(h));
    }
    *(bf16x8*)&H[fp] = *(bf16x8*)h8;
    *(bf16x8*)&L[fp] = *(bf16x8*)l8;
}

// ---------------------------------------------------------------------------
// Transpose [tb][c][n] -> fragment-major B tiles (+ optional exact linear
// copies for the f64 fixups).
// MODE 0: f32 src (+optional u8 Sadd) -> hi+lo frags of (x+s); optional exact
//         linear-transposed f32 F and u8 SPT.  MODE 1: u8 spikes -> hi frag.
// fragpos = (((t*NJT + jt)*nkb + kb)<<9) + (jl + 16*part)*8 + elem
// ---------------------------------------------------------------------------
template<int MODE>
__global__ __launch_bounds__(256) void tpose(
    const void* __restrict__ src, const u8* __restrict__ Sadd,
    short* __restrict__ H, short* __restrict__ L,
    float* __restrict__ F, u8* __restrict__ SPTo,
    int c_tot, int nct)
{
    __shared__ float lds[64][197];
    __shared__ u8 slds[MODE == 0 ? 64 : 1][MODE == 0 ? 197 : 1];
    const int tid = threadIdx.x;
    const int tb = blockIdx.x / nct;
    const int ct = blockIdx.x % nct;
    const int t = tb / B_, b = tb % B_;
    const int nkb = c_tot >> 5;
    const float* Xf = (const float*)src;
    const u8*    Xb = (const u8*)src;

    for (int i = tid; i < 64 * N_; i += 256) {
        int c = i / N_, n = i % N_;
        size_t g = ((size_t)tb * c_tot + ct * 64 + c) * N_ + n;
        if (MODE == 0) {
            float v = Xf[g];
            u8 s = Sadd ? Sadd[g] : (u8)0;
            lds[c][n] = v + (float)s;
            slds[c][n] = s;
        } else {
            lds[c][n] = (float)Xb[g];
        }
    }
    __syncthreads();

    for (int i = tid; i < N_ * 8; i += 256) {
        const int n = i >> 3;
        const int c_loc = (i & 7) << 3;
        const int c = ct * 64 + c_loc;
        const int j = b * N_ + n;
        const int jt = j >> 4, jl = j & 15;
        const int kb = c >> 5, part = (c & 31) >> 3;
        const size_t fp = (((size_t)(t * NJT + jt) * nkb + kb) << 9)
                        + (size_t)((jl + (part << 4)) << 3);
        short h8[8], l8[8];
        float f8[8];
#pragma unroll
        for (int k = 0; k < 8; ++k) {
            float f = lds[c_loc + k][n];
            f8[k] = f;
            short h = f2bf(f);
            h8[k] = h;
            if (MODE == 0) l8[k] = f2bf(f - bfbits2f(h));
        }
        *(bf16x8*)&H[fp] = *(bf16x8*)h8;
        if (MODE == 0) {
            *(bf16x8*)&L[fp] = *(bf16x8*)l8;
            if (F) {
                const size_t lp = ((size_t)(t * NCOL + j)) * c_tot + c;
                *(float4*)&F[lp]     = *(float4*)&f8[0];
                *(float4*)&F[lp + 4] = *(float4*)&f8[4];
            }
            if (SPTo) {
                const size_t lp = ((size_t)(t * NCOL + j)) * c_tot + c;
#pragma unroll
                for (int k = 0; k < 8; ++k) SPTo[lp + k] = slds[c_loc + k][n];
            }
        }
    }
}

// ---------------------------------------------------------------------------
// MFMA GEMM + BN + LIF + flagging.  C[o,j,t] = sum_c W[o,c] X[t,j,c].
// Block: 64o x 64m; 4 waves split m.  Bijective XCD swizzle (r10).
// r12: fragment-major operands -> every wave load is a contiguous 1KB burst.
// lo x lo MFMA dropped (err ~5e-5 << THRESH; fixup net covers near-threshold).
// D: col = lane&15, row = (lane>>4)*4 + reg  [m89-verified].
// ---------------------------------------------------------------------------
template<int SPLITS, int OM, int NZ>
__global__ __launch_bounds__(256) void gemm_lif(
    const short* __restrict__ BH, const short* __restrict__ BL,
    const short* __restrict__ WH0, const short* __restrict__ WH1, const short* __restrict__ WH2,
    const short* __restrict__ WL0, const short* __restrict__ WL1, const short* __restrict__ WL2,
    const float* __restrict__ cb0, const float* __restrict__ cb1, const float* __restrict__ cb2,
    const float* __restrict__ bn0, const float* __restrict__ bn1, const float* __restrict__ bn2,
    const float* __restrict__ lw0, const float* __restrict__ lw1, const float* __restrict__ lw2,
    u8* S0, u8* S1, u8* S2,
    const float* __restrict__ xres, const u8* __restrict__ sres, float* __restrict__ out,
    u32* __restrict__ cnt, u32* __restrict__ flags,
    int c_out, int c_in, int nob)
{
    const int tid = threadIdx.x;
    const int w = tid >> 6, l = tid & 63;

    // ---- bijective XCD-contiguity swizzle (8 XCDs, m204 formula) ----
    const u32 nwg = gridDim.x;
    const u32 q = nwg >> 3, r = nwg & 7;
    const u32 xcd = blockIdx.x & 7, off = blockIdx.x >> 3;
    const u32 id = (xcd < r ? xcd * (q + 1) : r * (q + 1) + (xcd - r) * q) + off;

    const int mt  = (int)(id / (u32)(nob * NZ));
    const int rem = (int)(id % (u32)(nob * NZ));
    const int z  = (NZ == 1) ? 0 : (rem % NZ);
    const int ob = (NZ == 1) ? rem : (rem / NZ);

    const short* WH = (z == 0) ? WH0 : ((z == 1) ? WH1 : WH2);
    const short* WL = (z == 0) ? WL0 : ((z == 1) ? WL1 : WL2);
    const float* cb  = (z == 0) ? cb0 : ((z == 1) ? cb1 : cb2);
    const float* bnp = (z == 0) ? bn0 : ((z == 1) ? bn1 : bn2);
    const float* lw  = (z == 0) ? lw0 : ((z == 1) ? lw1 : lw2);
    u8* SOUT         = (z == 0) ? S0  : ((z == 1) ? S1  : S2);

    const int nkb = c_in >> 5;
    const size_t tstrf = (size_t)NJT * nkb * 512;
    const int jt = mt * 4 + w;
    const int j  = jt * 16 + (l & 15);
    const int ob64 = ob * 64;

    f32x4 acc[4][4];
#pragma unroll
    for (int t = 0; t < 4; ++t)
#pragma unroll
        for (int os = 0; os < 4; ++os)
            acc[t][os] = (f32x4){0.f, 0.f, 0.f, 0.f};

    const short* bhp = BH + (size_t)jt * nkb * 512 + (size_t)l * 8;
    const short* blp = (SPLITS == 2) ? (BL + (size_t)jt * nkb * 512 + (size_t)l * 8) : nullptr;
    const short* ahp = WH + (size_t)(ob * 4) * nkb * 512 + (size_t)l * 8;
    const short* alp = WL + (size_t)(ob * 4) * nkb * 512 + (size_t)l * 8;

    // ping/pong B fragment sets (statically named; no dynamic indexing)
    bf16x8 bhA[4], blA[4], bhB[4], blB[4];

    auto LOADB = [&](int kb, bf16x8* bh, bf16x8* bl) {
#pragma unroll
        for (int t = 0; t < 4; ++t) {
            bh[t] = *(const bf16x8*)(bhp + (size_t)t * tstrf + (size_t)kb * 512);
            if (SPLITS == 2) bl[t] = *(const bf16x8*)(blp + (size_t)t * tstrf + (size_t)kb * 512);
        }
    };
    auto COMPUTE = [&](int kb, const bf16x8* bh, const bf16x8* bl) {
        bf16x8 ah[4], al[4];
#pragma unroll
        for (int os = 0; os < 4; ++os) {
            ah[os] = *(const bf16x8*)(ahp + (size_t)(os * nkb + kb) * 512);
            al[os] = *(const bf16x8*)(alp + (size_t)(os * nkb + kb) * 512);
        }
#pragma unroll
        for (int os = 0; os < 4; ++os) {
#pragma unroll
            for (int t = 0; t < 4; ++t) {
                acc[t][os] = __builtin_amdgcn_mfma_f32_16x16x32_bf16(ah[os], bh[t], acc[t][os], 0, 0, 0);
                acc[t][os] = __builtin_amdgcn_mfma_f32_16x16x32_bf16(al[os], bh[t], acc[t][os], 0, 0, 0);
                if (SPLITS == 2)   // lo x lo term dropped (r11)
                    acc[t][os] = __builtin_amdgcn_mfma_f32_16x16x32_bf16(ah[os], bl[t], acc[t][os], 0, 0, 0);
            }
        }
    };

    LOADB(0, bhA, blA);
    for (int kb = 0; kb < nkb; kb += 2) {
        LOADB(kb + 1, bhB, blB);
        COMPUTE(kb, bhA, blA);
        if (kb + 2 < nkb) LOADB(kb + 2, bhA, blA);
        COMPUTE(kb + 1, bhB, blB);
    }

    const float tau = 1.0f / (1.0f + expf(-lw[0]));
    const size_t per_t = (size_t)B_ * c_out * N_;
    const int jb = j / N_, jn = j % N_;
#pragma unroll
    for (int os = 0; os < 4; ++os) {
#pragma unroll
        for (int r2 = 0; r2 < 4; ++r2) {
            const int o = ob64 + os * 16 + (l >> 4) * 4 + r2;
            const float g  = bnp[o];
            const float be = bnp[c_out + o];
            const float mm = bnp[2 * c_out + o];
            const float vv = bnp[3 * c_out + o];
            const float inv   = g / sqrtf(vv + 1e-5f);
            const float shift = be - mm * inv;
            const float cbv   = cb ? cb[o] : 0.0f;
            const size_t idx0 = ((size_t)jb * c_out + o) * N_ + jn;
            float v = 0.0f;
            bool flag = false;
#pragma unroll
            for (int t = 0; t < 4; ++t) {
                const float yv = (acc[t][os][r2] + cbv) * inv + shift;
                const float h  = v + (yv - v) * tau;
                const float sp = (h >= 1.0f) ? 1.0f : 0.0f;
                flag = flag || (fabsf(h - 1.0f) < THRESH);
                v = h * (1.0f - sp);
                const size_t idx = (size_t)t * per_t + idx0;
                if (OM == 0) SOUT[idx] = (u8)sp;
                else out[idx] = (float)((double)xres[idx] + (double)sres[idx] + (double)sp);
            }
            if (flag) {
                u32 p = atomicAdd(cnt, 1u);
                if (p < FCAP) flags[p] = ((u32)(z * c_out + o)) * (u32)NCOL + (u32)j;
            }
        }
    }
}

// ---------------------------------------------------------------------------
// f64 fixup (decision math = r5/r7-proven all-f64 path).
// IN_MODE 0: linear f32 XT [t*NCOL+j][c]
// IN_MODE 1: fragment-major bf16 (exact spikes)  [reads frag layout directly]
// IN_MODE 2: linear f32 XT + linear u8 SPT
// ---------------------------------------------------------------------------
template<int IN_MODE, int OM>
__global__ __launch_bounds__(256) void fixup_t(
    const void* __restrict__ XT, const u8* __restrict__ SPT,
    const float* __restrict__ W0, const float* __restrict__ W1, const float* __restrict__ W2,
    const float* __restrict__ cb0, const float* __restrict__ cb1, const float* __restrict__ cb2,
    const float* __restrict__ bn0, const float* __restrict__ bn1, const float* __restrict__ bn2,
    const float* __restrict__ lw0, const float* __restrict__ lw1, const float* __restrict__ lw2,
    u8* S0, u8* S1, u8* S2,
    const float* __restrict__ xres, const u8* __restrict__ sres, float* out,
    const u32* __restrict__ cnt, const u32* __restrict__ flags,
    int c_out, int c_in)
{
    const int lane = threadIdx.x & 63;
    const int wid  = (blockIdx.x * 256 + threadIdx.x) >> 6;
    const int nw   = (gridDim.x * 256) >> 6;
    u32 nrec = *cnt;
    if (nrec > FCAP) nrec = FCAP;

    const float* XTf = (const float*)XT;
    const short* XTs = (const short*)XT;
    const int nkb = c_in >> 5;

    for (u32 r = wid; r < nrec; r += nw) {
        const u32 rec = flags[r];
        const int j  = (int)(rec % (u32)NCOL);
        const u32 zo = rec / (u32)NCOL;
        const int z  = (int)(zo / (u32)c_out);
        const int o  = (int)(zo % (u32)c_out);
        const int jt = j >> 4, jl = j & 15;

        const float* W   = (z == 0) ? W0  : ((z == 1) ? W1  : W2);
        const float* cb  = (z == 0) ? cb0 : ((z == 1) ? cb1 : cb2);
        const float* bnp = (z == 0) ? bn0 : ((z == 1) ? bn1 : bn2);
        const float* lw  = (z == 0) ? lw0 : ((z == 1) ? lw1 : lw2);
        u8* SOUT         = (z == 0) ? S0  : ((z == 1) ? S1  : S2);

        double acc[4] = {0.0, 0.0, 0.0, 0.0};
        for (int c = lane; c < c_in; c += 64) {
            const double w = (double)W[(size_t)o * c_in + c];
#pragma unroll
            for (int t = 0; t < 4; ++t) {
                double xval;
                if (IN_MODE == 1) {
                    const int kb = c >> 5, part = (c & 31) >> 3, elem = c & 7;
                    const size_t idx = (((size_t)(t * NJT + jt) * nkb + kb) << 9)
                                     + (size_t)((jl + (part << 4)) << 3) + elem;
                    xval = (double)bfbits2f(XTs[idx]);
                } else {
                    const size_t i = ((size_t)(t * NCOL + j)) * c_in + c;
                    if (IN_MODE == 0) xval = (double)XTf[i];
                    else              xval = (double)XTf[i] + (double)SPT[i];
                }
                acc[t] = fma(w, xval, acc[t]);
            }
        }
#pragma unroll
        for (int m = 32; m; m >>= 1) {
#pragma unroll
            for (int t = 0; t < 4; ++t)
                acc[t] += __shfl_xor(acc[t], m, 64);
        }

        if (lane == 0) {
            const double tau = 1.0 / (1.0 + exp(-(double)lw[0]));
            const double g  = (double)bnp[o];
            const double be = (double)bnp[c_out + o];
            const double mm = (double)bnp[2 * c_out + o];
            const double vv = (double)bnp[3 * c_out + o];
            const double inv   = g / sqrt(vv + 1e-5);
            const double shift = be - mm * inv;
            const double cbv   = cb ? (double)cb[o] : 0.0;
            const size_t per_t = (size_t)B_ * c_out * N_;
            const int jb = j / N_, jn = j % N_;
            const size_t idx0  = ((size_t)jb * c_out + o) * N_ + jn;
            double v = 0.0;
#pragma unroll
            for (int t = 0; t < 4; ++t) {
                const double yv = (acc[t] + cbv) * inv + shift;
                const double h  = v + (yv - v) * tau;
                const double sp = (h >= 1.0) ? 1.0 : 0.0;
                v = h * (1.0 - sp);
                const size_t idx = (size_t)t * per_t + idx0;
                if (OM == 0) SOUT[idx] = (u8)sp;
                else out[idx] = (float)((double)xres[idx] + (double)sres[idx] + sp);
            }
        }
    }
}

// ---------------------------------------------------------------------------
// Spike attention + fused LIF (exact dyadic arithmetic, r5-r11 proven).
// ---------------------------------------------------------------------------
__global__ __launch_bounds__(256) void attn_lif_kernel(
    const u8* __restrict__ SQ, const u8* __restrict__ SK, const u8* __restrict__ SV,
    u8* __restrict__ SATT, const float* __restrict__ lw)
{
    __shared__ u8 q_lds[DH_ * N_];
    __shared__ u8 k_lds[DH_ * N_];
    __shared__ u8 v_lds[DH_ * N_];
    __shared__ float kv_lds[DH_ * DH_];
    __shared__ float vstate[DH_ * N_];
    const int tid = threadIdx.x;
    const int b = blockIdx.x / NH_, h = blockIdx.x % NH_;
    const float tau = 1.0f / (1.0f + expf(-lw[0]));

    for (int i = tid; i < DH_ * N_; i += 256) vstate[i] = 0.0f;

    for (int t = 0; t < T_; ++t) {
        const size_t base = ((size_t)((t * B_ + b) * C_) + h * DH_) * N_;
        __syncthreads();
        for (int i = tid; i < DH_ * N_ / 4; i += 256) {
            ((unsigned int*)q_lds)[i] = ((const unsigned int*)(SQ + base))[i];
            ((unsigned int*)k_lds)[i] = ((const unsigned int*)(SK + base))[i];
            ((unsigned int*)v_lds)[i] = ((const unsigned int*)(SV + base))[i];
        }
        __syncthreads();

#pragma unroll
        for (int r = 0; r < 4; ++r) {
            const int e = tid + 256 * r;
            const int i = e >> 5, jj = e & 31;
            int s = 0;
            for (int nn = 0; nn < N_; nn += 4) {
                uchar4 kk = *(const uchar4*)&k_lds[i * N_ + nn];
                uchar4 uv = *(const uchar4*)&v_lds[jj * N_ + nn];
                s += kk.x * uv.x + kk.y * uv.y + kk.z * uv.z + kk.w * uv.w;
            }
            kv_lds[e] = (float)s;
        }
        __syncthreads();

        for (int e = tid; e < DH_ * N_; e += 256) {
            const int jj = e / N_, nn = e % N_;
            float s = 0.0f;
#pragma unroll
            for (int i = 0; i < DH_; ++i)
                s += q_lds[i * N_ + nn] ? kv_lds[i * DH_ + jj] : 0.0f;
            const float att = 0.125f * s;
            const float v = vstate[e];
            const float hh = v + (att - v) * tau;
            const float sp = (hh >= 1.0f) ? 1.0f : 0.0f;
            vstate[e] = hh * (1.0f - sp);
            SATT[base + e] = (u8)sp;
        }
    }
}

// ---------------------------------------------------------------------------
extern "C" void kernel_launch(void* const* d_in, const int* in_sizes, int n_in,
                              void* d_out, int out_size, void* d_ws, size_t ws_size,
                              hipStream_t stream)
{
    const float* x       = (const float*)d_in[0];
    const float* q_w     = (const float*)d_in[1];
    const float* q_bn    = (const float*)d_in[2];
    const float* q_lw    = (const float*)d_in[3];
    const float* k_w     = (const float*)d_in[4];
    const float* k_bn    = (const float*)d_in[5];
    const float* k_lw    = (const float*)d_in[6];
    const float* v_w     = (const float*)d_in[7];
    const float* v_bn    = (const float*)d_in[8];
    const float* v_lw    = (const float*)d_in[9];
    const float* attn_lw = (const float*)d_in[10];
    const float* proj_w  = (const float*)d_in[11];
    const float* proj_b  = (const float*)d_in[12];
    const float* proj_bn = (const float*)d_in[13];
    const float* proj_lw = (const float*)d_in[14];
    const float* fc1_w   = (const float*)d_in[15];
    const float* fc1_b   = (const float*)d_in[16];
    const float* fc1_bn  = (const float*)d_in[17];
    const float* fc1_lw  = (const float*)d_in[18];
    const float* fc2_w   = (const float*)d_in[19];
    const float* fc2_b   = (const float*)d_in[20];
    const float* fc2_bn  = (const float*)d_in[21];
    const float* fc2_lw  = (const float*)d_in[22];

    // ---- workspace layout (~154 MB), phase-aliased ----
    u8* base = (u8*)d_ws;
    float* XTf32   = (float*)(base);                // [0, 38.5M)   ph1-4 (exact x, linear-T)
    short* XTfr_h  = (short*)(base + 38535168);     // [38.5, 57.8) ph1 & ph4 (frag)
    short* XTfr_l  = (short*)(base + 57802752);     // [57.8, 77.1) ph1 & ph4 (frag)
    short* SZfrag  = (short*)(base);                // [0, 77.1)    ph5 overlay (frag, c=1536)
    u8*    SQ      = base + 77070336;               // 9,633,792 each, ph1-2
    u8*    SK      = base + 86704128;
    u8*    SV      = base + 96337920;
    u8*    SATT    = base + 105971712;              // ph2-3
    u8*    SZ      = base + 77070336;               // ph4-5 overlay of SQ..SATT (u8 row-major)
    short* SATTfr  = (short*)(base + 115605504);    // 19.3M, ph3 (frag)
    u8*    SPT     = base + 115605504;              // 9.6M,  ph4 overlay (linear-T u8)
    u8*    SP      = base + 134873088;              // 9.6M,  ph3-5
    u32*   cnt     = (u32*)(base + 144506880);      // 256 B
    u32*   flags   = (u32*)(base + 144507136);      // 2.1M
    short* WHb     = (short*)(base + 146604288);    // 3.54M (frag)
    short* WLb     = (short*)(base + 150143232);    // 3.54M -> ends ~153.7M
    float* out = (float*)d_out;

    short *WHq = WHb,          *WHk = WHb + 147456, *WHv = WHb + 294912,
          *WHp = WHb + 442368, *WH1 = WHb + 589824, *WH2 = WHb + 1179648;
    short *WLq = WLb,          *WLk = WLb + 147456, *WLv = WLb + 294912,
          *WLp = WLb + 442368, *WL1 = WLb + 589824, *WL2 = WLb + 1179648;
    u32 *flQ = flags, *flP = flags + FCAP, *fl1 = flags + 2 * FCAP, *fl2 = flags + 3 * FCAP;

    zero_counters<<<1, 64, 0, stream>>>(cnt);

    // 0. weight splits -> fragment layout (grid over c_out * c_in/8)
    wprep<<<72, 256, 0, stream>>>(q_w,    WHq, WLq, C_, C_);
    wprep<<<72, 256, 0, stream>>>(k_w,    WHk, WLk, C_, C_);
    wprep<<<72, 256, 0, stream>>>(v_w,    WHv, WLv, C_, C_);
    wprep<<<72, 256, 0, stream>>>(proj_w, WHp, WLp, C_, C_);
    wprep<<<288, 256, 0, stream>>>(fc1_w, WH1, WL1, HID_, C_);
    wprep<<<288, 256, 0, stream>>>(fc2_w, WH2, WL2, C_, HID_);

    // 1. x -> frags + exact linear XTf32; fused q/k/v GEMM+LIF; f64 fixup
    tpose<0><<<128 * 6, 256, 0, stream>>>(x, nullptr, XTfr_h, XTfr_l, XTf32, nullptr, C_, 6);
    gemm_lif<2, 0, 3><<<98 * 6 * 3, 256, 0, stream>>>(
        XTfr_h, XTfr_l, WHq, WHk, WHv, WLq, WLk, WLv,
        nullptr, nullptr, nullptr, q_bn, k_bn, v_bn, q_lw, k_lw, v_lw,
        SQ, SK, SV, nullptr, nullptr, nullptr, cnt + 0, flQ, C_, C_, 6);
    fixup_t<0, 0><<<512, 256, 0, stream>>>(
        XTf32, nullptr, q_w, k_w, v_w, nullptr, nullptr, nullptr,
        q_bn, k_bn, v_bn, q_lw, k_lw, v_lw,
        SQ, SK, SV, nullptr, nullptr, nullptr, cnt + 0, flQ, C_, C_);

    // 2. attention + LIF (exact)
    attn_lif_kernel<<<B_ * NH_, 256, 0, stream>>>(SQ, SK, SV, SATT, attn_lw);

    // 3. proj: SATT -> frag (exact bf16); GEMM; fixup reads frag directly
    tpose<1><<<128 * 6, 256, 0, stream>>>(SATT, nullptr, SATTfr, nullptr, nullptr, nullptr, C_, 6);
    gemm_lif<1, 0, 1><<<98 * 6, 256, 0, stream>>>(
        SATTfr, nullptr, WHp, WHp, WHp, WLp, WLp, WLp,
        proj_b, proj_b, proj_b, proj_bn, proj_bn, proj_bn, proj_lw, proj_lw, proj_lw,
        SP, SP, SP, nullptr, nullptr, nullptr, cnt + 1, flP, C_, C_, 6);
    fixup_t<1, 0><<<512, 256, 0, stream>>>(
        SATTfr, nullptr, proj_w, proj_w, proj_w, proj_b, proj_b, proj_b,
        proj_bn, proj_bn, proj_bn, proj_lw, proj_lw, proj_lw,
        SP, SP, SP, nullptr, nullptr, nullptr, cnt + 1, flP, C_, C_);

    // 4. fc1: (x+SP) -> frags + SPT; GEMM; fixup reads XTf32 + SPT
    tpose<0><<<128 * 6, 256, 0, stream>>>(x, SP, XTfr_h, XTfr_l, nullptr, SPT, C_, 6);
    gemm_lif<2, 0, 1><<<98 * 24, 256, 0, stream>>>(
        XTfr_h, XTfr_l, WH1, WH1, WH1, WL1, WL1, WL1,
        fc1_b, fc1_b, fc1_b, fc1_bn, fc1_bn, fc1_bn, fc1_lw, fc1_lw, fc1_lw,
        SZ, SZ, SZ, nullptr, nullptr, nullptr, cnt + 2, fl1, HID_, C_, 24);
    fixup_t<2, 0><<<512, 256, 0, stream>>>(
        XTf32, SPT, fc1_w, fc1_w, fc1_w, fc1_b, fc1_b, fc1_b,
        fc1_bn, fc1_bn, fc1_bn, fc1_lw, fc1_lw, fc1_lw,
        SZ, SZ, SZ, nullptr, nullptr, nullptr, cnt + 2, fl1, HID_, C_);

    // 5. fc2: SZ -> frag (exact bf16, overlays region A); GEMM -> out; fixup
    tpose<1><<<128 * 24, 256, 0, stream>>>(SZ, nullptr, SZfrag, nullptr, nullptr, nullptr, HID_, 24);
    gemm_lif<1, 1, 1><<<98 * 6, 256, 0, stream>>>(
        SZfrag, nullptr, WH2, WH2, WH2, WL2, WL2, WL2,
        fc2_b, fc2_b, fc2_b, fc2_bn, fc2_bn, fc2_bn, fc2_lw, fc2_lw, fc2_lw,
        nullptr, nullptr, nullptr, x, SP, out, cnt + 3, fl2, C_, HID_, 6);
    fixup_t<1, 1><<<512, 256, 0, stream>>>(
        SZfrag, nullptr, fc2_w, fc2_w, fc2_w, fc2_b, fc2_b, fc2_b,
        fc2_bn, fc2_bn, fc2_bn, fc2_lw, fc2_lw, fc2_lw,
        nullptr, nullptr, nullptr, x, SP, out, cnt + 3, fl2, C_, HID_);
}

// Round 13
// 1029.599 us; speedup vs baseline: 6.7788x; 1.1066x over previous
//
#include <hip/hip_runtime.h>
#include <math.h>

#define T_   4
#define B_   32
#define C_   384
#define N_   196
#define HID_ 1536
#define NH_  12
#define DH_  32
#define NCOL (B_*N_)            // 6272 columns j=(b,n)
#define NJT  (NCOL/16)          // 392 j-tiles of 16
#define THRESH 2e-3f            // certainty margin (worst-case MFMA-path err ~3e-4)
#define FCAP (1u<<17)

typedef unsigned char u8;
typedef unsigned int  u32;
using bf16x8 = __attribute__((ext_vector_type(8))) short;
using f32x4  = __attribute__((ext_vector_type(4))) float;

__device__ __forceinline__ float bfbits2f(short u) {
    union { u32 i; float f; } c; c.i = ((u32)(unsigned short)u) << 16; return c.f;
}
__device__ __forceinline__ short f2bf(float f) {       // RNE f32 -> bf16 bits
    u32 b = __float_as_uint(f);
    return (short)((b + 0x7FFFu + ((b >> 16) & 1u)) >> 16);
}

__device__ __forceinline__ void gload_lds16(const short* g, short* l) {
    __builtin_amdgcn_global_load_lds(
        (const __attribute__((address_space(1))) void*)g,
        (__attribute__((address_space(3))) void*)l, 16, 0, 0);
}

__global__ void zero_counters(u32* cnt) { if (threadIdx.x < 4) cnt[threadIdx.x] = 0; }

// ---------------------------------------------------------------------------
// Weight split -> FRAGMENT-MAJOR layout (r12-proven).
// frag[((ot*nkb + kb)<<9) + lane*8 + i] = W[ot*16 + (lane&15)][kb*32 + (lane>>4)*8 + i]
// ---------------------------------------------------------------------------
__global__ void wprep(const float* __restrict__ W, short* __restrict__ H,
                      short* __restrict__ L, int c_out, int c_in)
{
    const int ng = c_out * (c_in >> 3);
    int i = blockIdx.x * 256 + threadIdx.x;
    if (i >= ng) return;
    const int o = i / (c_in >> 3);
    const int c = (i % (c_in >> 3)) << 3;
    const int ot = o >> 4, ol = o & 15;
    const int kb = c >> 5, part = (c & 31) >> 3;
    const int nkb = c_in >> 5;
    const size_t fp = (((size_t)(ot * nkb + kb)) << 9) + (size_t)((ol + (part << 4)) << 3);
    short h8[8], l8[8];
#pragma unroll
    for (int k = 0; k < 8; ++k) {
        float f = W[(size_t)o * c_in + c + k];
        short h = f2bf(f);
        h8[k] = h;
        l8[k] = f2bf(f - bfbits2f(h));
    }
    *(bf16x8*)&H[fp] = *(bf16x8*)h8;
    *(bf16x8*)&L[fp] = *(bf16x8*)l8;
}

// ---------------------------------------------------------------------------
// Transpose [tb][c][n] -> fragment-major B tiles (+ optional exact linear
// copies for the f64 fixups).  (r12-proven)
// ---------------------------------------------------------------------------
template<int MODE>
__global__ __launch_bounds__(256) void tpose(
    const void* __restrict__ src, const u8* __restrict__ Sadd,
    short* __restrict__ H, short* __restrict__ L,
    float* __restrict__ F, u8* __restrict__ SPTo,
    int c_tot, int nct)
{
    __shared__ float lds[64][197];
    __shared__ u8 slds[MODE == 0 ? 64 : 1][MODE == 0 ? 197 : 1];
    const int tid = threadIdx.x;
    const int tb = blockIdx.x / nct;
    const int ct = blockIdx.x % nct;
    const int t = tb / B_, b = tb % B_;
    const int nkb = c_tot >> 5;
    const float* Xf = (const float*)src;
    const u8*    Xb = (const u8*)src;

    for (int i = tid; i < 64 * N_; i += 256) {
        int c = i / N_, n = i % N_;
        size_t g = ((size_t)tb * c_tot + ct * 64 + c) * N_ + n;
        if (MODE == 0) {
            float v = Xf[g];
            u8 s = Sadd ? Sadd[g] : (u8)0;
            lds[c][n] = v + (float)s;
            slds[c][n] = s;
        } else {
            lds[c][n] = (float)Xb[g];
        }
    }
    __syncthreads();

    for (int i = tid; i < N_ * 8; i += 256) {
        const int n = i >> 3;
        const int c_loc = (i & 7) << 3;
        const int c = ct * 64 + c_loc;
        const int j = b * N_ + n;
        const int jt = j >> 4, jl = j & 15;
        const int kb = c >> 5, part = (c & 31) >> 3;
        const size_t fp = (((size_t)(t * NJT + jt) * nkb + kb) << 9)
                        + (size_t)((jl + (part << 4)) << 3);
        short h8[8], l8[8];
        float f8[8];
#pragma unroll
        for (int k = 0; k < 8; ++k) {
            float f = lds[c_loc + k][n];
            f8[k] = f;
            short h = f2bf(f);
            h8[k] = h;
            if (MODE == 0) l8[k] = f2bf(f - bfbits2f(h));
        }
        *(bf16x8*)&H[fp] = *(bf16x8*)h8;
        if (MODE == 0) {
            *(bf16x8*)&L[fp] = *(bf16x8*)l8;
            if (F) {
                const size_t lp = ((size_t)(t * NCOL + j)) * c_tot + c;
                *(float4*)&F[lp]     = *(float4*)&f8[0];
                *(float4*)&F[lp + 4] = *(float4*)&f8[4];
            }
            if (SPTo) {
                const size_t lp = ((size_t)(t * NCOL + j)) * c_tot + c;
#pragma unroll
                for (int k = 0; k < 8; ++k) SPTo[lp + k] = slds[c_loc + k][n];
            }
        }
    }
}

// ---------------------------------------------------------------------------
// MFMA GEMM + BN + LIF + flagging.  C[o,j,t] = sum_c W[o,c] X[t,j,c].
// Block: 64o x 64m; 4 waves split m.  Bijective XCD swizzle (r10).
// r13: A (weights hi+lo) staged once per block into double-buffered LDS via
// global_load_lds (fragment chunks are contiguous 1KB = the exact wave-
// uniform-base + lane*16 pattern); waves ds_read_b128 their fragments
// (conflict-free).  Cuts per-block global loads 64 -> 40 per kb and dedupes
// A traffic 4x.  Per-lane A values bit-identical to r12.
// D: col = lane&15, row = (lane>>4)*4 + reg  [m89-verified].
// ---------------------------------------------------------------------------
template<int SPLITS, int OM, int NZ>
__global__ __launch_bounds__(256) void gemm_lif(
    const short* __restrict__ BH, const short* __restrict__ BL,
    const short* __restrict__ WH0, const short* __restrict__ WH1, const short* __restrict__ WH2,
    const short* __restrict__ WL0, const short* __restrict__ WL1, const short* __restrict__ WL2,
    const float* __restrict__ cb0, const float* __restrict__ cb1, const float* __restrict__ cb2,
    const float* __restrict__ bn0, const float* __restrict__ bn1, const float* __restrict__ bn2,
    const float* __restrict__ lw0, const float* __restrict__ lw1, const float* __restrict__ lw2,
    u8* S0, u8* S1, u8* S2,
    const float* __restrict__ xres, const u8* __restrict__ sres, float* __restrict__ out,
    u32* __restrict__ cnt, u32* __restrict__ flags,
    int c_out, int c_in, int nob)
{
    __shared__ short a_lds[2][8][512];     // [buf][chunk = os*2+split][1KB]
    const int tid = threadIdx.x;
    const int w = tid >> 6, l = tid & 63;

    // ---- bijective XCD-contiguity swizzle (8 XCDs, m204 formula) ----
    const u32 nwg = gridDim.x;
    const u32 q = nwg >> 3, r = nwg & 7;
    const u32 xcd = blockIdx.x & 7, off = blockIdx.x >> 3;
    const u32 id = (xcd < r ? xcd * (q + 1) : r * (q + 1) + (xcd - r) * q) + off;

    const int mt  = (int)(id / (u32)(nob * NZ));
    const int rem = (int)(id % (u32)(nob * NZ));
    const int z  = (NZ == 1) ? 0 : (rem % NZ);
    const int ob = (NZ == 1) ? rem : (rem / NZ);

    const short* WH = (z == 0) ? WH0 : ((z == 1) ? WH1 : WH2);
    const short* WL = (z == 0) ? WL0 : ((z == 1) ? WL1 : WL2);
    const float* cb  = (z == 0) ? cb0 : ((z == 1) ? cb1 : cb2);
    const float* bnp = (z == 0) ? bn0 : ((z == 1) ? bn1 : bn2);
    const float* lw  = (z == 0) ? lw0 : ((z == 1) ? lw1 : lw2);
    u8* SOUT         = (z == 0) ? S0  : ((z == 1) ? S1  : S2);

    const int nkb = c_in >> 5;
    const size_t tstrf = (size_t)NJT * nkb * 512;
    const int jt = mt * 4 + w;
    const int j  = jt * 16 + (l & 15);
    const int ob64 = ob * 64;

    f32x4 acc[4][4];
#pragma unroll
    for (int t = 0; t < 4; ++t)
#pragma unroll
        for (int os = 0; os < 4; ++os)
            acc[t][os] = (f32x4){0.f, 0.f, 0.f, 0.f};

    const short* bhp = BH + (size_t)jt * nkb * 512 + (size_t)l * 8;
    const short* blp = (SPLITS == 2) ? (BL + (size_t)jt * nkb * 512 + (size_t)l * 8) : nullptr;

    // ping/pong B fragment sets (statically named; no dynamic indexing)
    bf16x8 bhA[4], blA[4], bhB[4], blB[4];

    auto LOADB = [&](int kb, bf16x8* bh, bf16x8* bl) {
#pragma unroll
        for (int t = 0; t < 4; ++t) {
            bh[t] = *(const bf16x8*)(bhp + (size_t)t * tstrf + (size_t)kb * 512);
            if (SPLITS == 2) bl[t] = *(const bf16x8*)(blp + (size_t)t * tstrf + (size_t)kb * 512);
        }
    };
    // wave w stages chunks {2w, 2w+1} of A(kb) into buf p (1KB each, lane*16)
    auto STAGE = [&](int kb, int p) {
#pragma unroll
        for (int cc = 0; cc < 2; ++cc) {
            const int ch = w * 2 + cc;
            const int os = ch >> 1, split = ch & 1;
            const short* src = (split ? WL : WH)
                             + (((size_t)(ob * 4 + os) * nkb + kb) << 9) + (size_t)l * 8;
            gload_lds16(src, &a_lds[p][ch][(size_t)l * 8]);
        }
    };
    auto COMPUTE = [&](int p, const bf16x8* bh, const bf16x8* bl) {
        bf16x8 ah[4], al[4];
#pragma unroll
        for (int os = 0; os < 4; ++os) {
            ah[os] = *(const bf16x8*)&a_lds[p][os * 2][(size_t)l * 8];
            al[os] = *(const bf16x8*)&a_lds[p][os * 2 + 1][(size_t)l * 8];
        }
#pragma unroll
        for (int os = 0; os < 4; ++os) {
#pragma unroll
            for (int t = 0; t < 4; ++t) {
                acc[t][os] = __builtin_amdgcn_mfma_f32_16x16x32_bf16(ah[os], bh[t], acc[t][os], 0, 0, 0);
                acc[t][os] = __builtin_amdgcn_mfma_f32_16x16x32_bf16(al[os], bh[t], acc[t][os], 0, 0, 0);
                if (SPLITS == 2)   // lo x lo term dropped (r11)
                    acc[t][os] = __builtin_amdgcn_mfma_f32_16x16x32_bf16(ah[os], bl[t], acc[t][os], 0, 0, 0);
            }
        }
    };

    STAGE(0, 0);
    LOADB(0, bhA, blA);
    __syncthreads();                       // buf0 ready
    for (int kb = 0; kb < nkb; kb += 2) {  // nkb is even (12 or 48)
        STAGE(kb + 1, 1);
        LOADB(kb + 1, bhB, blB);
        COMPUTE(0, bhA, blA);
        __syncthreads();                   // buf1 ready; buf0 free
        if (kb + 2 < nkb) {
            STAGE(kb + 2, 0);
            LOADB(kb + 2, bhA, blA);
        }
        COMPUTE(1, bhB, blB);
        __syncthreads();                   // buf0 ready; buf1 free
    }

    const float tau = 1.0f / (1.0f + expf(-lw[0]));
    const size_t per_t = (size_t)B_ * c_out * N_;
    const int jb = j / N_, jn = j % N_;
#pragma unroll
    for (int os = 0; os < 4; ++os) {
#pragma unroll
        for (int r2 = 0; r2 < 4; ++r2) {
            const int o = ob64 + os * 16 + (l >> 4) * 4 + r2;
            const float g  = bnp[o];
            const float be = bnp[c_out + o];
            const float mm = bnp[2 * c_out + o];
            const float vv = bnp[3 * c_out + o];
            const float inv   = g / sqrtf(vv + 1e-5f);
            const float shift = be - mm * inv;
            const float cbv   = cb ? cb[o] : 0.0f;
            const size_t idx0 = ((size_t)jb * c_out + o) * N_ + jn;
            float v = 0.0f;
            bool flag = false;
#pragma unroll
            for (int t = 0; t < 4; ++t) {
                const float yv = (acc[t][os][r2] + cbv) * inv + shift;
                const float h  = v + (yv - v) * tau;
                const float sp = (h >= 1.0f) ? 1.0f : 0.0f;
                flag = flag || (fabsf(h - 1.0f) < THRESH);
                v = h * (1.0f - sp);
                const size_t idx = (size_t)t * per_t + idx0;
                if (OM == 0) SOUT[idx] = (u8)sp;
                else out[idx] = (float)((double)xres[idx] + (double)sres[idx] + (double)sp);
            }
            if (flag) {
                u32 p = atomicAdd(cnt, 1u);
                if (p < FCAP) flags[p] = ((u32)(z * c_out + o)) * (u32)NCOL + (u32)j;
            }
        }
    }
}

// ---------------------------------------------------------------------------
// f64 fixup (decision math = r5/r7-proven all-f64 path).
// IN_MODE 0: linear f32 XT; 1: fragment-major bf16 (exact spikes);
// 2: linear f32 XT + linear u8 SPT.
// ---------------------------------------------------------------------------
template<int IN_MODE, int OM>
__global__ __launch_bounds__(256) void fixup_t(
    const void* __restrict__ XT, const u8* __restrict__ SPT,
    const float* __restrict__ W0, const float* __restrict__ W1, const float* __restrict__ W2,
    const float* __restrict__ cb0, const float* __restrict__ cb1, const float* __restrict__ cb2,
    const float* __restrict__ bn0, const float* __restrict__ bn1, const float* __restrict__ bn2,
    const float* __restrict__ lw0, const float* __restrict__ lw1, const float* __restrict__ lw2,
    u8* S0, u8* S1, u8* S2,
    const float* __restrict__ xres, const u8* __restrict__ sres, float* out,
    const u32* __restrict__ cnt, const u32* __restrict__ flags,
    int c_out, int c_in)
{
    const int lane = threadIdx.x & 63;
    const int wid  = (blockIdx.x * 256 + threadIdx.x) >> 6;
    const int nw   = (gridDim.x * 256) >> 6;
    u32 nrec = *cnt;
    if (nrec > FCAP) nrec = FCAP;

    const float* XTf = (const float*)XT;
    const short* XTs = (const short*)XT;
    const int nkb = c_in >> 5;

    for (u32 r = wid; r < nrec; r += nw) {
        const u32 rec = flags[r];
        const int j  = (int)(rec % (u32)NCOL);
        const u32 zo = rec / (u32)NCOL;
        const int z  = (int)(zo / (u32)c_out);
        const int o  = (int)(zo % (u32)c_out);
        const int jt = j >> 4, jl = j & 15;

        const float* W   = (z == 0) ? W0  : ((z == 1) ? W1  : W2);
        const float* cb  = (z == 0) ? cb0 : ((z == 1) ? cb1 : cb2);
        const float* bnp = (z == 0) ? bn0 : ((z == 1) ? bn1 : bn2);
        const float* lw  = (z == 0) ? lw0 : ((z == 1) ? lw1 : lw2);
        u8* SOUT         = (z == 0) ? S0  : ((z == 1) ? S1  : S2);

        double acc[4] = {0.0, 0.0, 0.0, 0.0};
        for (int c = lane; c < c_in; c += 64) {
            const double w = (double)W[(size_t)o * c_in + c];
#pragma unroll
            for (int t = 0; t < 4; ++t) {
                double xval;
                if (IN_MODE == 1) {
                    const int kb = c >> 5, part = (c & 31) >> 3, elem = c & 7;
                    const size_t idx = (((size_t)(t * NJT + jt) * nkb + kb) << 9)
                                     + (size_t)((jl + (part << 4)) << 3) + elem;
                    xval = (double)bfbits2f(XTs[idx]);
                } else {
                    const size_t i = ((size_t)(t * NCOL + j)) * c_in + c;
                    if (IN_MODE == 0) xval = (double)XTf[i];
                    else              xval = (double)XTf[i] + (double)SPT[i];
                }
                acc[t] = fma(w, xval, acc[t]);
            }
        }
#pragma unroll
        for (int m = 32; m; m >>= 1) {
#pragma unroll
            for (int t = 0; t < 4; ++t)
                acc[t] += __shfl_xor(acc[t], m, 64);
        }

        if (lane == 0) {
            const double tau = 1.0 / (1.0 + exp(-(double)lw[0]));
            const double g  = (double)bnp[o];
            const double be = (double)bnp[c_out + o];
            const double mm = (double)bnp[2 * c_out + o];
            const double vv = (double)bnp[3 * c_out + o];
            const double inv   = g / sqrt(vv + 1e-5);
            const double shift = be - mm * inv;
            const double cbv   = cb ? (double)cb[o] : 0.0;
            const size_t per_t = (size_t)B_ * c_out * N_;
            const int jb = j / N_, jn = j % N_;
            const size_t idx0  = ((size_t)jb * c_out + o) * N_ + jn;
            double v = 0.0;
#pragma unroll
            for (int t = 0; t < 4; ++t) {
                const double yv = (acc[t] + cbv) * inv + shift;
                const double h  = v + (yv - v) * tau;
                const double sp = (h >= 1.0) ? 1.0 : 0.0;
                v = h * (1.0 - sp);
                const size_t idx = (size_t)t * per_t + idx0;
                if (OM == 0) SOUT[idx] = (u8)sp;
                else out[idx] = (float)((double)xres[idx] + (double)sres[idx] + sp);
            }
        }
    }
}

// ---------------------------------------------------------------------------
// Spike attention + fused LIF (exact dyadic arithmetic, r5-r12 proven).
// ---------------------------------------------------------------------------
__global__ __launch_bounds__(256) void attn_lif_kernel(
    const u8* __restrict__ SQ, const u8* __restrict__ SK, const u8* __restrict__ SV,
    u8* __restrict__ SATT, const float* __restrict__ lw)
{
    __shared__ u8 q_lds[DH_ * N_];
    __shared__ u8 k_lds[DH_ * N_];
    __shared__ u8 v_lds[DH_ * N_];
    __shared__ float kv_lds[DH_ * DH_];
    __shared__ float vstate[DH_ * N_];
    const int tid = threadIdx.x;
    const int b = blockIdx.x / NH_, h = blockIdx.x % NH_;
    const float tau = 1.0f / (1.0f + expf(-lw[0]));

    for (int i = tid; i < DH_ * N_; i += 256) vstate[i] = 0.0f;

    for (int t = 0; t < T_; ++t) {
        const size_t base = ((size_t)((t * B_ + b) * C_) + h * DH_) * N_;
        __syncthreads();
        for (int i = tid; i < DH_ * N_ / 4; i += 256) {
            ((unsigned int*)q_lds)[i] = ((const unsigned int*)(SQ + base))[i];
            ((unsigned int*)k_lds)[i] = ((const unsigned int*)(SK + base))[i];
            ((unsigned int*)v_lds)[i] = ((const unsigned int*)(SV + base))[i];
        }
        __syncthreads();

#pragma unroll
        for (int r = 0; r < 4; ++r) {
            const int e = tid + 256 * r;
            const int i = e >> 5, jj = e & 31;
            int s = 0;
            for (int nn = 0; nn < N_; nn += 4) {
                uchar4 kk = *(const uchar4*)&k_lds[i * N_ + nn];
                uchar4 uv = *(const uchar4*)&v_lds[jj * N_ + nn];
                s += kk.x * uv.x + kk.y * uv.y + kk.z * uv.z + kk.w * uv.w;
            }
            kv_lds[e] = (float)s;
        }
        __syncthreads();

        for (int e = tid; e < DH_ * N_; e += 256) {
            const int jj = e / N_, nn = e % N_;
            float s = 0.0f;
#pragma unroll
            for (int i = 0; i < DH_; ++i)
                s += q_lds[i * N_ + nn] ? kv_lds[i * DH_ + jj] : 0.0f;
            const float att = 0.125f * s;
            const float v = vstate[e];
            const float hh = v + (att - v) * tau;
            const float sp = (hh >= 1.0f) ? 1.0f : 0.0f;
            vstate[e] = hh * (1.0f - sp);
            SATT[base + e] = (u8)sp;
        }
    }
}

// ---------------------------------------------------------------------------
extern "C" void kernel_launch(void* const* d_in, const int* in_sizes, int n_in,
                              void* d_out, int out_size, void* d_ws, size_t ws_size,
                              hipStream_t stream)
{
    const float* x       = (const float*)d_in[0];
    const float* q_w     = (const float*)d_in[1];
    const float* q_bn    = (const float*)d_in[2];
    const float* q_lw    = (const float*)d_in[3];
    const float* k_w     = (const float*)d_in[4];
    const float* k_bn    = (const float*)d_in[5];
    const float* k_lw    = (const float*)d_in[6];
    const float* v_w     = (const float*)d_in[7];
    const float* v_bn    = (const float*)d_in[8];
    const float* v_lw    = (const float*)d_in[9];
    const float* attn_lw = (const float*)d_in[10];
    const float* proj_w  = (const float*)d_in[11];
    const float* proj_b  = (const float*)d_in[12];
    const float* proj_bn = (const float*)d_in[13];
    const float* proj_lw = (const float*)d_in[14];
    const float* fc1_w   = (const float*)d_in[15];
    const float* fc1_b   = (const float*)d_in[16];
    const float* fc1_bn  = (const float*)d_in[17];
    const float* fc1_lw  = (const float*)d_in[18];
    const float* fc2_w   = (const float*)d_in[19];
    const float* fc2_b   = (const float*)d_in[20];
    const float* fc2_bn  = (const float*)d_in[21];
    const float* fc2_lw  = (const float*)d_in[22];

    // ---- workspace layout (~154 MB), phase-aliased (r12-proven) ----
    u8* base = (u8*)d_ws;
    float* XTf32   = (float*)(base);                // [0, 38.5M)   ph1-4 (exact x, linear-T)
    short* XTfr_h  = (short*)(base + 38535168);     // [38.5, 57.8) ph1 & ph4 (frag)
    short* XTfr_l  = (short*)(base + 57802752);     // [57.8, 77.1) ph1 & ph4 (frag)
    short* SZfrag  = (short*)(base);                // [0, 77.1)    ph5 overlay (frag, c=1536)
    u8*    SQ      = base + 77070336;               // 9,633,792 each, ph1-2
    u8*    SK      = base + 86704128;
    u8*    SV      = base + 96337920;
    u8*    SATT    = base + 105971712;              // ph2-3
    u8*    SZ      = base + 77070336;               // ph4-5 overlay of SQ..SATT (u8 row-major)
    short* SATTfr  = (short*)(base + 115605504);    // 19.3M, ph3 (frag)
    u8*    SPT     = base + 115605504;              // 9.6M,  ph4 overlay (linear-T u8)
    u8*    SP      = base + 134873088;              // 9.6M,  ph3-5
    u32*   cnt     = (u32*)(base + 144506880);      // 256 B
    u32*   flags   = (u32*)(base + 144507136);      // 2.1M
    short* WHb     = (short*)(base + 146604288);    // 3.54M (frag)
    short* WLb     = (short*)(base + 150143232);    // 3.54M -> ends ~153.7M
    float* out = (float*)d_out;

    short *WHq = WHb,          *WHk = WHb + 147456, *WHv = WHb + 294912,
          *WHp = WHb + 442368, *WH1 = WHb + 589824, *WH2 = WHb + 1179648;
    short *WLq = WLb,          *WLk = WLb + 147456, *WLv = WLb + 294912,
          *WLp = WLb + 442368, *WL1 = WLb + 589824, *WL2 = WLb + 1179648;
    u32 *flQ = flags, *flP = flags + FCAP, *fl1 = flags + 2 * FCAP, *fl2 = flags + 3 * FCAP;

    zero_counters<<<1, 64, 0, stream>>>(cnt);

    // 0. weight splits -> fragment layout
    wprep<<<72, 256, 0, stream>>>(q_w,    WHq, WLq, C_, C_);
    wprep<<<72, 256, 0, stream>>>(k_w,    WHk, WLk, C_, C_);
    wprep<<<72, 256, 0, stream>>>(v_w,    WHv, WLv, C_, C_);
    wprep<<<72, 256, 0, stream>>>(proj_w, WHp, WLp, C_, C_);
    wprep<<<288, 256, 0, stream>>>(fc1_w, WH1, WL1, HID_, C_);
    wprep<<<288, 256, 0, stream>>>(fc2_w, WH2, WL2, C_, HID_);

    // 1. x -> frags + exact linear XTf32; fused q/k/v GEMM+LIF; f64 fixup
    tpose<0><<<128 * 6, 256, 0, stream>>>(x, nullptr, XTfr_h, XTfr_l, XTf32, nullptr, C_, 6);
    gemm_lif<2, 0, 3><<<98 * 6 * 3, 256, 0, stream>>>(
        XTfr_h, XTfr_l, WHq, WHk, WHv, WLq, WLk, WLv,
        nullptr, nullptr, nullptr, q_bn, k_bn, v_bn, q_lw, k_lw, v_lw,
        SQ, SK, SV, nullptr, nullptr, nullptr, cnt + 0, flQ, C_, C_, 6);
    fixup_t<0, 0><<<512, 256, 0, stream>>>(
        XTf32, nullptr, q_w, k_w, v_w, nullptr, nullptr, nullptr,
        q_bn, k_bn, v_bn, q_lw, k_lw, v_lw,
        SQ, SK, SV, nullptr, nullptr, nullptr, cnt + 0, flQ, C_, C_);

    // 2. attention + LIF (exact)
    attn_lif_kernel<<<B_ * NH_, 256, 0, stream>>>(SQ, SK, SV, SATT, attn_lw);

    // 3. proj: SATT -> frag (exact bf16); GEMM; fixup reads frag directly
    tpose<1><<<128 * 6, 256, 0, stream>>>(SATT, nullptr, SATTfr, nullptr, nullptr, nullptr, C_, 6);
    gemm_lif<1, 0, 1><<<98 * 6, 256, 0, stream>>>(
        SATTfr, nullptr, WHp, WHp, WHp, WLp, WLp, WLp,
        proj_b, proj_b, proj_b, proj_bn, proj_bn, proj_bn, proj_lw, proj_lw, proj_lw,
        SP, SP, SP, nullptr, nullptr, nullptr, cnt + 1, flP, C_, C_, 6);
    fixup_t<1, 0><<<512, 256, 0, stream>>>(
        SATTfr, nullptr, proj_w, proj_w, proj_w, proj_b, proj_b, proj_b,
        proj_bn, proj_bn, proj_bn, proj_lw, proj_lw, proj_lw,
        SP, SP, SP, nullptr, nullptr, nullptr, cnt + 1, flP, C_, C_);

    // 4. fc1: (x+SP) -> frags + SPT; GEMM; fixup reads XTf32 + SPT
    tpose<0><<<128 * 6, 256, 0, stream>>>(x, SP, XTfr_h, XTfr_l, nullptr, SPT, C_, 6);
    gemm_lif<2, 0, 1><<<98 * 24, 256, 0, stream>>>(
        XTfr_h, XTfr_l, WH1, WH1, WH1, WL1, WL1, WL1,
        fc1_b, fc1_b, fc1_b, fc1_bn, fc1_bn, fc1_bn, fc1_lw, fc1_lw, fc1_lw,
        SZ, SZ, SZ, nullptr, nullptr, nullptr, cnt + 2, fl1, HID_, C_, 24);
    fixup_t<2, 0><<<512, 256, 0, stream>>>(
        XTf32, SPT, fc1_w, fc1_w, fc1_w, fc1_b, fc1_b, fc1_b,
        fc1_bn, fc1_bn, fc1_bn, fc1_lw, fc1_lw, fc1_lw,
        SZ, SZ, SZ, nullptr, nullptr, nullptr, cnt + 2, fl1, HID_, C_);

    // 5. fc2: SZ -> frag (exact bf16, overlays region A); GEMM -> out; fixup
    tpose<1><<<128 * 24, 256, 0, stream>>>(SZ, nullptr, SZfrag, nullptr, nullptr, nullptr, HID_, 24);
    gemm_lif<1, 1, 1><<<98 * 6, 256, 0, stream>>>(
        SZfrag, nullptr, WH2, WH2, WH2, WL2, WL2, WL2,
        fc2_b, fc2_b, fc2_b, fc2_bn, fc2_bn, fc2_bn, fc2_lw, fc2_lw, fc2_lw,
        nullptr, nullptr, nullptr, x, SP, out, cnt + 3, fl2, C_, HID_, 6);
    fixup_t<1, 1><<<512, 256, 0, stream>>>(
        SZfrag, nullptr, fc2_w, fc2_w, fc2_w, fc2_b, fc2_b, fc2_b,
        fc2_bn, fc2_bn, fc2_bn, fc2_lw, fc2_lw, fc2_lw,
        nullptr, nullptr, nullptr, x, SP, out, cnt + 3, fl2, C_, HID_);
}

// Round 14
// 1016.356 us; speedup vs baseline: 6.8672x; 1.0130x over previous
//
#include <hip/hip_runtime.h>
#include <math.h>

#define T_   4
#define B_   32
#define C_   384
#define N_   196
#define HID_ 1536
#define NH_  12
#define DH_  32
#define NCOL (B_*N_)            // 6272 columns j=(b,n)
#define NJT  (NCOL/16)          // 392 j-tiles of 16
#define THRESH 2e-3f            // certainty margin (worst-case MFMA-path err ~3e-4)
#define FCAP (1u<<17)

typedef unsigned char u8;
typedef unsigned int  u32;
using bf16x8 = __attribute__((ext_vector_type(8))) short;
using f32x4  = __attribute__((ext_vector_type(4))) float;

__device__ __forceinline__ float bfbits2f(short u) {
    union { u32 i; float f; } c; c.i = ((u32)(unsigned short)u) << 16; return c.f;
}
__device__ __forceinline__ short f2bf(float f) {       // RNE f32 -> bf16 bits
    u32 b = __float_as_uint(f);
    return (short)((b + 0x7FFFu + ((b >> 16) & 1u)) >> 16);
}

__device__ __forceinline__ void gload_lds16(const short* g, short* l) {
    __builtin_amdgcn_global_load_lds(
        (const __attribute__((address_space(1))) void*)g,
        (__attribute__((address_space(3))) void*)l, 16, 0, 0);
}

__global__ void zero_counters(u32* cnt) { if (threadIdx.x < 4) cnt[threadIdx.x] = 0; }

// ---------------------------------------------------------------------------
// Weight split -> fragment-major, hi/lo ADJACENT (r14):
// A[((ot*nkb + kb)*2 + s)*512 + (ol + 16*part)*8 + elem]
// ---------------------------------------------------------------------------
__global__ void wprep(const float* __restrict__ W, short* __restrict__ HL,
                      int c_out, int c_in)
{
    const int ng = c_out * (c_in >> 3);
    int i = blockIdx.x * 256 + threadIdx.x;
    if (i >= ng) return;
    const int o = i / (c_in >> 3);
    const int c = (i % (c_in >> 3)) << 3;
    const int ot = o >> 4, ol = o & 15;
    const int kb = c >> 5, part = (c & 31) >> 3;
    const int nkb = c_in >> 5;
    const size_t fp = (((size_t)(ot * nkb + kb) * 2) << 9) + (size_t)((ol + (part << 4)) << 3);
    short h8[8], l8[8];
#pragma unroll
    for (int k = 0; k < 8; ++k) {
        float f = W[(size_t)o * c_in + c + k];
        short h = f2bf(f);
        h8[k] = h;
        l8[k] = f2bf(f - bfbits2f(h));
    }
    *(bf16x8*)&HL[fp]       = *(bf16x8*)h8;
    *(bf16x8*)&HL[fp + 512] = *(bf16x8*)l8;
}

// ---------------------------------------------------------------------------
// Transpose [tb][c][n] -> fragment-major B superchunks, t INNER, hi/lo
// adjacent (r14):
//   SPL=2: B[((jt*nkb+kb)*8 + t*2 + s)*512 + (jl+16*part)*8 + elem]
//   SPL=1: B[((jt*nkb+kb)*4 + t    )*512 + ...]  (spikes, hi only, exact)
// + optional exact linear copies for the f64 fixups.
// ---------------------------------------------------------------------------
template<int MODE>
__global__ __launch_bounds__(256) void tpose(
    const void* __restrict__ src, const u8* __restrict__ Sadd,
    short* __restrict__ HL,
    float* __restrict__ F, u8* __restrict__ SPTo,
    int c_tot, int nct)
{
    __shared__ float lds[64][197];
    __shared__ u8 slds[MODE == 0 ? 64 : 1][MODE == 0 ? 197 : 1];
    const int tid = threadIdx.x;
    const int tb = blockIdx.x / nct;
    const int ct = blockIdx.x % nct;
    const int t = tb / B_, b = tb % B_;
    const int nkb = c_tot >> 5;
    const float* Xf = (const float*)src;
    const u8*    Xb = (const u8*)src;

    for (int i = tid; i < 64 * N_; i += 256) {
        int c = i / N_, n = i % N_;
        size_t g = ((size_t)tb * c_tot + ct * 64 + c) * N_ + n;
        if (MODE == 0) {
            float v = Xf[g];
            u8 s = Sadd ? Sadd[g] : (u8)0;
            lds[c][n] = v + (float)s;
            slds[c][n] = s;
        } else {
            lds[c][n] = (float)Xb[g];
        }
    }
    __syncthreads();

    for (int i = tid; i < N_ * 8; i += 256) {
        const int n = i >> 3;
        const int c_loc = (i & 7) << 3;
        const int c = ct * 64 + c_loc;
        const int j = b * N_ + n;
        const int jt = j >> 4, jl = j & 15;
        const int kb = c >> 5, part = (c & 31) >> 3;
        const size_t pos = (size_t)((jl + (part << 4)) << 3);
        short h8[8], l8[8];
        float f8[8];
#pragma unroll
        for (int k = 0; k < 8; ++k) {
            float f = lds[c_loc + k][n];
            f8[k] = f;
            short h = f2bf(f);
            h8[k] = h;
            if (MODE == 0) l8[k] = f2bf(f - bfbits2f(h));
        }
        if (MODE == 0) {
            const size_t fp = (((size_t)(jt * nkb + kb) * 8 + t * 2) << 9) + pos;
            *(bf16x8*)&HL[fp]       = *(bf16x8*)h8;
            *(bf16x8*)&HL[fp + 512] = *(bf16x8*)l8;
            if (F) {
                const size_t lp = ((size_t)(t * NCOL + j)) * c_tot + c;
                *(float4*)&F[lp]     = *(float4*)&f8[0];
                *(float4*)&F[lp + 4] = *(float4*)&f8[4];
            }
            if (SPTo) {
                const size_t lp = ((size_t)(t * NCOL + j)) * c_tot + c;
#pragma unroll
                for (int k = 0; k < 8; ++k) SPTo[lp + k] = slds[c_loc + k][n];
            }
        } else {
            const size_t fp = (((size_t)(jt * nkb + kb) * 4 + t) << 9) + pos;
            *(bf16x8*)&HL[fp] = *(bf16x8*)h8;
        }
    }
}

// ---------------------------------------------------------------------------
// MFMA GEMM + BN + LIF + flagging.  C[o,j,t] = sum_c W[o,c] X[t,j,c].
// Block: 64o x 64m; 4 waves split m.  Bijective XCD swizzle (r10).
// r14: B superchunks -> a wave's 8 loads/kb are 8 CONSECUTIVE KB from one
// base; A hi/lo adjacent.  A staged via double-buffered LDS (r13).
// Per-lane data bit-identical to r12/r13 -> all spike decisions unchanged.
// D: col = lane&15, row = (lane>>4)*4 + reg  [m89-verified].
// ---------------------------------------------------------------------------
template<int SPLITS, int OM, int NZ>
__global__ __launch_bounds__(256) void gemm_lif(
    const short* __restrict__ BHL,
    const short* __restrict__ WA0, const short* __restrict__ WA1, const short* __restrict__ WA2,
    const float* __restrict__ cb0, const float* __restrict__ cb1, const float* __restrict__ cb2,
    const float* __restrict__ bn0, const float* __restrict__ bn1, const float* __restrict__ bn2,
    const float* __restrict__ lw0, const float* __restrict__ lw1, const float* __restrict__ lw2,
    u8* S0, u8* S1, u8* S2,
    const float* __restrict__ xres, const u8* __restrict__ sres, float* __restrict__ out,
    u32* __restrict__ cnt, u32* __restrict__ flags,
    int c_out, int c_in, int nob)
{
    __shared__ short a_lds[2][8][512];     // [buf][chunk = os*2+split][1KB]
    const int tid = threadIdx.x;
    const int w = tid >> 6, l = tid & 63;

    // ---- bijective XCD-contiguity swizzle (8 XCDs, m204 formula) ----
    const u32 nwg = gridDim.x;
    const u32 q = nwg >> 3, r = nwg & 7;
    const u32 xcd = blockIdx.x & 7, off = blockIdx.x >> 3;
    const u32 id = (xcd < r ? xcd * (q + 1) : r * (q + 1) + (xcd - r) * q) + off;

    const int mt  = (int)(id / (u32)(nob * NZ));
    const int rem = (int)(id % (u32)(nob * NZ));
    const int z  = (NZ == 1) ? 0 : (rem % NZ);
    const int ob = (NZ == 1) ? rem : (rem / NZ);

    const short* WA  = (z == 0) ? WA0 : ((z == 1) ? WA1 : WA2);
    const float* cb  = (z == 0) ? cb0 : ((z == 1) ? cb1 : cb2);
    const float* bnp = (z == 0) ? bn0 : ((z == 1) ? bn1 : bn2);
    const float* lw  = (z == 0) ? lw0 : ((z == 1) ? lw1 : lw2);
    u8* SOUT         = (z == 0) ? S0  : ((z == 1) ? S1  : S2);

    const int nkb = c_in >> 5;
    const int jt = mt * 4 + w;
    const int j  = jt * 16 + (l & 15);
    const int ob64 = ob * 64;

    f32x4 acc[4][4];
#pragma unroll
    for (int t = 0; t < 4; ++t)
#pragma unroll
        for (int os = 0; os < 4; ++os)
            acc[t][os] = (f32x4){0.f, 0.f, 0.f, 0.f};

    // B superchunk base: per kb, 8 (or 4) consecutive 1KB chunks
    const short* bbase = BHL + (size_t)l * 8;

    // ping/pong B fragment sets (statically named; no dynamic indexing)
    bf16x8 bhA[4], blA[4], bhB[4], blB[4];

    auto LOADB = [&](int kb, bf16x8* bh, bf16x8* bl) {
        const short* p = bbase + (((size_t)jt * nkb + kb) << (SPLITS == 2 ? 12 : 11));
#pragma unroll
        for (int t = 0; t < 4; ++t) {
            if (SPLITS == 2) {
                bh[t] = *(const bf16x8*)(p + ((size_t)(t * 2)     << 9));
                bl[t] = *(const bf16x8*)(p + ((size_t)(t * 2 + 1) << 9));
            } else {
                bh[t] = *(const bf16x8*)(p + ((size_t)t << 9));
            }
        }
    };
    // wave w stages chunks {2w, 2w+1} of A(kb) into buf p (1KB each, lane*16)
    auto STAGE = [&](int kb, int p) {
#pragma unroll
        for (int cc = 0; cc < 2; ++cc) {
            const int ch = w * 2 + cc;
            const int os = ch >> 1, split = ch & 1;
            const short* src = WA
                + ((((size_t)(ob * 4 + os) * nkb + kb) * 2 + split) << 9) + (size_t)l * 8;
            gload_lds16(src, &a_lds[p][ch][(size_t)l * 8]);
        }
    };
    auto COMPUTE = [&](int p, const bf16x8* bh, const bf16x8* bl) {
        bf16x8 ah[4], al[4];
#pragma unroll
        for (int os = 0; os < 4; ++os) {
            ah[os] = *(const bf16x8*)&a_lds[p][os * 2][(size_t)l * 8];
            al[os] = *(const bf16x8*)&a_lds[p][os * 2 + 1][(size_t)l * 8];
        }
#pragma unroll
        for (int os = 0; os < 4; ++os) {
#pragma unroll
            for (int t = 0; t < 4; ++t) {
                acc[t][os] = __builtin_amdgcn_mfma_f32_16x16x32_bf16(ah[os], bh[t], acc[t][os], 0, 0, 0);
                acc[t][os] = __builtin_amdgcn_mfma_f32_16x16x32_bf16(al[os], bh[t], acc[t][os], 0, 0, 0);
                if (SPLITS == 2)   // lo x lo term dropped (r11)
                    acc[t][os] = __builtin_amdgcn_mfma_f32_16x16x32_bf16(ah[os], bl[t], acc[t][os], 0, 0, 0);
            }
        }
    };

    STAGE(0, 0);
    LOADB(0, bhA, blA);
    __syncthreads();                       // buf0 ready
    for (int kb = 0; kb < nkb; kb += 2) {  // nkb is even (12 or 48)
        STAGE(kb + 1, 1);
        LOADB(kb + 1, bhB, blB);
        COMPUTE(0, bhA, blA);
        __syncthreads();                   // buf1 ready; buf0 free
        if (kb + 2 < nkb) {
            STAGE(kb + 2, 0);
            LOADB(kb + 2, bhA, blA);
        }
        COMPUTE(1, bhB, blB);
        __syncthreads();                   // buf0 ready; buf1 free
    }

    const float tau = 1.0f / (1.0f + expf(-lw[0]));
    const size_t per_t = (size_t)B_ * c_out * N_;
    const int jb = j / N_, jn = j % N_;
#pragma unroll
    for (int os = 0; os < 4; ++os) {
#pragma unroll
        for (int r2 = 0; r2 < 4; ++r2) {
            const int o = ob64 + os * 16 + (l >> 4) * 4 + r2;
            const float g  = bnp[o];
            const float be = bnp[c_out + o];
            const float mm = bnp[2 * c_out + o];
            const float vv = bnp[3 * c_out + o];
            const float inv   = g / sqrtf(vv + 1e-5f);
            const float shift = be - mm * inv;
            const float cbv   = cb ? cb[o] : 0.0f;
            const size_t idx0 = ((size_t)jb * c_out + o) * N_ + jn;
            float v = 0.0f;
            bool flag = false;
#pragma unroll
            for (int t = 0; t < 4; ++t) {
                const float yv = (acc[t][os][r2] + cbv) * inv + shift;
                const float h  = v + (yv - v) * tau;
                const float sp = (h >= 1.0f) ? 1.0f : 0.0f;
                flag = flag || (fabsf(h - 1.0f) < THRESH);
                v = h * (1.0f - sp);
                const size_t idx = (size_t)t * per_t + idx0;
                if (OM == 0) SOUT[idx] = (u8)sp;
                else out[idx] = (float)((double)xres[idx] + (double)sres[idx] + (double)sp);
            }
            if (flag) {
                u32 p = atomicAdd(cnt, 1u);
                if (p < FCAP) flags[p] = ((u32)(z * c_out + o)) * (u32)NCOL + (u32)j;
            }
        }
    }
}

// ---------------------------------------------------------------------------
// f64 fixup (decision math = r5/r7-proven all-f64 path).
// IN_MODE 0: linear f32 XT; 1: fragment-major bf16 spikes (r14 layout);
// 2: linear f32 XT + linear u8 SPT.
// ---------------------------------------------------------------------------
template<int IN_MODE, int OM>
__global__ __launch_bounds__(256) void fixup_t(
    const void* __restrict__ XT, const u8* __restrict__ SPT,
    const float* __restrict__ W0, const float* __restrict__ W1, const float* __restrict__ W2,
    const float* __restrict__ cb0, const float* __restrict__ cb1, const float* __restrict__ cb2,
    const float* __restrict__ bn0, const float* __restrict__ bn1, const float* __restrict__ bn2,
    const float* __restrict__ lw0, const float* __restrict__ lw1, const float* __restrict__ lw2,
    u8* S0, u8* S1, u8* S2,
    const float* __restrict__ xres, const u8* __restrict__ sres, float* out,
    const u32* __restrict__ cnt, const u32* __restrict__ flags,
    int c_out, int c_in)
{
    const int lane = threadIdx.x & 63;
    const int wid  = (blockIdx.x * 256 + threadIdx.x) >> 6;
    const int nw   = (gridDim.x * 256) >> 6;
    u32 nrec = *cnt;
    if (nrec > FCAP) nrec = FCAP;

    const float* XTf = (const float*)XT;
    const short* XTs = (const short*)XT;
    const int nkb = c_in >> 5;

    for (u32 r = wid; r < nrec; r += nw) {
        const u32 rec = flags[r];
        const int j  = (int)(rec % (u32)NCOL);
        const u32 zo = rec / (u32)NCOL;
        const int z  = (int)(zo / (u32)c_out);
        const int o  = (int)(zo % (u32)c_out);
        const int jt = j >> 4, jl = j & 15;

        const float* W   = (z == 0) ? W0  : ((z == 1) ? W1  : W2);
        const float* cb  = (z == 0) ? cb0 : ((z == 1) ? cb1 : cb2);
        const float* bnp = (z == 0) ? bn0 : ((z == 1) ? bn1 : bn2);
        const float* lw  = (z == 0) ? lw0 : ((z == 1) ? lw1 : lw2);
        u8* SOUT         = (z == 0) ? S0  : ((z == 1) ? S1  : S2);

        double acc[4] = {0.0, 0.0, 0.0, 0.0};
        for (int c = lane; c < c_in; c += 64) {
            const double w = (double)W[(size_t)o * c_in + c];
#pragma unroll
            for (int t = 0; t < 4; ++t) {
                double xval;
                if (IN_MODE == 1) {
                    const int kb = c >> 5, part = (c & 31) >> 3, elem = c & 7;
                    const size_t idx = (((size_t)(jt * nkb + kb) * 4 + t) << 9)
                                     + (size_t)((jl + (part << 4)) << 3) + elem;
                    xval = (double)bfbits2f(XTs[idx]);
                } else {
                    const size_t i = ((size_t)(t * NCOL + j)) * c_in + c;
                    if (IN_MODE == 0) xval = (double)XTf[i];
                    else              xval = (double)XTf[i] + (double)SPT[i];
                }
                acc[t] = fma(w, xval, acc[t]);
            }
        }
#pragma unroll
        for (int m = 32; m; m >>= 1) {
#pragma unroll
            for (int t = 0; t < 4; ++t)
                acc[t] += __shfl_xor(acc[t], m, 64);
        }

        if (lane == 0) {
            const double tau = 1.0 / (1.0 + exp(-(double)lw[0]));
            const double g  = (double)bnp[o];
            const double be = (double)bnp[c_out + o];
            const double mm = (double)bnp[2 * c_out + o];
            const double vv = (double)bnp[3 * c_out + o];
            const double inv   = g / sqrt(vv + 1e-5);
            const double shift = be - mm * inv;
            const double cbv   = cb ? (double)cb[o] : 0.0;
            const size_t per_t = (size_t)B_ * c_out * N_;
            const int jb = j / N_, jn = j % N_;
            const size_t idx0  = ((size_t)jb * c_out + o) * N_ + jn;
            double v = 0.0;
#pragma unroll
            for (int t = 0; t < 4; ++t) {
                const double yv = (acc[t] + cbv) * inv + shift;
                const double h  = v + (yv - v) * tau;
                const double sp = (h >= 1.0) ? 1.0 : 0.0;
                v = h * (1.0 - sp);
                const size_t idx = (size_t)t * per_t + idx0;
                if (OM == 0) SOUT[idx] = (u8)sp;
                else out[idx] = (float)((double)xres[idx] + (double)sres[idx] + sp);
            }
        }
    }
}

// ---------------------------------------------------------------------------
// Spike attention + fused LIF (exact dyadic arithmetic, r5-r13 proven).
// ---------------------------------------------------------------------------
__global__ __launch_bounds__(256) void attn_lif_kernel(
    const u8* __restrict__ SQ, const u8* __restrict__ SK, const u8* __restrict__ SV,
    u8* __restrict__ SATT, const float* __restrict__ lw)
{
    __shared__ u8 q_lds[DH_ * N_];
    __shared__ u8 k_lds[DH_ * N_];
    __shared__ u8 v_lds[DH_ * N_];
    __shared__ float kv_lds[DH_ * DH_];
    __shared__ float vstate[DH_ * N_];
    const int tid = threadIdx.x;
    const int b = blockIdx.x / NH_, h = blockIdx.x % NH_;
    const float tau = 1.0f / (1.0f + expf(-lw[0]));

    for (int i = tid; i < DH_ * N_; i += 256) vstate[i] = 0.0f;

    for (int t = 0; t < T_; ++t) {
        const size_t base = ((size_t)((t * B_ + b) * C_) + h * DH_) * N_;
        __syncthreads();
        for (int i = tid; i < DH_ * N_ / 4; i += 256) {
            ((unsigned int*)q_lds)[i] = ((const unsigned int*)(SQ + base))[i];
            ((unsigned int*)k_lds)[i] = ((const unsigned int*)(SK + base))[i];
            ((unsigned int*)v_lds)[i] = ((const unsigned int*)(SV + base))[i];
        }
        __syncthreads();

#pragma unroll
        for (int r = 0; r < 4; ++r) {
            const int e = tid + 256 * r;
            const int i = e >> 5, jj = e & 31;
            int s = 0;
            for (int nn = 0; nn < N_; nn += 4) {
                uchar4 kk = *(const uchar4*)&k_lds[i * N_ + nn];
                uchar4 uv = *(const uchar4*)&v_lds[jj * N_ + nn];
                s += kk.x * uv.x + kk.y * uv.y + kk.z * uv.z + kk.w * uv.w;
            }
            kv_lds[e] = (float)s;
        }
        __syncthreads();

        for (int e = tid; e < DH_ * N_; e += 256) {
            const int jj = e / N_, nn = e % N_;
            float s = 0.0f;
#pragma unroll
            for (int i = 0; i < DH_; ++i)
                s += q_lds[i * N_ + nn] ? kv_lds[i * DH_ + jj] : 0.0f;
            const float att = 0.125f * s;
            const float v = vstate[e];
            const float hh = v + (att - v) * tau;
            const float sp = (hh >= 1.0f) ? 1.0f : 0.0f;
            vstate[e] = hh * (1.0f - sp);
            SATT[base + e] = (u8)sp;
        }
    }
}

// ---------------------------------------------------------------------------
extern "C" void kernel_launch(void* const* d_in, const int* in_sizes, int n_in,
                              void* d_out, int out_size, void* d_ws, size_t ws_size,
                              hipStream_t stream)
{
    const float* x       = (const float*)d_in[0];
    const float* q_w     = (const float*)d_in[1];
    const float* q_bn    = (const float*)d_in[2];
    const float* q_lw    = (const float*)d_in[3];
    const float* k_w     = (const float*)d_in[4];
    const float* k_bn    = (const float*)d_in[5];
    const float* k_lw    = (const float*)d_in[6];
    const float* v_w     = (const float*)d_in[7];
    const float* v_bn    = (const float*)d_in[8];
    const float* v_lw    = (const float*)d_in[9];
    const float* attn_lw = (const float*)d_in[10];
    const float* proj_w  = (const float*)d_in[11];
    const float* proj_b  = (const float*)d_in[12];
    const float* proj_bn = (const float*)d_in[13];
    const float* proj_lw = (const float*)d_in[14];
    const float* fc1_w   = (const float*)d_in[15];
    const float* fc1_b   = (const float*)d_in[16];
    const float* fc1_bn  = (const float*)d_in[17];
    const float* fc1_lw  = (const float*)d_in[18];
    const float* fc2_w   = (const float*)d_in[19];
    const float* fc2_b   = (const float*)d_in[20];
    const float* fc2_bn  = (const float*)d_in[21];
    const float* fc2_lw  = (const float*)d_in[22];

    // ---- workspace layout (~154 MB), phase-aliased (regions as r12/r13) ----
    u8* base = (u8*)d_ws;
    float* XTf32   = (float*)(base);                // [0, 38.5M)   ph1-4 (exact x, linear-T)
    short* XTfr    = (short*)(base + 38535168);     // [38.5, 77.1) ph1 & ph4 (frag, hi+lo merged)
    short* SZfrag  = (short*)(base);                // [0, 77.1)    ph5 overlay (frag, c=1536, spikes)
    u8*    SQ      = base + 77070336;               // 9,633,792 each, ph1-2
    u8*    SK      = base + 86704128;
    u8*    SV      = base + 96337920;
    u8*    SATT    = base + 105971712;              // ph2-3
    u8*    SZ      = base + 77070336;               // ph4-5 overlay of SQ..SATT (u8 row-major)
    short* SATTfr  = (short*)(base + 115605504);    // 19.3M, ph3 (frag, spikes)
    u8*    SPT     = base + 115605504;              // 9.6M,  ph4 overlay (linear-T u8)
    u8*    SP      = base + 134873088;              // 9.6M,  ph3-5
    u32*   cnt     = (u32*)(base + 144506880);      // 256 B
    u32*   flags   = (u32*)(base + 144507136);      // 2.1M
    short* WAb     = (short*)(base + 146604288);    // 7.08M (frag, hi+lo merged)
    float* out = (float*)d_out;

    short *WAq = WAb,           *WAk = WAb + 294912, *WAv = WAb + 589824,
          *WAp = WAb + 884736,  *WA1 = WAb + 1179648, *WA2 = WAb + 2359296;
    u32 *flQ = flags, *flP = flags + FCAP, *fl1 = flags + 2 * FCAP, *fl2 = flags + 3 * FCAP;

    zero_counters<<<1, 64, 0, stream>>>(cnt);

    // 0. weight splits -> fragment layout (hi/lo adjacent)
    wprep<<<72, 256, 0, stream>>>(q_w,    WAq, C_, C_);
    wprep<<<72, 256, 0, stream>>>(k_w,    WAk, C_, C_);
    wprep<<<72, 256, 0, stream>>>(v_w,    WAv, C_, C_);
    wprep<<<72, 256, 0, stream>>>(proj_w, WAp, C_, C_);
    wprep<<<288, 256, 0, stream>>>(fc1_w, WA1, HID_, C_);
    wprep<<<288, 256, 0, stream>>>(fc2_w, WA2, C_, HID_);

    // 1. x -> frag superchunks + exact linear XTf32; fused q/k/v GEMM+LIF; fixup
    tpose<0><<<128 * 6, 256, 0, stream>>>(x, nullptr, XTfr, XTf32, nullptr, C_, 6);
    gemm_lif<2, 0, 3><<<98 * 6 * 3, 256, 0, stream>>>(
        XTfr, WAq, WAk, WAv,
        nullptr, nullptr, nullptr, q_bn, k_bn, v_bn, q_lw, k_lw, v_lw,
        SQ, SK, SV, nullptr, nullptr, nullptr, cnt + 0, flQ, C_, C_, 6);
    fixup_t<0, 0><<<512, 256, 0, stream>>>(
        XTf32, nullptr, q_w, k_w, v_w, nullptr, nullptr, nullptr,
        q_bn, k_bn, v_bn, q_lw, k_lw, v_lw,
        SQ, SK, SV, nullptr, nullptr, nullptr, cnt + 0, flQ, C_, C_);

    // 2. attention + LIF (exact)
    attn_lif_kernel<<<B_ * NH_, 256, 0, stream>>>(SQ, SK, SV, SATT, attn_lw);

    // 3. proj: SATT -> frag (exact bf16); GEMM; fixup reads frag directly
    tpose<1><<<128 * 6, 256, 0, stream>>>(SATT, nullptr, SATTfr, nullptr, nullptr, C_, 6);
    gemm_lif<1, 0, 1><<<98 * 6, 256, 0, stream>>>(
        SATTfr, WAp, WAp, WAp,
        proj_b, proj_b, proj_b, proj_bn, proj_bn, proj_bn, proj_lw, proj_lw, proj_lw,
        SP, SP, SP, nullptr, nullptr, nullptr, cnt + 1, flP, C_, C_, 6);
    fixup_t<1, 0><<<512, 256, 0, stream>>>(
        SATTfr, nullptr, proj_w, proj_w, proj_w, proj_b, proj_b, proj_b,
        proj_bn, proj_bn, proj_bn, proj_lw, proj_lw, proj_lw,
        SP, SP, SP, nullptr, nullptr, nullptr, cnt + 1, flP, C_, C_);

    // 4. fc1: (x+SP) -> frag superchunks + SPT; GEMM; fixup reads XTf32 + SPT
    tpose<0><<<128 * 6, 256, 0, stream>>>(x, SP, XTfr, nullptr, SPT, C_, 6);
    gemm_lif<2, 0, 1><<<98 * 24, 256, 0, stream>>>(
        XTfr, WA1, WA1, WA1,
        fc1_b, fc1_b, fc1_b, fc1_bn, fc1_bn, fc1_bn, fc1_lw, fc1_lw, fc1_lw,
        SZ, SZ, SZ, nullptr, nullptr, nullptr, cnt + 2, fl1, HID_, C_, 24);
    fixup_t<2, 0><<<512, 256, 0, stream>>>(
        XTf32, SPT, fc1_w, fc1_w, fc1_w, fc1_b, fc1_b, fc1_b,
        fc1_bn, fc1_bn, fc1_bn, fc1_lw, fc1_lw, fc1_lw,
        SZ, SZ, SZ, nullptr, nullptr, nullptr, cnt + 2, fl1, HID_, C_);

    // 5. fc2: SZ -> frag (exact bf16, overlays region A); GEMM -> out; fixup
    tpose<1><<<128 * 24, 256, 0, stream>>>(SZ, nullptr, SZfrag, nullptr, nullptr, HID_, 24);
    gemm_lif<1, 1, 1><<<98 * 6, 256, 0, stream>>>(
        SZfrag, WA2, WA2, WA2,
        fc2_b, fc2_b, fc2_b, fc2_bn, fc2_bn, fc2_bn, fc2_lw, fc2_lw, fc2_lw,
        nullptr, nullptr, nullptr, x, SP, out, cnt + 3, fl2, C_, HID_, 6);
    fixup_t<1, 1><<<512, 256, 0, stream>>>(
        SZfrag, nullptr, fc2_w, fc2_w, fc2_w, fc2_b, fc2_b, fc2_b,
        fc2_bn, fc2_bn, fc2_bn, fc2_lw, fc2_lw, fc2_lw,
        nullptr, nullptr, nullptr, x, SP, out, cnt + 3, fl2, C_, HID_);
}